// Round 1
// baseline (5472.961 us; speedup 1.0000x reference)
//
#include <hip/hip_runtime.h>
#include <hip/hip_bf16.h>

// Gated Transformer-XL forward, bf16 MFMA GEMMs with fused epilogues.
// Dims: L=4, D=1024, NH=16, HD=64, CUR=512, MEM=512, BS=8, IN=512, FF=4096, FULL=1024
// Row layout convention: activations are (seq*BS, D) with row = i*BS + b.

typedef __attribute__((ext_vector_type(8))) __bf16 bfrag;
typedef __attribute__((ext_vector_type(4))) float f4;
typedef __attribute__((ext_vector_type(4))) unsigned short u16x4;

__device__ __forceinline__ unsigned short f2bf(float f){
  union { float f; unsigned u; } v; v.f = f;
  unsigned r = v.u + 0x7fffu + ((v.u >> 16) & 1u);
  return (unsigned short)(r >> 16);
}
__device__ __forceinline__ float geluf(float x){
  return 0.5f * x * (1.0f + erff(x * 0.7071067811865476f));
}
__device__ __forceinline__ float sigm(float x){ return 1.0f/(1.0f + __expf(-x)); }

__device__ __forceinline__ void gl_lds(const void* g, void* l){
  __builtin_amdgcn_global_load_lds(
    reinterpret_cast<const __attribute__((address_space(1))) unsigned int*>(
        reinterpret_cast<unsigned long>(g)),
    reinterpret_cast<__attribute__((address_space(3))) unsigned int*>(
        reinterpret_cast<unsigned long>(l)),
    16, 0, 0);
}

// ---------------------------------------------------------------------------
// GEMM: C[M,N] = A[M,K] (bf16, row-major, lda) @ B[N,K]^T (bf16 row-major, ldb)
// Batched over grid.z: offsets = z*s?z + b*s?b + h*s?h  with bh = bh0+z, b=bh>>4, h=bh&15.
// EPI: 0 C=acc | 1 O1=bf(acc) | 2 O1=bf(acc+bias1[c]),O2=bf(acc+bias2[c])
//      3 vhT scatter | 4 BD rel-shift scatter | 5 score: C=(C+acc)/8 masked
//      6 O1=bf(gelu(acc+bias1)) | 7 gelu both f32+bf16 | 8 rx=bf(sigm(C+acc)*X)
//      9 C=sigm(C+acc-2) | 10 gru: o=(1-Z)*X+Z*tanh(C+acc) -> OF,O1
// ---------------------------------------------------------------------------
struct GP {
  const unsigned short* A;
  const unsigned short* B;
  float* C;
  unsigned short* O1;
  unsigned short* O2;
  float* OF;
  const float* bias1;
  const float* bias2;
  const float* X;
  const float* Z;
  int K, lda, ldb, ldc, ldo;
  int sAz, sAb, sAh, sBz, sBb, sBh, sCz, sOb, sOh;
  int bh0;
};

template<int BM, int BN, int EPI>
__global__ __launch_bounds__(256) void gemm_k(GP p){
  __shared__ unsigned short As[BM*32];
  __shared__ unsigned short Bs[BN*32];
  const int tid  = threadIdx.x;
  const int lane = tid & 63;
  const int wid  = tid >> 6;
  const int lr   = lane & 15;
  const int lg   = lane >> 4;
  constexpr int FM = BM/32, FN = BN/32;
  const int m0 = blockIdx.y * BM;
  const int n0 = blockIdx.x * BN;
  const int z  = blockIdx.z;
  const int bh = p.bh0 + z;
  const int bb = bh >> 4, hh = bh & 15;
  const unsigned short* Ab = p.A + (long)z*p.sAz + (long)bb*p.sAb + (long)hh*p.sAh + (long)m0*p.lda;
  const unsigned short* Bb = p.B + (long)z*p.sBz + (long)bb*p.sBb + (long)hh*p.sBh + (long)n0*p.ldb;
  const int srow = tid >> 2;          // 0..63
  const int skk  = (tid & 3) * 8;

  f4 acc[FM][FN];
  f4 zero4 = {0.0f, 0.0f, 0.0f, 0.0f};
  #pragma unroll
  for (int m=0;m<FM;m++)
    #pragma unroll
    for (int n=0;n<FN;n++) acc[m][n] = zero4;

  for (int k0 = 0; k0 < p.K; k0 += 32){
    #pragma unroll
    for (int q=0;q<BM/64;q++)
      gl_lds(Ab + (long)(q*64 + srow)*p.lda + k0 + skk, (char*)As + q*4096 + wid*1024);
    #pragma unroll
    for (int q=0;q<BN/64;q++)
      gl_lds(Bb + (long)(q*64 + srow)*p.ldb + k0 + skk, (char*)Bs + q*4096 + wid*1024);
    __syncthreads();
    bfrag af[FM], bfr[FN];
    #pragma unroll
    for (int m=0;m<FM;m++)
      af[m] = *(const bfrag*)&As[((wid>>1)*(BM/2) + m*16 + lr)*32 + lg*8];
    #pragma unroll
    for (int n=0;n<FN;n++)
      bfr[n] = *(const bfrag*)&Bs[((wid&1)*(BN/2) + n*16 + lr)*32 + lg*8];
    #pragma unroll
    for (int m=0;m<FM;m++)
      #pragma unroll
      for (int n=0;n<FN;n++)
        acc[m][n] = __builtin_amdgcn_mfma_f32_16x16x32_bf16(af[m], bfr[n], acc[m][n], 0, 0, 0);
    __syncthreads();
  }

  const int wr0 = m0 + (wid>>1)*(BM/2);
  const int wc0 = n0 + (wid&1)*(BN/2);
  const long offC = (long)z * p.sCz;
  const long offO = (long)bb * p.sOb + (long)hh * p.sOh;
  #pragma unroll
  for (int m=0;m<FM;m++)
    #pragma unroll
    for (int n=0;n<FN;n++)
      #pragma unroll
      for (int r=0;r<4;r++){
        const int gr = wr0 + m*16 + lg*4 + r;
        const int gc = wc0 + n*16 + lr;
        const float a = acc[m][n][r];
        const long ic = offC + (long)gr*p.ldc + gc;
        const long io = offO + (long)gr*p.ldo + gc;
        if constexpr (EPI==0){ p.C[ic] = a; }
        else if constexpr (EPI==1){ p.O1[io] = f2bf(a); }
        else if constexpr (EPI==2){ p.O1[io] = f2bf(a + p.bias1[gc]); p.O2[io] = f2bf(a + p.bias2[gc]); }
        else if constexpr (EPI==3){ // vh -> vhT[(b*16+h)][d][jseq]
          const int b_ = gr & 7, js = gr >> 3, h_ = gc >> 6, d_ = gc & 63;
          p.O1[(long)(b_*16 + h_)*65536 + d_*1024 + js] = f2bf(a);
        }
        else if constexpr (EPI==4){ // rel-shift scatter: j = r_idx + i - 511
          const int j = gc + gr - 511;
          if (j >= 0) p.C[offC + (long)gr*p.ldc + j] = a;
        }
        else if constexpr (EPI==5){ // score: add AC, scale, mask
          float sc = (p.C[ic] + a) * 0.125f;
          if (gc > 512 + gr) sc = -1e30f;
          p.C[ic] = sc;
        }
        else if constexpr (EPI==6){
          const float t = a + (p.bias1 ? p.bias1[gc] : 0.0f);
          p.O1[io] = f2bf(geluf(t));
        }
        else if constexpr (EPI==7){
          const float t = geluf(a + p.bias1[gc]);
          p.OF[ic] = t; p.O1[io] = f2bf(t);
        }
        else if constexpr (EPI==8){
          const float v = p.C[ic] + a;
          p.O1[io] = f2bf(sigm(v) * p.X[ic]);
        }
        else if constexpr (EPI==9){
          p.C[ic] = sigm(p.C[ic] + a - 2.0f);
        }
        else if constexpr (EPI==10){
          const float v  = p.C[ic] + a;
          const float zz = p.Z[ic];
          const float xx = p.X[ic];
          const float oo = (1.0f - zz)*xx + zz*tanhf(v);
          p.OF[ic] = oo; p.O1[io] = f2bf(oo);
        }
      }
}

// ---------------------------------------------------------------------------
__global__ __launch_bounds__(256) void ln_k(const float* __restrict__ srcA,
                                            const float* __restrict__ srcB, int splitRow,
                                            const float* __restrict__ g, const float* __restrict__ b,
                                            unsigned short* __restrict__ dst){
  const int row = blockIdx.x;
  const float* src = (srcB != nullptr && row >= splitRow)
                       ? (srcB + (long)(row - splitRow)*1024)
                       : (srcA + (long)row*1024);
  const int t = threadIdx.x;
  float4 v = ((const float4*)src)[t];
  float s1 = v.x+v.y+v.z+v.w;
  float s2 = v.x*v.x+v.y*v.y+v.z*v.z+v.w*v.w;
  #pragma unroll
  for (int o=32;o;o>>=1){ s1 += __shfl_xor(s1,o); s2 += __shfl_xor(s2,o); }
  __shared__ float r1[4], r2[4];
  const int w = t>>6;
  if ((t&63)==0){ r1[w]=s1; r2[w]=s2; }
  __syncthreads();
  s1 = r1[0]+r1[1]+r1[2]+r1[3];
  s2 = r2[0]+r2[1]+r2[2]+r2[3];
  const float mean = s1*(1.0f/1024.0f);
  const float var  = s2*(1.0f/1024.0f) - mean*mean;
  const float rs   = rsqrtf(var + 1e-5f);
  const int c = t*4;
  float4 gg = ((const float4*)g)[t];
  float4 bb = ((const float4*)b)[t];
  u16x4 o;
  o.x = f2bf((v.x-mean)*rs*gg.x + bb.x);
  o.y = f2bf((v.y-mean)*rs*gg.y + bb.y);
  o.z = f2bf((v.z-mean)*rs*gg.z + bb.z);
  o.w = f2bf((v.w-mean)*rs*gg.w + bb.w);
  *(u16x4*)(dst + (long)row*1024 + c) = o;
}

__global__ __launch_bounds__(256) void softmax_k(float* __restrict__ S){
  float* row = S + (long)blockIdx.x*1024;
  const int t = threadIdx.x;
  float4 v = ((const float4*)row)[t];
  float m = fmaxf(fmaxf(v.x,v.y), fmaxf(v.z,v.w));
  #pragma unroll
  for (int o=32;o;o>>=1) m = fmaxf(m, __shfl_xor(m,o));
  __shared__ float r1[4], r2[4];
  const int w = t>>6;
  if ((t&63)==0) r1[w]=m;
  __syncthreads();
  m = fmaxf(fmaxf(r1[0],r1[1]), fmaxf(r1[2],r1[3]));
  const float e0=__expf(v.x-m), e1=__expf(v.y-m), e2=__expf(v.z-m), e3=__expf(v.w-m);
  float s = e0+e1+e2+e3;
  #pragma unroll
  for (int o=32;o;o>>=1) s += __shfl_xor(s,o);
  if ((t&63)==0) r2[w]=s;
  __syncthreads();
  s = r2[0]+r2[1]+r2[2]+r2[3];
  const float inv = 1.0f/s;
  unsigned short* pp = (unsigned short*)row;   // in-place bf16 P (lda=2048)
  u16x4 o;
  o.x=f2bf(e0*inv); o.y=f2bf(e1*inv); o.z=f2bf(e2*inv); o.w=f2bf(e3*inv);
  *(u16x4*)(pp + t*4) = o;
}

__global__ __launch_bounds__(256) void conv_k(const float* __restrict__ s,
                                              unsigned short* __restrict__ d, long n){
  long i = ((long)blockIdx.x*256 + threadIdx.x)*4;
  if (i >= n) return;
  float4 v = *(const float4*)(s + i);
  u16x4 o; o.x=f2bf(v.x); o.y=f2bf(v.y); o.z=f2bf(v.z); o.w=f2bf(v.w);
  *(u16x4*)(d + i) = o;
}

__global__ __launch_bounds__(128) void ht_k(const float* __restrict__ h,
                                            unsigned short* __restrict__ d){
  const int row = blockIdx.x;           // i*8+b
  const int i = row>>3, b = row&7;
  const float* src = h + ((long)b*512 + i)*512;
  const int t = threadIdx.x;
  float4 v = ((const float4*)src)[t];
  u16x4 o; o.x=f2bf(v.x); o.y=f2bf(v.y); o.z=f2bf(v.z); o.w=f2bf(v.w);
  *(u16x4*)(d + (long)row*512 + t*4) = o;
}

__global__ __launch_bounds__(256) void pos_k(unsigned short* __restrict__ d){
  const int r = blockIdx.x, t = threadIdx.x;
  const float seq = (float)(1023 - r);
  u16x4 o;
  #pragma unroll
  for (int q=0;q<4;q++){
    const int c = t*4 + q;
    const int f = (c < 512) ? c : (c - 512);
    const float inv = expf((float)f * -0.017988946039016f); // -2*ln(1e4)/1024
    const float ang = seq * inv;
    const float val = (c < 512) ? sinf(ang) : cosf(ang);
    o[q] = f2bf(val);
  }
  *(u16x4*)(d + (long)r*1024 + t*4) = o;
}

__global__ __launch_bounds__(256) void outT_k(const float* __restrict__ o,
                                              float* __restrict__ d){
  const int row = blockIdx.x;   // b*512 + i
  const int b = row>>9, i = row&511;
  const float4 v = ((const float4*)(o + ((long)i*8 + b)*1024))[threadIdx.x];
  ((float4*)(d + (long)row*1024))[threadIdx.x] = v;
}

// ---------------------------------------------------------------------------
extern "C" void kernel_launch(void* const* d_in, const int* in_sizes, int n_in,
                              void* d_out, int out_size, void* d_ws, size_t ws_size,
                              hipStream_t stream){
  (void)in_sizes; (void)n_in; (void)out_size;
  const float* h     = (const float*)d_in[0];
  const float* memin = (const float*)d_in[1];
  const float* Wemb  = (const float*)d_in[2];
  const float* bemb  = (const float*)d_in[3];
  const float* Ub    = (const float*)d_in[4];
  const float* Vb    = (const float*)d_in[5];
  const float* ln1   = (const float*)d_in[6];
  const float* ln2   = (const float*)d_in[7];
  const float* Wattn = (const float*)d_in[8];
  const float* g1w   = (const float*)d_in[9];
  const float* g2w   = (const float*)d_in[10];
  const float* fw1   = (const float*)d_in[11];
  const float* fb1   = (const float*)d_in[12];
  const float* fw2   = (const float*)d_in[13];
  const float* fb2   = (const float*)d_in[14];

  char* Wp = (char*)d_ws;
  size_t off = 0;
  auto take = [&](size_t bytes)->size_t{ size_t r = off; off += (bytes + 255) & ~(size_t)255; return r; };
  float*          outf = (float*)         (Wp + take(16777216)); // out (cur*bs, D) f32
  unsigned short* xbf  = (unsigned short*)(Wp + take( 8388608)); // out bf16
  float*          o1f  = (float*)         (Wp + take(16777216));
  unsigned short* o1b  = (unsigned short*)(Wp + take( 8388608));
  float*          zbf  = (float*)         (Wp + take(16777216)); // gru z
  float*          t1f  = (float*)         (Wp + take(16777216)); // gru pre-act scratch
  unsigned short* rxb  = (unsigned short*)(Wp + take( 8388608)); // r*x bf16
  unsigned short* yb   = (unsigned short*)(Wp + take( 8388608)); // Y / E2 bf16
  unsigned short* Eb   = (unsigned short*)(Wp + take( 8388608)); // LN2 out bf16
  unsigned short* wb0  = (unsigned short*)(Wp + take(52428800)); // layer weights bf16 (25M)
  unsigned short* hTb  = (unsigned short*)(Wp + take( 4194304));
  unsigned short* webb = (unsigned short*)(Wp + take( 1048576));
  unsigned short* posb = (unsigned short*)(Wp + take( 2097152));
  unsigned short* nkb  = (unsigned short*)(Wp + take(16777216)); // LN'd key (full*bs, D)
  unsigned short* qUb  = (unsigned short*)(Wp + take( 8388608));
  unsigned short* qVb  = (unsigned short*)(Wp + take( 8388608));
  unsigned short* khb  = (unsigned short*)(Wp + take(16777216));
  unsigned short* vhTb = (unsigned short*)(Wp + take(16777216));
  unsigned short* F1b  = khb; // FF hidden (32MB) overlaps kh+vhT (phase-disjoint)
  unsigned short* rhb  = (unsigned short*)(Wp + take( 2097152));
  unsigned short* ctxb = (unsigned short*)(Wp + take( 8388608));
  float* Sf = (float*)(Wp + off);                                // score chunk buffer
  const size_t avail = (ws_size > off) ? (ws_size - off) : 0;
  int spc = 1;  // (b,h) slices per chunk (power of 2, divides 128)
  while (spc < 128 && (size_t)(spc*2) * 2097152ull <= avail) spc <<= 1;
  const int nch = 128 / spc;

  const int M1 = 1048576; // D*D elements

  // one-time prep
  conv_k<<<512, 256, 0, stream>>>(Wemb, webb, 524288);
  ht_k<<<4096, 128, 0, stream>>>(h, hTb);
  pos_k<<<1024, 256, 0, stream>>>(posb);

  { // embed: out = gelu(h @ Wemb^T + bemb)  (f32 + bf16)
    GP p{}; p.A=hTb; p.B=webb; p.OF=outf; p.O1=xbf; p.bias1=bemb;
    p.K=512; p.lda=512; p.ldb=512; p.ldc=1024; p.ldo=1024;
    gemm_k<128,128,7><<<dim3(8,32,1),256,0,stream>>>(p);
  }

  auto gru_fn = [&](const unsigned short* xb, const float* xf, const unsigned short* yb_,
                    const unsigned short* w6, float* of, unsigned short* ob){
    { GP p{}; p.A=yb_; p.B=w6;        p.C=t1f; p.K=1024; p.lda=1024; p.ldb=1024; p.ldc=1024;
      gemm_k<128,128,0><<<dim3(8,32,1),256,0,stream>>>(p); }
    { GP p{}; p.A=xb;  p.B=w6+M1;     p.C=t1f; p.X=xf; p.O1=rxb;
      p.K=1024; p.lda=1024; p.ldb=1024; p.ldc=1024; p.ldo=1024;
      gemm_k<128,128,8><<<dim3(8,32,1),256,0,stream>>>(p); }
    { GP p{}; p.A=yb_; p.B=w6+2*M1;   p.C=zbf; p.K=1024; p.lda=1024; p.ldb=1024; p.ldc=1024;
      gemm_k<128,128,0><<<dim3(8,32,1),256,0,stream>>>(p); }
    { GP p{}; p.A=xb;  p.B=w6+3*M1;   p.C=zbf; p.K=1024; p.lda=1024; p.ldb=1024; p.ldc=1024;
      gemm_k<128,128,9><<<dim3(8,32,1),256,0,stream>>>(p); }
    { GP p{}; p.A=yb_; p.B=w6+4*M1;   p.C=t1f; p.K=1024; p.lda=1024; p.ldb=1024; p.ldc=1024;
      gemm_k<128,128,0><<<dim3(8,32,1),256,0,stream>>>(p); }
    { GP p{}; p.A=rxb; p.B=w6+5*M1;   p.C=t1f; p.X=xf; p.Z=zbf; p.OF=of; p.O1=ob;
      p.K=1024; p.lda=1024; p.ldb=1024; p.ldc=1024; p.ldo=1024;
      gemm_k<128,128,10><<<dim3(8,32,1),256,0,stream>>>(p); }
  };

  for (int l = 0; l < 4; ++l){
    // layer weights -> bf16
    conv_k<<<5120,256,0,stream>>>(Wattn + (long)l*5242880, wb0,          5242880);
    conv_k<<<6144,256,0,stream>>>(g1w   + (long)l*6291456, wb0 +  5*M1,  6291456);
    conv_k<<<6144,256,0,stream>>>(g2w   + (long)l*6291456, wb0 + 11*M1,  6291456);
    conv_k<<<4096,256,0,stream>>>(fw1   + (long)l*4194304, wb0 + 17*M1,  4194304);
    conv_k<<<4096,256,0,stream>>>(fw2   + (long)l*4194304, wb0 + 21*M1,  4194304);

    // nk = LN(concat(mem[l], out)); rows [4096:8192) are nq
    ln_k<<<8192,256,0,stream>>>(memin + (long)l*4194304, outf, 4096,
                                ln1 + l*2048, ln1 + l*2048 + 1024, nkb);

    { GP p{}; p.A=nkb+4194304; p.B=wb0; p.O1=qUb; p.O2=qVb; p.bias1=Ub; p.bias2=Vb;
      p.K=1024; p.lda=1024; p.ldb=1024; p.ldo=1024;
      gemm_k<128,128,2><<<dim3(8,32,1),256,0,stream>>>(p); }
    { GP p{}; p.A=nkb; p.B=wb0+M1; p.O1=khb; p.K=1024; p.lda=1024; p.ldb=1024; p.ldo=1024;
      gemm_k<128,128,1><<<dim3(8,64,1),256,0,stream>>>(p); }
    { GP p{}; p.A=nkb; p.B=wb0+2*M1; p.O1=vhTb; p.K=1024; p.lda=1024; p.ldb=1024;
      gemm_k<128,128,3><<<dim3(8,64,1),256,0,stream>>>(p); }
    { GP p{}; p.A=posb; p.B=wb0+3*M1; p.O1=rhb; p.K=1024; p.lda=1024; p.ldb=1024; p.ldo=1024;
      gemm_k<128,128,1><<<dim3(8,8,1),256,0,stream>>>(p); }

    for (int c = 0; c < nch; ++c){
      const int bh0 = c*spc;
      { // BD: pre[i,r] = (qh+V).rh, scattered to j = r+i-511
        GP p{}; p.A=qVb; p.B=rhb; p.C=Sf; p.bh0=bh0; p.K=64;
        p.lda=8192; p.ldb=1024; p.ldc=1024; p.sAb=1024; p.sAh=64; p.sBh=64; p.sCz=524288;
        gemm_k<128,128,4><<<dim3(8,4,spc),256,0,stream>>>(p); }
      { // AC accumulate + scale + mask
        GP p{}; p.A=qUb; p.B=khb; p.C=Sf; p.bh0=bh0; p.K=64;
        p.lda=8192; p.ldb=8192; p.ldc=1024; p.sAb=1024; p.sAh=64; p.sBb=1024; p.sBh=64; p.sCz=524288;
        gemm_k<128,128,5><<<dim3(8,4,spc),256,0,stream>>>(p); }
      softmax_k<<<spc*512,256,0,stream>>>(Sf);
      { // PV: ctx[i, h*64+d] = P @ vhT^T
        GP p{}; p.A=(const unsigned short*)Sf; p.B=vhTb; p.O1=ctxb; p.bh0=bh0; p.K=1024;
        p.lda=2048; p.ldb=1024; p.ldo=8192;
        p.sAz=1048576; p.sBb=1048576; p.sBh=65536; p.sOb=1024; p.sOh=64;
        gemm_k<128,64,1><<<dim3(1,4,spc),256,0,stream>>>(p); }
    }

    { // Y = gelu(ctx @ Wo^T)
      GP p{}; p.A=ctxb; p.B=wb0+4*M1; p.O1=yb; p.K=1024; p.lda=1024; p.ldb=1024; p.ldo=1024;
      gemm_k<128,128,6><<<dim3(8,32,1),256,0,stream>>>(p); }

    gru_fn(xbf, outf, yb, wb0 + 5*M1, o1f, o1b);

    ln_k<<<4096,256,0,stream>>>(o1f, nullptr, 1<<30,
                                ln2 + l*2048, ln2 + l*2048 + 1024, Eb);

    { GP p{}; p.A=Eb;  p.B=wb0+17*M1; p.O1=F1b; p.bias1=fb1 + l*4096;
      p.K=1024; p.lda=1024; p.ldb=1024; p.ldo=4096;
      gemm_k<128,128,6><<<dim3(32,32,1),256,0,stream>>>(p); }
    { GP p{}; p.A=F1b; p.B=wb0+21*M1; p.O1=yb; p.bias1=fb2 + l*1024;
      p.K=4096; p.lda=4096; p.ldb=4096; p.ldo=1024;
      gemm_k<128,128,6><<<dim3(8,32,1),256,0,stream>>>(p); }

    gru_fn(o1b, o1f, yb, wb0 + 11*M1, outf, xbf);
  }

  outT_k<<<4096,256,0,stream>>>(outf, (float*)d_out);
}

// Round 2
// 3281.138 us; speedup vs baseline: 1.6680x; 1.6680x over previous
//
#include <hip/hip_runtime.h>
#include <hip/hip_bf16.h>

// Gated Transformer-XL forward.
// Dims: L=4, D=1024, NH=16, HD=64, CUR=512, MEM=512, BS=8, IN=512, FF=4096, FULL=1024
// Activation layout: (seq*BS, D), row = i*BS + b.

typedef __attribute__((ext_vector_type(8))) __bf16 bfrag;
typedef __attribute__((ext_vector_type(4))) float f4;
typedef __attribute__((ext_vector_type(4))) unsigned short u16x4;
typedef __attribute__((ext_vector_type(8))) unsigned short u16x8;

__device__ __forceinline__ unsigned short f2bf(float f){
  union { float f; unsigned u; } v; v.f = f;
  unsigned r = v.u + 0x7fffu + ((v.u >> 16) & 1u);
  return (unsigned short)(r >> 16);
}
__device__ __forceinline__ float bf2f(unsigned short u){
  union { unsigned u; float f; } v; v.u = (unsigned)u << 16; return v.f;
}
__device__ __forceinline__ float geluf(float x){
  return 0.5f * x * (1.0f + erff(x * 0.7071067811865476f));
}
__device__ __forceinline__ float sigm(float x){ return 1.0f/(1.0f + __expf(-x)); }

__device__ __forceinline__ void gl_lds(const void* g, void* l){
  __builtin_amdgcn_global_load_lds(
    reinterpret_cast<const __attribute__((address_space(1))) unsigned int*>(
        reinterpret_cast<unsigned long>(g)),
    reinterpret_cast<__attribute__((address_space(3))) unsigned int*>(
        reinterpret_cast<unsigned long>(l)),
    16, 0, 0);
}

// ---------------------------------------------------------------------------
// Dense GEMM: C[M,N] = A[M,K] @ B[N,K]^T (bf16, row-major). Optional K-concat:
// k >= Ksplit reads A2/B2 (so r = sigma([y|x]@[W|U]^T) needs one launch).
// EPI: 6  O1 = bf(gelu(acc + bias1))
//      7  OF = gelu(acc+bias1) f32, O1 = bf16 of same          (embed)
//      11 z==0: O1 = bf(sigm(acc) * X)   (GRU r-gate * x)
//         z==1: OF = sigm(acc - 2)       (GRU z-gate)
//      12 o = (1-Z)*X + Z*tanh(acc); OF = o; O1 = bf(o)        (GRU combine)
//      13 fused QKV+R: z=0 kh, z=1 vhT-scatter, z=2 qU/qV(+bias), z=3 rh
// ---------------------------------------------------------------------------
struct GP {
  const unsigned short* A;
  const unsigned short* A2;
  const unsigned short* B;
  const unsigned short* B2;
  unsigned short* O1;
  unsigned short* O2;
  unsigned short* O3;
  unsigned short* O4;
  unsigned short* O5;
  float* OF;
  const float* bias1;
  const float* bias2;
  const float* X;
  const float* Z;
  int K, Ksplit, lda, ldb, ldo;
  int sBz;
};

template<int BM, int BN, int EPI>
__global__ __launch_bounds__(256) void gemm_k(GP p){
  __shared__ unsigned short As[BM*32];
  __shared__ unsigned short Bs[BN*32];
  const int tid  = threadIdx.x;
  const int lane = tid & 63;
  const int wid  = tid >> 6;
  const int lr   = lane & 15;
  const int lg   = lane >> 4;
  constexpr int FM = BM/32, FN = BN/32;
  const int m0 = blockIdx.y * BM;
  const int n0 = blockIdx.x * BN;
  const int z  = blockIdx.z;

  const unsigned short* Abase = p.A;
  const unsigned short* Bbase = p.B;
  if constexpr (EPI==13){
    if (z==2){ if (blockIdx.y >= 32) return; Abase = p.A + 4194304; }
    if (z==3){ if (blockIdx.y >= 8)  return; Abase = p.A2; }
    const int zsel = (z==0)?1:((z==1)?2:((z==2)?0:3));
    Bbase = p.B + (long)zsel*1048576;
  }

  const int ksp = p.Ksplit ? p.Ksplit : p.K;
  const unsigned short* AbL = Abase + (long)m0*p.lda;
  const unsigned short* AbH = p.A2 && EPI!=13 ? (p.A2 + (long)m0*p.lda - ksp) : AbL;
  const unsigned short* BbL = Bbase + (long)z*p.sBz + (long)n0*p.ldb;
  const unsigned short* BbH = p.B2 ? (p.B2 + (long)z*p.sBz + (long)n0*p.ldb - ksp) : BbL;

  const int srow = tid >> 2;          // 0..63
  const int skk  = (tid & 3) * 8;

  f4 acc[FM][FN];
  f4 zero4 = {0.0f, 0.0f, 0.0f, 0.0f};
  #pragma unroll
  for (int m=0;m<FM;m++)
    #pragma unroll
    for (int n=0;n<FN;n++) acc[m][n] = zero4;

  for (int k0 = 0; k0 < p.K; k0 += 32){
    const unsigned short* A_ = (k0 < ksp) ? AbL : AbH;
    const unsigned short* B_ = (k0 < ksp) ? BbL : BbH;
    #pragma unroll
    for (int q=0;q<BM/64;q++)
      gl_lds(A_ + (long)(q*64 + srow)*p.lda + k0 + skk, (char*)As + q*4096 + wid*1024);
    #pragma unroll
    for (int q=0;q<BN/64;q++)
      gl_lds(B_ + (long)(q*64 + srow)*p.ldb + k0 + skk, (char*)Bs + q*4096 + wid*1024);
    __syncthreads();
    bfrag af[FM], bfr[FN];
    #pragma unroll
    for (int m=0;m<FM;m++)
      af[m] = *(const bfrag*)&As[((wid>>1)*(BM/2) + m*16 + lr)*32 + lg*8];
    #pragma unroll
    for (int n=0;n<FN;n++)
      bfr[n] = *(const bfrag*)&Bs[((wid&1)*(BN/2) + n*16 + lr)*32 + lg*8];
    #pragma unroll
    for (int m=0;m<FM;m++)
      #pragma unroll
      for (int n=0;n<FN;n++)
        acc[m][n] = __builtin_amdgcn_mfma_f32_16x16x32_bf16(af[m], bfr[n], acc[m][n], 0, 0, 0);
    __syncthreads();
  }

  const int wr0 = m0 + (wid>>1)*(BM/2);
  const int wc0 = n0 + (wid&1)*(BN/2);
  #pragma unroll
  for (int m=0;m<FM;m++)
    #pragma unroll
    for (int n=0;n<FN;n++)
      #pragma unroll
      for (int r=0;r<4;r++){
        const int gr = wr0 + m*16 + lg*4 + r;
        const int gc = wc0 + n*16 + lr;
        const float a = acc[m][n][r];
        const long base = (long)gr*p.ldo + gc;
        if constexpr (EPI==6){
          const float t = a + (p.bias1 ? p.bias1[gc] : 0.0f);
          p.O1[base] = f2bf(geluf(t));
        }
        else if constexpr (EPI==7){
          const float t = geluf(a + p.bias1[gc]);
          p.OF[base] = t; p.O1[base] = f2bf(t);
        }
        else if constexpr (EPI==11){
          const long ix = (long)gr*1024 + gc;
          if (z==0) p.O1[ix] = f2bf(sigm(a) * p.X[ix]);
          else      p.OF[ix] = sigm(a - 2.0f);
        }
        else if constexpr (EPI==12){
          const long ix = (long)gr*1024 + gc;
          const float zz = p.Z[ix];
          const float oo = (1.0f - zz)*p.X[ix] + zz*tanhf(a);
          p.OF[ix] = oo; p.O1[ix] = f2bf(oo);
        }
        else if constexpr (EPI==13){
          const long ix = (long)gr*1024 + gc;
          if (z==0){ p.O1[ix] = f2bf(a); }
          else if (z==1){
            const int b_ = gr & 7, js = gr >> 3, h_ = gc >> 6, d_ = gc & 63;
            p.O2[(long)(b_*16 + h_)*65536 + (long)d_*1024 + js] = f2bf(a);
          }
          else if (z==2){ p.O3[ix] = f2bf(a + p.bias1[gc]); p.O4[ix] = f2bf(a + p.bias2[gc]); }
          else { p.O5[ix] = f2bf(a); }
        }
      }
}

// ---------------------------------------------------------------------------
// Fused relative attention: per block = one (b,h) and 32 query rows.
//   phase1: BDpre = qV @ rh^T over all r (waves split cols), scatter bf16 into
//           LDS at shifted col j = r + i - 511 (XOR-swizzled rows).
//   phase2: AC = qU @ kh^T; S = (AC + BD)/8 masked; full-row softmax via
//           shfl + LDS cross-wave reduce; P (unnormalized, bf16) -> same LDS.
//   phase3: PV with waves splitting K; cross-wave f32 reduce; /denom; -> ctx.
// ---------------------------------------------------------------------------
__global__ __launch_bounds__(256) void attn_k(const unsigned short* __restrict__ qU,
                                              const unsigned short* __restrict__ qV,
                                              const unsigned short* __restrict__ kh,
                                              const unsigned short* __restrict__ rh,
                                              const unsigned short* __restrict__ vhT,
                                              unsigned short* __restrict__ ctx){
  __shared__ unsigned short S[32*1024];   // 64KB: scores / P / (reuse) partial out
  __shared__ float redm[4][32];
  __shared__ float reds[4][32];
  __shared__ float invd[32];
  const int tid = threadIdx.x;
  const int w   = tid >> 6;
  const int lane= tid & 63;
  const int lr  = lane & 15;
  const int lg  = lane >> 4;
  // XCD-aware mapping: same (b,h) tiles colocate on one XCD for kh/rh/vhT L2 reuse
  const int id = blockIdx.x;
  const int b  = id & 7;
  const int k5 = id >> 3;        // 0..255
  const int h  = k5 >> 4;        // 0..15
  const int i0 = (k5 & 15) * 32;
  const long qoff = (long)h*64;

  f4 acc[2][16];
  const f4 z4 = {0.f,0.f,0.f,0.f};
  bfrag av[2][2];

  // ---------------- phase 1: BDpre + shifted scatter ----------------
  #pragma unroll
  for (int m=0;m<2;m++)
    #pragma unroll
    for (int kk=0;kk<2;kk++)
      av[m][kk] = *(const bfrag*)(qV + ((long)(i0 + m*16 + lr)*8 + b)*1024 + qoff + kk*32 + lg*8);
  #pragma unroll
  for (int m=0;m<2;m++)
    #pragma unroll
    for (int n=0;n<16;n++) acc[m][n] = z4;
  #pragma unroll
  for (int n=0;n<16;n++){
    const long r = w*256 + n*16 + lr;
    bfrag b0 = *(const bfrag*)(rh + r*1024 + qoff + lg*8);
    bfrag b1 = *(const bfrag*)(rh + r*1024 + qoff + 32 + lg*8);
    #pragma unroll
    for (int m=0;m<2;m++){
      acc[m][n] = __builtin_amdgcn_mfma_f32_16x16x32_bf16(av[m][0], b0, acc[m][n],0,0,0);
      acc[m][n] = __builtin_amdgcn_mfma_f32_16x16x32_bf16(av[m][1], b1, acc[m][n],0,0,0);
    }
  }
  #pragma unroll
  for (int m=0;m<2;m++)
    #pragma unroll
    for (int n=0;n<16;n++)
      #pragma unroll
      for (int r4=0;r4<4;r4++){
        const int di = m*16 + lg*4 + r4;
        const int j  = (w*256 + n*16 + lr) + i0 + di - 511;
        if (j >= 0 && j < 1024){
          const int byte = di*2048 + (((j*2) ^ ((di&7)<<4)));
          *(unsigned short*)((char*)S + byte) = f2bf(acc[m][n][r4]);
        }
      }
  __syncthreads();

  // ---------------- phase 2: AC + BD + mask, softmax ----------------
  #pragma unroll
  for (int m=0;m<2;m++)
    #pragma unroll
    for (int kk=0;kk<2;kk++)
      av[m][kk] = *(const bfrag*)(qU + ((long)(i0 + m*16 + lr)*8 + b)*1024 + qoff + kk*32 + lg*8);
  #pragma unroll
  for (int m=0;m<2;m++)
    #pragma unroll
    for (int n=0;n<16;n++) acc[m][n] = z4;
  #pragma unroll
  for (int n=0;n<16;n++){
    const long j = w*256 + n*16 + lr;
    bfrag b0 = *(const bfrag*)(kh + (j*8 + b)*1024 + qoff + lg*8);
    bfrag b1 = *(const bfrag*)(kh + (j*8 + b)*1024 + qoff + 32 + lg*8);
    #pragma unroll
    for (int m=0;m<2;m++){
      acc[m][n] = __builtin_amdgcn_mfma_f32_16x16x32_bf16(av[m][0], b0, acc[m][n],0,0,0);
      acc[m][n] = __builtin_amdgcn_mfma_f32_16x16x32_bf16(av[m][1], b1, acc[m][n],0,0,0);
    }
  }
  float mx[2][4];
  #pragma unroll
  for (int m=0;m<2;m++)
    #pragma unroll
    for (int r4=0;r4<4;r4++) mx[m][r4] = -3.0e38f;
  #pragma unroll
  for (int m=0;m<2;m++)
    #pragma unroll
    for (int n=0;n<16;n++)
      #pragma unroll
      for (int r4=0;r4<4;r4++){
        const int di = m*16 + lg*4 + r4;
        const int jc = w*256 + n*16 + lr;
        const int byte = di*2048 + (((jc*2) ^ ((di&7)<<4)));
        const float bd = bf2f(*(const unsigned short*)((char*)S + byte));
        float s = (acc[m][n][r4] + bd) * 0.125f;
        s = (jc > i0 + di + 512) ? -1e30f : s;
        acc[m][n][r4] = s;
        mx[m][r4] = fmaxf(mx[m][r4], s);
      }
  #pragma unroll
  for (int m=0;m<2;m++)
    #pragma unroll
    for (int r4=0;r4<4;r4++){
      float v = mx[m][r4];
      v = fmaxf(v, __shfl_xor(v, 1));
      v = fmaxf(v, __shfl_xor(v, 2));
      v = fmaxf(v, __shfl_xor(v, 4));
      v = fmaxf(v, __shfl_xor(v, 8));
      if (lr == 0) redm[w][m*16 + lg*4 + r4] = v;
    }
  __syncthreads();
  float sm[2][4];
  #pragma unroll
  for (int m=0;m<2;m++)
    #pragma unroll
    for (int r4=0;r4<4;r4++){
      const int row = m*16 + lg*4 + r4;
      mx[m][r4] = fmaxf(fmaxf(redm[0][row], redm[1][row]), fmaxf(redm[2][row], redm[3][row]));
      sm[m][r4] = 0.0f;
    }
  #pragma unroll
  for (int m=0;m<2;m++)
    #pragma unroll
    for (int n=0;n<16;n++)
      #pragma unroll
      for (int r4=0;r4<4;r4++){
        const int di = m*16 + lg*4 + r4;
        const int jc = w*256 + n*16 + lr;
        const float e = __expf(acc[m][n][r4] - mx[m][r4]);
        sm[m][r4] += e;
        const int byte = di*2048 + (((jc*2) ^ ((di&7)<<4)));
        *(unsigned short*)((char*)S + byte) = f2bf(e);
      }
  #pragma unroll
  for (int m=0;m<2;m++)
    #pragma unroll
    for (int r4=0;r4<4;r4++){
      float v = sm[m][r4];
      v += __shfl_xor(v, 1);
      v += __shfl_xor(v, 2);
      v += __shfl_xor(v, 4);
      v += __shfl_xor(v, 8);
      if (lr == 0) reds[w][m*16 + lg*4 + r4] = v;
    }
  __syncthreads();
  if (tid < 32)
    invd[tid] = 1.0f / (reds[0][tid] + reds[1][tid] + reds[2][tid] + reds[3][tid]);

  // ---------------- phase 3: PV (waves split K) ----------------
  f4 oac[2][4];
  #pragma unroll
  for (int m=0;m<2;m++)
    #pragma unroll
    for (int nd=0;nd<4;nd++) oac[m][nd] = z4;
  const unsigned short* vb_base = vhT + (long)(b*16 + h)*65536;
  #pragma unroll
  for (int jt=0;jt<8;jt++){
    const int jb = w*256 + jt*32;
    bfrag pa[2], vb[4];
    #pragma unroll
    for (int m=0;m<2;m++){
      const int row = m*16 + lr;
      const int cb  = ((jb + lg*8)*2) ^ ((row&7)<<4);
      pa[m] = *(const bfrag*)((char*)S + row*2048 + cb);
    }
    #pragma unroll
    for (int nd=0;nd<4;nd++)
      vb[nd] = *(const bfrag*)(vb_base + (long)(nd*16 + lr)*1024 + jb + lg*8);
    #pragma unroll
    for (int m=0;m<2;m++)
      #pragma unroll
      for (int nd=0;nd<4;nd++)
        oac[m][nd] = __builtin_amdgcn_mfma_f32_16x16x32_bf16(pa[m], vb[nd], oac[m][nd],0,0,0);
  }
  __syncthreads();
  float* po = (float*)S;
  #pragma unroll
  for (int m=0;m<2;m++)
    #pragma unroll
    for (int nd=0;nd<4;nd++)
      #pragma unroll
      for (int r4=0;r4<4;r4++)
        po[w*2048 + (m*16 + lg*4 + r4)*64 + nd*16 + lr] = oac[m][nd][r4];
  __syncthreads();
  {
    const int e0 = tid*8;
    const int row = e0 >> 6;
    const int d0 = e0 & 63;
    float s[8];
    #pragma unroll
    for (int q=0;q<8;q++) s[q] = po[e0 + q];
    #pragma unroll
    for (int ww=1;ww<4;ww++)
      #pragma unroll
      for (int q=0;q<8;q++) s[q] += po[ww*2048 + e0 + q];
    const float inv = invd[row];
    u16x8 o;
    #pragma unroll
    for (int q=0;q<8;q++) o[q] = f2bf(s[q]*inv);
    *(u16x8*)(ctx + ((long)(i0 + row)*8 + b)*1024 + qoff + d0) = o;
  }
}

// ---------------------------------------------------------------------------
__global__ __launch_bounds__(256) void ln_k(const float* __restrict__ srcA,
                                            const float* __restrict__ srcB, int splitRow,
                                            const float* __restrict__ g, const float* __restrict__ b,
                                            unsigned short* __restrict__ dst){
  const int row = blockIdx.x;
  const float* src = (srcB != nullptr && row >= splitRow)
                       ? (srcB + (long)(row - splitRow)*1024)
                       : (srcA + (long)row*1024);
  const int t = threadIdx.x;
  float4 v = ((const float4*)src)[t];
  float s1 = v.x+v.y+v.z+v.w;
  float s2 = v.x*v.x+v.y*v.y+v.z*v.z+v.w*v.w;
  #pragma unroll
  for (int o=32;o;o>>=1){ s1 += __shfl_xor(s1,o); s2 += __shfl_xor(s2,o); }
  __shared__ float r1[4], r2[4];
  const int w = t>>6;
  if ((t&63)==0){ r1[w]=s1; r2[w]=s2; }
  __syncthreads();
  s1 = r1[0]+r1[1]+r1[2]+r1[3];
  s2 = r2[0]+r2[1]+r2[2]+r2[3];
  const float mean = s1*(1.0f/1024.0f);
  const float var  = s2*(1.0f/1024.0f) - mean*mean;
  const float rs   = rsqrtf(var + 1e-5f);
  float4 gg = ((const float4*)g)[t];
  float4 bb = ((const float4*)b)[t];
  u16x4 o;
  o.x = f2bf((v.x-mean)*rs*gg.x + bb.x);
  o.y = f2bf((v.y-mean)*rs*gg.y + bb.y);
  o.z = f2bf((v.z-mean)*rs*gg.z + bb.z);
  o.w = f2bf((v.w-mean)*rs*gg.w + bb.w);
  *(u16x4*)(dst + (long)row*1024 + t*4) = o;
}

__global__ __launch_bounds__(256) void conv_k(const float* __restrict__ s,
                                              unsigned short* __restrict__ d, long n){
  long i = ((long)blockIdx.x*256 + threadIdx.x)*4;
  if (i >= n) return;
  float4 v = *(const float4*)(s + i);
  u16x4 o; o.x=f2bf(v.x); o.y=f2bf(v.y); o.z=f2bf(v.z); o.w=f2bf(v.w);
  *(u16x4*)(d + i) = o;
}

__global__ __launch_bounds__(128) void ht_k(const float* __restrict__ h,
                                            unsigned short* __restrict__ d){
  const int row = blockIdx.x;           // i*8+b
  const int i = row>>3, b = row&7;
  const float* src = h + ((long)b*512 + i)*512;
  const int t = threadIdx.x;
  float4 v = ((const float4*)src)[t];
  u16x4 o; o.x=f2bf(v.x); o.y=f2bf(v.y); o.z=f2bf(v.z); o.w=f2bf(v.w);
  *(u16x4*)(d + (long)row*512 + t*4) = o;
}

__global__ __launch_bounds__(256) void pos_k(unsigned short* __restrict__ d){
  const int r = blockIdx.x, t = threadIdx.x;
  const float seq = (float)(1023 - r);
  u16x4 o;
  #pragma unroll
  for (int q=0;q<4;q++){
    const int c = t*4 + q;
    const int f = (c < 512) ? c : (c - 512);
    const float inv = expf((float)f * -0.017988946039016f); // -2*ln(1e4)/1024
    const float ang = seq * inv;
    const float val = (c < 512) ? sinf(ang) : cosf(ang);
    o[q] = f2bf(val);
  }
  *(u16x4*)(d + (long)r*1024 + t*4) = o;
}

__global__ __launch_bounds__(256) void outT_k(const float* __restrict__ o,
                                              float* __restrict__ d){
  const int row = blockIdx.x;   // b*512 + i
  const int b = row>>9, i = row&511;
  const float4 v = ((const float4*)(o + ((long)i*8 + b)*1024))[threadIdx.x];
  ((float4*)(d + (long)row*1024))[threadIdx.x] = v;
}

// ---------------------------------------------------------------------------
extern "C" void kernel_launch(void* const* d_in, const int* in_sizes, int n_in,
                              void* d_out, int out_size, void* d_ws, size_t ws_size,
                              hipStream_t stream){
  (void)in_sizes; (void)n_in; (void)out_size; (void)ws_size;
  const float* h     = (const float*)d_in[0];
  const float* memin = (const float*)d_in[1];
  const float* Wemb  = (const float*)d_in[2];
  const float* bemb  = (const float*)d_in[3];
  const float* Ub    = (const float*)d_in[4];
  const float* Vb    = (const float*)d_in[5];
  const float* ln1   = (const float*)d_in[6];
  const float* ln2   = (const float*)d_in[7];
  const float* Wattn = (const float*)d_in[8];
  const float* g1w   = (const float*)d_in[9];
  const float* g2w   = (const float*)d_in[10];
  const float* fw1   = (const float*)d_in[11];
  const float* fb1   = (const float*)d_in[12];
  const float* fw2   = (const float*)d_in[13];
  const float* fb2   = (const float*)d_in[14];

  char* Wp = (char*)d_ws;
  size_t off = 0;
  auto take = [&](size_t bytes)->size_t{ size_t r = off; off += (bytes + 255) & ~(size_t)255; return r; };
  float*          outf = (float*)         (Wp + take(16777216)); // out (cur*bs, D) f32
  unsigned short* xbf  = (unsigned short*)(Wp + take( 8388608)); // out bf16
  float*          o1f  = (float*)         (Wp + take(16777216));
  unsigned short* o1b  = (unsigned short*)(Wp + take( 8388608));
  float*          zbf  = (float*)         (Wp + take(16777216)); // gru z-gate f32
  unsigned short* rxb  = (unsigned short*)(Wp + take( 8388608)); // r*x bf16
  unsigned short* yb   = (unsigned short*)(Wp + take( 8388608)); // Y / E2 bf16
  unsigned short* Eb   = (unsigned short*)(Wp + take( 8388608)); // LN2 out bf16
  unsigned short* wb0  = (unsigned short*)(Wp + take(52428800)); // layer weights bf16
  unsigned short* hTb  = (unsigned short*)(Wp + take( 4194304));
  unsigned short* webb = (unsigned short*)(Wp + take( 1048576));
  unsigned short* posb = (unsigned short*)(Wp + take( 2097152));
  unsigned short* nkb  = (unsigned short*)(Wp + take(16777216)); // LN'd key (full*bs, D)
  unsigned short* qUb  = (unsigned short*)(Wp + take( 8388608));
  unsigned short* qVb  = (unsigned short*)(Wp + take( 8388608));
  unsigned short* khb  = (unsigned short*)(Wp + take(16777216));
  unsigned short* vhTb = (unsigned short*)(Wp + take(16777216));
  unsigned short* F1b  = khb; // FF hidden (32MB) overlaps khb+vhTb (phase-disjoint)
  unsigned short* rhb  = (unsigned short*)(Wp + take( 2097152));
  unsigned short* ctxb = (unsigned short*)(Wp + take( 8388608));

  const int M1 = 1048576; // D*D elements

  // one-time prep
  conv_k<<<512, 256, 0, stream>>>(Wemb, webb, 524288);
  ht_k<<<4096, 128, 0, stream>>>(h, hTb);
  pos_k<<<1024, 256, 0, stream>>>(posb);

  { // embed: out = gelu(h @ Wemb^T + bemb)  (f32 + bf16)
    GP p{}; p.A=hTb; p.B=webb; p.OF=outf; p.O1=xbf; p.bias1=bemb;
    p.K=512; p.lda=512; p.ldb=512; p.ldo=1024;
    gemm_k<128,128,7><<<dim3(8,32,1),256,0,stream>>>(p);
  }

  // GRU (2 launches, K=2048 concat): x=xb/xf, y=yb_, weights w6 = [Wr,Ur,Wz,Uz,Wg,Ug]
  auto gru_fn = [&](const unsigned short* xb, const float* xf, const unsigned short* yb_,
                    const unsigned short* w6, float* of, unsigned short* ob){
    { GP p{}; p.A=yb_; p.A2=xb; p.B=w6; p.B2=w6+M1; p.sBz=2*M1;
      p.O1=rxb; p.OF=zbf; p.X=xf;
      p.K=2048; p.Ksplit=1024; p.lda=1024; p.ldb=1024; p.ldo=1024;
      gemm_k<128,128,11><<<dim3(8,32,2),256,0,stream>>>(p); }
    { GP p{}; p.A=yb_; p.A2=rxb; p.B=w6+4*M1; p.B2=w6+5*M1;
      p.X=xf; p.Z=zbf; p.OF=of; p.O1=ob;
      p.K=2048; p.Ksplit=1024; p.lda=1024; p.ldb=1024; p.ldo=1024;
      gemm_k<128,64,12><<<dim3(16,32,1),256,0,stream>>>(p); }
  };

  for (int l = 0; l < 4; ++l){
    // layer weights -> bf16
    conv_k<<<5120,256,0,stream>>>(Wattn + (long)l*5242880, wb0,          5242880);
    conv_k<<<6144,256,0,stream>>>(g1w   + (long)l*6291456, wb0 +  5*M1,  6291456);
    conv_k<<<6144,256,0,stream>>>(g2w   + (long)l*6291456, wb0 + 11*M1,  6291456);
    conv_k<<<4096,256,0,stream>>>(fw1   + (long)l*4194304, wb0 + 17*M1,  4194304);
    conv_k<<<4096,256,0,stream>>>(fw2   + (long)l*4194304, wb0 + 21*M1,  4194304);

    // nk = LN(concat(mem[l], out)); rows [4096:8192) are nq
    ln_k<<<8192,256,0,stream>>>(memin + (long)l*4194304, outf, 4096,
                                ln1 + l*2048, ln1 + l*2048 + 1024, nkb);

    { // fused QKV + R: z=0 kh, z=1 vhT, z=2 qU/qV, z=3 rh
      GP p{}; p.A=nkb; p.A2=posb; p.B=wb0;
      p.O1=khb; p.O2=vhTb; p.O3=qUb; p.O4=qVb; p.O5=rhb;
      p.bias1=Ub; p.bias2=Vb;
      p.K=1024; p.lda=1024; p.ldb=1024; p.ldo=1024;
      gemm_k<128,128,13><<<dim3(8,64,4),256,0,stream>>>(p); }

    attn_k<<<2048,256,0,stream>>>(qUb, qVb, khb, rhb, vhTb, ctxb);

    { // Y = gelu(ctx @ Wo^T)
      GP p{}; p.A=ctxb; p.B=wb0+4*M1; p.O1=yb;
      p.K=1024; p.lda=1024; p.ldb=1024; p.ldo=1024;
      gemm_k<128,64,6><<<dim3(16,32,1),256,0,stream>>>(p); }

    gru_fn(xbf, outf, yb, wb0 + 5*M1, o1f, o1b);

    ln_k<<<4096,256,0,stream>>>(o1f, nullptr, 1<<30,
                                ln2 + l*2048, ln2 + l*2048 + 1024, Eb);

    { GP p{}; p.A=Eb;  p.B=wb0+17*M1; p.O1=F1b; p.bias1=fb1 + l*4096;
      p.K=1024; p.lda=1024; p.ldb=1024; p.ldo=4096;
      gemm_k<128,128,6><<<dim3(32,32,1),256,0,stream>>>(p); }
    { GP p{}; p.A=F1b; p.B=wb0+21*M1; p.O1=yb; p.bias1=fb2 + l*1024;
      p.K=4096; p.lda=4096; p.ldb=4096; p.ldo=1024;
      gemm_k<128,64,6><<<dim3(16,32,1),256,0,stream>>>(p); }

    gru_fn(o1b, o1f, yb, wb0 + 11*M1, outf, xbf);
  }

  outT_k<<<4096,256,0,stream>>>(outf, (float*)d_out);
}

// Round 3
// 3082.956 us; speedup vs baseline: 1.7752x; 1.0643x over previous
//
#include <hip/hip_runtime.h>
#include <hip/hip_bf16.h>

// Gated Transformer-XL forward.
// Dims: L=4, D=1024, NH=16, HD=64, CUR=512, MEM=512, BS=8, IN=512, FF=4096, FULL=1024
// Activation layout: (seq*BS, D), row = i*BS + b.

typedef __attribute__((ext_vector_type(8))) __bf16 bfrag;
typedef __attribute__((ext_vector_type(4))) float f4;
typedef __attribute__((ext_vector_type(4))) unsigned short u16x4;
typedef __attribute__((ext_vector_type(8))) unsigned short u16x8;

__device__ __forceinline__ unsigned short f2bf(float f){
  union { float f; unsigned u; } v; v.f = f;
  unsigned r = v.u + 0x7fffu + ((v.u >> 16) & 1u);
  return (unsigned short)(r >> 16);
}
__device__ __forceinline__ float bf2f(unsigned short u){
  union { unsigned u; float f; } v; v.u = (unsigned)u << 16; return v.f;
}
__device__ __forceinline__ float geluf(float x){
  return 0.5f * x * (1.0f + erff(x * 0.7071067811865476f));
}
__device__ __forceinline__ float sigm(float x){ return 1.0f/(1.0f + __expf(-x)); }

__device__ __forceinline__ void gl_lds(const void* g, void* l){
  __builtin_amdgcn_global_load_lds(
    reinterpret_cast<const __attribute__((address_space(1))) unsigned int*>(
        reinterpret_cast<unsigned long>(g)),
    reinterpret_cast<__attribute__((address_space(3))) unsigned int*>(
        reinterpret_cast<unsigned long>(l)),
    16, 0, 0);
}

// ---------------------------------------------------------------------------
// Dense GEMM: C[M,N] = A[M,K] @ B[N,K]^T (bf16, row-major). Optional K-concat.
// EPI: 6  O1 = bf(gelu(acc + bias1))
//      7  OF = gelu(acc+bias1) f32, O1 = bf16 of same          (embed)
//      11 z==0: O1 = bf(sigm(acc) * X)   (GRU r-gate * x)
//         z==1: OF = sigm(acc - 2)       (GRU z-gate)
//      12 o = (1-Z)*X + Z*tanh(acc); OF = o; O1 = bf(o)        (GRU combine)
//      13 fused QKV+R: z=0 kh, z=1 vhT-scatter, z=2 qU/qV(+bias, *0.125), z=3 rh
// ---------------------------------------------------------------------------
struct GP {
  const unsigned short* A;
  const unsigned short* A2;
  const unsigned short* B;
  const unsigned short* B2;
  unsigned short* O1;
  unsigned short* O2;
  unsigned short* O3;
  unsigned short* O4;
  unsigned short* O5;
  float* OF;
  const float* bias1;
  const float* bias2;
  const float* X;
  const float* Z;
  int K, Ksplit, lda, ldb, ldo;
  int sBz;
};

template<int BM, int BN, int EPI>
__global__ __launch_bounds__(256) void gemm_k(GP p){
  __shared__ unsigned short As[BM*32];
  __shared__ unsigned short Bs[BN*32];
  const int tid  = threadIdx.x;
  const int lane = tid & 63;
  const int wid  = tid >> 6;
  const int lr   = lane & 15;
  const int lg   = lane >> 4;
  constexpr int FM = BM/32, FN = BN/32;
  const int m0 = blockIdx.y * BM;
  const int n0 = blockIdx.x * BN;
  const int z  = blockIdx.z;

  const unsigned short* Abase = p.A;
  const unsigned short* Bbase = p.B;
  if constexpr (EPI==13){
    if (z==2){ if (blockIdx.y >= 32) return; Abase = p.A + 4194304; }
    if (z==3){ if (blockIdx.y >= 8)  return; Abase = p.A2; }
    const int zsel = (z==0)?1:((z==1)?2:((z==2)?0:3));
    Bbase = p.B + (long)zsel*1048576;
  }

  const int ksp = p.Ksplit ? p.Ksplit : p.K;
  const unsigned short* AbL = Abase + (long)m0*p.lda;
  const unsigned short* AbH = p.A2 && EPI!=13 ? (p.A2 + (long)m0*p.lda - ksp) : AbL;
  const unsigned short* BbL = Bbase + (long)z*p.sBz + (long)n0*p.ldb;
  const unsigned short* BbH = p.B2 ? (p.B2 + (long)z*p.sBz + (long)n0*p.ldb - ksp) : BbL;

  const int srow = tid >> 2;          // 0..63
  const int skk  = (tid & 3) * 8;

  f4 acc[FM][FN];
  f4 zero4 = {0.0f, 0.0f, 0.0f, 0.0f};
  #pragma unroll
  for (int m=0;m<FM;m++)
    #pragma unroll
    for (int n=0;n<FN;n++) acc[m][n] = zero4;

  for (int k0 = 0; k0 < p.K; k0 += 32){
    const unsigned short* A_ = (k0 < ksp) ? AbL : AbH;
    const unsigned short* B_ = (k0 < ksp) ? BbL : BbH;
    #pragma unroll
    for (int q=0;q<BM/64;q++)
      gl_lds(A_ + (long)(q*64 + srow)*p.lda + k0 + skk, (char*)As + q*4096 + wid*1024);
    #pragma unroll
    for (int q=0;q<BN/64;q++)
      gl_lds(B_ + (long)(q*64 + srow)*p.ldb + k0 + skk, (char*)Bs + q*4096 + wid*1024);
    __syncthreads();
    bfrag af[FM], bfr[FN];
    #pragma unroll
    for (int m=0;m<FM;m++)
      af[m] = *(const bfrag*)&As[((wid>>1)*(BM/2) + m*16 + lr)*32 + lg*8];
    #pragma unroll
    for (int n=0;n<FN;n++)
      bfr[n] = *(const bfrag*)&Bs[((wid&1)*(BN/2) + n*16 + lr)*32 + lg*8];
    #pragma unroll
    for (int m=0;m<FM;m++)
      #pragma unroll
      for (int n=0;n<FN;n++)
        acc[m][n] = __builtin_amdgcn_mfma_f32_16x16x32_bf16(af[m], bfr[n], acc[m][n], 0, 0, 0);
    __syncthreads();
  }

  const int wr0 = m0 + (wid>>1)*(BM/2);
  const int wc0 = n0 + (wid&1)*(BN/2);
  #pragma unroll
  for (int m=0;m<FM;m++)
    #pragma unroll
    for (int n=0;n<FN;n++)
      #pragma unroll
      for (int r=0;r<4;r++){
        const int gr = wr0 + m*16 + lg*4 + r;
        const int gc = wc0 + n*16 + lr;
        const float a = acc[m][n][r];
        const long base = (long)gr*p.ldo + gc;
        if constexpr (EPI==6){
          const float t = a + (p.bias1 ? p.bias1[gc] : 0.0f);
          p.O1[base] = f2bf(geluf(t));
        }
        else if constexpr (EPI==7){
          const float t = geluf(a + p.bias1[gc]);
          p.OF[base] = t; p.O1[base] = f2bf(t);
        }
        else if constexpr (EPI==11){
          const long ix = (long)gr*1024 + gc;
          if (z==0) p.O1[ix] = f2bf(sigm(a) * p.X[ix]);
          else      p.OF[ix] = sigm(a - 2.0f);
        }
        else if constexpr (EPI==12){
          const long ix = (long)gr*1024 + gc;
          const float zz = p.Z[ix];
          const float oo = (1.0f - zz)*p.X[ix] + zz*tanhf(a);
          p.OF[ix] = oo; p.O1[ix] = f2bf(oo);
        }
        else if constexpr (EPI==13){
          const long ix = (long)gr*1024 + gc;
          if (z==0){ p.O1[ix] = f2bf(a); }
          else if (z==1){
            const int b_ = gr & 7, js = gr >> 3, h_ = gc >> 6, d_ = gc & 63;
            p.O2[(long)(b_*16 + h_)*65536 + (long)d_*1024 + js] = f2bf(a);
          }
          else if (z==2){ p.O3[ix] = f2bf((a + p.bias1[gc])*0.125f);
                          p.O4[ix] = f2bf((a + p.bias2[gc])*0.125f); }
          else { p.O5[ix] = f2bf(a); }
        }
      }
}

// ---------------------------------------------------------------------------
// Fused relative attention. Block = one (b,h), 16 query rows [i0,i0+16).
// 4 waves; wave w owns cols [w*128,+128) of each 512-col half.
// Cols processed in two halves; BDpre^T band (shift-on-read) in LDS:
//   half0: rr = jc - di + 15            (528 rows)
//   half1: rr = jc - di - 497           (16 + i0 rows)
// Softmax over full row in regs; P staged per-32-col chunk into LDS (reusing
// band region); PV per wave over its 256 cols; cross-wave f32 merge.
// ---------------------------------------------------------------------------
__global__ __launch_bounds__(256,3) void attn_k(const unsigned short* __restrict__ qU,
                                                const unsigned short* __restrict__ qV,
                                                const unsigned short* __restrict__ kh,
                                                const unsigned short* __restrict__ rh,
                                                const unsigned short* __restrict__ vhT,
                                                unsigned short* __restrict__ ctx){
  __shared__ char Sm[20480];          // band (16896) / P-chunks (4KB) + po (16KB)
  __shared__ float redm[4][16];
  __shared__ float reds[4][16];
  __shared__ float invd[16];
  const int tid = threadIdx.x;
  const int w   = tid >> 6;
  const int lane= tid & 63;
  const int lr  = lane & 15;
  const int lg  = lane >> 4;
  const int id = blockIdx.x;
  const int b  = id & 7;              // id%8 -> XCD: per-b kh/vhT slice (2MB) stays in one L2
  const int i0 = ((id >> 3) & 31) * 16;
  const int h  = id >> 8;
  const long hoff = (long)h * 64;
  const f4 z4 = {0.f,0.f,0.f,0.f};

  // qV as B-operand (N=di) for band fill
  bfrag bqv[2];
  #pragma unroll
  for (int kk=0;kk<2;kk++)
    bqv[kk] = *(const bfrag*)(qV + ((long)(i0 + lr)*8 + b)*1024 + hoff + kk*32 + lg*8);
  // qU as A-operand (M=i) for AC
  bfrag aq[2];
  #pragma unroll
  for (int kk=0;kk<2;kk++)
    aq[kk] = *(const bfrag*)(qU + ((long)(i0 + lr)*8 + b)*1024 + hoff + kk*32 + lg*8);

  f4 s[16];

  #pragma unroll
  for (int half=0; half<2; ++half){
    const int c0    = half*512;
    const int rbase = half ? (1008 - i0) : (496 - i0);
    const int ntil  = half ? (1 + (i0>>4)) : 33;
    const int radd  = half ? -497 : 15;      // rr = jc - di + radd
    // ---- band fill: BDpre^T rows r, cols di ----
    for (int mt = w; mt < ntil; mt += 4){
      const int r0 = rbase + mt*16;
      f4 acc = z4;
      #pragma unroll
      for (int kk=0;kk<2;kk++){
        bfrag ar = *(const bfrag*)(rh + (long)(r0 + lr)*1024 + hoff + kk*32 + lg*8);
        acc = __builtin_amdgcn_mfma_f32_16x16x32_bf16(ar, bqv[kk], acc, 0,0,0);
      }
      #pragma unroll
      for (int q=0;q<4;q++){
        const int rr = mt*16 + lg*4 + q;
        *(unsigned short*)(Sm + rr*32 + ((lr*2) ^ ((rr&15)<<1))) = f2bf(acc[q]);
      }
    }
    __syncthreads();
    // ---- AC + BD for this wave's 128 cols ----
    const int cw = c0 + w*128;
    #pragma unroll
    for (int n=0;n<8;n++){
      f4 a = z4;
      #pragma unroll
      for (int kk=0;kk<2;kk++){
        bfrag bk = *(const bfrag*)(kh + ((long)(cw + n*16 + lr)*8 + b)*1024 + hoff + kk*32 + lg*8);
        a = __builtin_amdgcn_mfma_f32_16x16x32_bf16(aq[kk], bk, a, 0,0,0);
      }
      #pragma unroll
      for (int q=0;q<4;q++){
        const int di = lg*4 + q;
        const int jc = cw + n*16 + lr;
        if (jc > i0 + di + 512) a[q] = -1e30f;
        else {
          const int rr = jc - di + radd;
          a[q] += bf2f(*(const unsigned short*)(Sm + rr*32 + (((di*2)) ^ ((rr&15)<<1))));
        }
      }
      s[half*8 + n] = a;
    }
    __syncthreads();   // all band reads done before next half / P staging
  }

  // ---- softmax stats over full 1024 cols ----
  float mx[4], sum[4];
  #pragma unroll
  for (int q=0;q<4;q++){
    float m = -3.0e38f;
    #pragma unroll
    for (int n=0;n<16;n++) m = fmaxf(m, fmaxf(fmaxf(s[n][q], s[n][q]), s[n][q]));
    // (fmax over the single q-th element of each n)
    m = s[0][q];
    #pragma unroll
    for (int n=1;n<16;n++) m = fmaxf(m, s[n][q]);
    m = fmaxf(m, __shfl_xor(m, 1));
    m = fmaxf(m, __shfl_xor(m, 2));
    m = fmaxf(m, __shfl_xor(m, 4));
    m = fmaxf(m, __shfl_xor(m, 8));
    if (lr == 0) redm[w][lg*4+q] = m;
  }
  __syncthreads();
  #pragma unroll
  for (int q=0;q<4;q++){
    const int row = lg*4+q;
    mx[q] = fmaxf(fmaxf(redm[0][row], redm[1][row]), fmaxf(redm[2][row], redm[3][row]));
    sum[q] = 0.0f;
  }
  #pragma unroll
  for (int n=0;n<16;n++)
    #pragma unroll
    for (int q=0;q<4;q++){
      const float e = __expf(s[n][q] - mx[q]);
      s[n][q] = e;
      sum[q] += e;
    }
  #pragma unroll
  for (int q=0;q<4;q++){
    float v = sum[q];
    v += __shfl_xor(v, 1);
    v += __shfl_xor(v, 2);
    v += __shfl_xor(v, 4);
    v += __shfl_xor(v, 8);
    if (lr == 0) reds[w][lg*4+q] = v;
  }
  __syncthreads();
  if (tid < 16)
    invd[tid] = 1.0f / (reds[0][tid] + reds[1][tid] + reds[2][tid] + reds[3][tid]);

  // ---- PV: per-wave over its 256 cols, P staged per 32-col chunk ----
  f4 oac[4];
  #pragma unroll
  for (int nd=0;nd<4;nd++) oac[nd] = z4;
  const unsigned short* vb_base = vhT + (long)(b*16 + h)*65536;
  char* Pch = Sm + w*1024;            // [16 rows][32 cols] u16, swizzled
  #pragma unroll
  for (int t=0;t<8;t++){
    const int jb = (t < 4) ? (w*128 + t*32) : (512 + w*128 + (t-4)*32);
    #pragma unroll
    for (int nn=0;nn<2;nn++){
      const f4 e = s[2*t + nn];
      #pragma unroll
      for (int q=0;q<4;q++){
        const int row = lg*4 + q;
        const int col = nn*16 + lr;
        *(unsigned short*)(Pch + row*64 + ((col*2) ^ (((row>>2)&3)<<4))) = f2bf(e[q]);
      }
    }
    bfrag pa = *(const bfrag*)(Pch + lr*64 + ((lg*16) ^ (((lr>>2)&3)<<4)));
    #pragma unroll
    for (int nd=0;nd<4;nd++){
      bfrag bv = *(const bfrag*)(vb_base + (long)(nd*16 + lr)*1024 + jb + lg*8);
      oac[nd] = __builtin_amdgcn_mfma_f32_16x16x32_bf16(pa, bv, oac[nd], 0,0,0);
    }
  }
  // partial O to LDS
  float* po = (float*)(Sm + 4096 + w*4096);   // [16][64] f32
  #pragma unroll
  for (int nd=0;nd<4;nd++)
    #pragma unroll
    for (int q=0;q<4;q++)
      po[(lg*4+q)*64 + nd*16 + lr] = oac[nd][q];
  __syncthreads();
  // ---- merge + normalize + write ----
  {
    const int row = tid >> 4;
    const int d0  = (tid & 15) * 4;
    f4 v = *(const f4*)(Sm + 4096 + (row*64 + d0)*4);
    #pragma unroll
    for (int ww=1;ww<4;ww++){
      const f4 u = *(const f4*)(Sm + 4096 + ww*4096 + (row*64 + d0)*4);
      v.x += u.x; v.y += u.y; v.z += u.z; v.w += u.w;
    }
    const float iv = invd[row];
    u16x4 o;
    o.x = f2bf(v.x*iv); o.y = f2bf(v.y*iv); o.z = f2bf(v.z*iv); o.w = f2bf(v.w*iv);
    *(u16x4*)(ctx + ((long)(i0 + row)*8 + b)*1024 + hoff + d0) = o;
  }
}

// ---------------------------------------------------------------------------
__global__ __launch_bounds__(256) void ln_k(const float* __restrict__ srcA,
                                            const float* __restrict__ srcB, int splitRow,
                                            const float* __restrict__ g, const float* __restrict__ b,
                                            unsigned short* __restrict__ dst){
  const int row = blockIdx.x;
  const float* src = (srcB != nullptr && row >= splitRow)
                       ? (srcB + (long)(row - splitRow)*1024)
                       : (srcA + (long)row*1024);
  const int t = threadIdx.x;
  float4 v = ((const float4*)src)[t];
  float s1 = v.x+v.y+v.z+v.w;
  float s2 = v.x*v.x+v.y*v.y+v.z*v.z+v.w*v.w;
  #pragma unroll
  for (int o=32;o;o>>=1){ s1 += __shfl_xor(s1,o); s2 += __shfl_xor(s2,o); }
  __shared__ float r1[4], r2[4];
  const int w = t>>6;
  if ((t&63)==0){ r1[w]=s1; r2[w]=s2; }
  __syncthreads();
  s1 = r1[0]+r1[1]+r1[2]+r1[3];
  s2 = r2[0]+r2[1]+r2[2]+r2[3];
  const float mean = s1*(1.0f/1024.0f);
  const float var  = s2*(1.0f/1024.0f) - mean*mean;
  const float rs   = rsqrtf(var + 1e-5f);
  float4 gg = ((const float4*)g)[t];
  float4 bb = ((const float4*)b)[t];
  u16x4 o;
  o.x = f2bf((v.x-mean)*rs*gg.x + bb.x);
  o.y = f2bf((v.y-mean)*rs*gg.y + bb.y);
  o.z = f2bf((v.z-mean)*rs*gg.z + bb.z);
  o.w = f2bf((v.w-mean)*rs*gg.w + bb.w);
  *(u16x4*)(dst + (long)row*1024 + t*4) = o;
}

__global__ __launch_bounds__(256) void conv_k(const float* __restrict__ s,
                                              unsigned short* __restrict__ d, long n){
  long i = ((long)blockIdx.x*256 + threadIdx.x)*4;
  if (i >= n) return;
  float4 v = *(const float4*)(s + i);
  u16x4 o; o.x=f2bf(v.x); o.y=f2bf(v.y); o.z=f2bf(v.z); o.w=f2bf(v.w);
  *(u16x4*)(d + i) = o;
}

__global__ __launch_bounds__(128) void ht_k(const float* __restrict__ h,
                                            unsigned short* __restrict__ d){
  const int row = blockIdx.x;           // i*8+b
  const int i = row>>3, b = row&7;
  const float* src = h + ((long)b*512 + i)*512;
  const int t = threadIdx.x;
  float4 v = ((const float4*)src)[t];
  u16x4 o; o.x=f2bf(v.x); o.y=f2bf(v.y); o.z=f2bf(v.z); o.w=f2bf(v.w);
  *(u16x4*)(d + (long)row*512 + t*4) = o;
}

__global__ __launch_bounds__(256) void pos_k(unsigned short* __restrict__ d){
  const int r = blockIdx.x, t = threadIdx.x;
  const float seq = (float)(1023 - r);
  u16x4 o;
  #pragma unroll
  for (int q=0;q<4;q++){
    const int c = t*4 + q;
    const int f = (c < 512) ? c : (c - 512);
    const float inv = expf((float)f * -0.017988946039016f); // -2*ln(1e4)/1024
    const float ang = seq * inv;
    const float val = (c < 512) ? sinf(ang) : cosf(ang);
    o[q] = f2bf(val);
  }
  *(u16x4*)(d + (long)r*1024 + t*4) = o;
}

__global__ __launch_bounds__(256) void outT_k(const float* __restrict__ o,
                                              float* __restrict__ d){
  const int row = blockIdx.x;   // b*512 + i
  const int b = row>>9, i = row&511;
  const float4 v = ((const float4*)(o + ((long)i*8 + b)*1024))[threadIdx.x];
  ((float4*)(d + (long)row*1024))[threadIdx.x] = v;
}

// ---------------------------------------------------------------------------
extern "C" void kernel_launch(void* const* d_in, const int* in_sizes, int n_in,
                              void* d_out, int out_size, void* d_ws, size_t ws_size,
                              hipStream_t stream){
  (void)in_sizes; (void)n_in; (void)out_size; (void)ws_size;
  const float* h     = (const float*)d_in[0];
  const float* memin = (const float*)d_in[1];
  const float* Wemb  = (const float*)d_in[2];
  const float* bemb  = (const float*)d_in[3];
  const float* Ub    = (const float*)d_in[4];
  const float* Vb    = (const float*)d_in[5];
  const float* ln1   = (const float*)d_in[6];
  const float* ln2   = (const float*)d_in[7];
  const float* Wattn = (const float*)d_in[8];
  const float* g1w   = (const float*)d_in[9];
  const float* g2w   = (const float*)d_in[10];
  const float* fw1   = (const float*)d_in[11];
  const float* fb1   = (const float*)d_in[12];
  const float* fw2   = (const float*)d_in[13];
  const float* fb2   = (const float*)d_in[14];

  char* Wp = (char*)d_ws;
  size_t off = 0;
  auto take = [&](size_t bytes)->size_t{ size_t r = off; off += (bytes + 255) & ~(size_t)255; return r; };
  float*          outf = (float*)         (Wp + take(16777216)); // out (cur*bs, D) f32
  unsigned short* xbf  = (unsigned short*)(Wp + take( 8388608)); // out bf16
  float*          o1f  = (float*)         (Wp + take(16777216));
  unsigned short* o1b  = (unsigned short*)(Wp + take( 8388608));
  float*          zbf  = (float*)         (Wp + take(16777216)); // gru z-gate f32
  unsigned short* rxb  = (unsigned short*)(Wp + take( 8388608)); // r*x bf16
  unsigned short* yb   = (unsigned short*)(Wp + take( 8388608)); // Y / E2 bf16
  unsigned short* Eb   = (unsigned short*)(Wp + take( 8388608)); // LN2 out bf16
  unsigned short* wb0  = (unsigned short*)(Wp + take(52428800)); // layer weights bf16
  unsigned short* hTb  = (unsigned short*)(Wp + take( 4194304));
  unsigned short* webb = (unsigned short*)(Wp + take( 1048576));
  unsigned short* posb = (unsigned short*)(Wp + take( 2097152));
  unsigned short* nkb  = (unsigned short*)(Wp + take(16777216)); // LN'd key (full*bs, D)
  unsigned short* qUb  = (unsigned short*)(Wp + take( 8388608));
  unsigned short* qVb  = (unsigned short*)(Wp + take( 8388608));
  unsigned short* khb  = (unsigned short*)(Wp + take(16777216));
  unsigned short* vhTb = (unsigned short*)(Wp + take(16777216));
  unsigned short* F1b  = khb; // FF hidden (32MB) overlaps khb+vhTb (phase-disjoint)
  unsigned short* rhb  = (unsigned short*)(Wp + take( 2097152));
  unsigned short* ctxb = (unsigned short*)(Wp + take( 8388608));

  const int M1 = 1048576; // D*D elements

  // one-time prep
  conv_k<<<512, 256, 0, stream>>>(Wemb, webb, 524288);
  ht_k<<<4096, 128, 0, stream>>>(h, hTb);
  pos_k<<<1024, 256, 0, stream>>>(posb);

  { // embed: out = gelu(h @ Wemb^T + bemb)  (f32 + bf16)
    GP p{}; p.A=hTb; p.B=webb; p.OF=outf; p.O1=xbf; p.bias1=bemb;
    p.K=512; p.lda=512; p.ldb=512; p.ldo=1024;
    gemm_k<128,64,7><<<dim3(16,32,1),256,0,stream>>>(p);
  }

  // GRU (2 launches, K=2048 concat): x=xb/xf, y=yb_, weights w6 = [Wr,Ur,Wz,Uz,Wg,Ug]
  auto gru_fn = [&](const unsigned short* xb, const float* xf, const unsigned short* yb_,
                    const unsigned short* w6, float* of, unsigned short* ob){
    { GP p{}; p.A=yb_; p.A2=xb; p.B=w6; p.B2=w6+M1; p.sBz=2*M1;
      p.O1=rxb; p.OF=zbf; p.X=xf;
      p.K=2048; p.Ksplit=1024; p.lda=1024; p.ldb=1024; p.ldo=1024;
      gemm_k<128,128,11><<<dim3(8,32,2),256,0,stream>>>(p); }
    { GP p{}; p.A=yb_; p.A2=rxb; p.B=w6+4*M1; p.B2=w6+5*M1;
      p.X=xf; p.Z=zbf; p.OF=of; p.O1=ob;
      p.K=2048; p.Ksplit=1024; p.lda=1024; p.ldb=1024; p.ldo=1024;
      gemm_k<128,64,12><<<dim3(16,32,1),256,0,stream>>>(p); }
  };

  for (int l = 0; l < 4; ++l){
    // layer weights -> bf16
    conv_k<<<5120,256,0,stream>>>(Wattn + (long)l*5242880, wb0,          5242880);
    conv_k<<<6144,256,0,stream>>>(g1w   + (long)l*6291456, wb0 +  5*M1,  6291456);
    conv_k<<<6144,256,0,stream>>>(g2w   + (long)l*6291456, wb0 + 11*M1,  6291456);
    conv_k<<<4096,256,0,stream>>>(fw1   + (long)l*4194304, wb0 + 17*M1,  4194304);
    conv_k<<<4096,256,0,stream>>>(fw2   + (long)l*4194304, wb0 + 21*M1,  4194304);

    // nk = LN(concat(mem[l], out)); rows [4096:8192) are nq
    ln_k<<<8192,256,0,stream>>>(memin + (long)l*4194304, outf, 4096,
                                ln1 + l*2048, ln1 + l*2048 + 1024, nkb);

    { // fused QKV + R: z=0 kh, z=1 vhT, z=2 qU/qV (*0.125), z=3 rh
      GP p{}; p.A=nkb; p.A2=posb; p.B=wb0;
      p.O1=khb; p.O2=vhTb; p.O3=qUb; p.O4=qVb; p.O5=rhb;
      p.bias1=Ub; p.bias2=Vb;
      p.K=1024; p.lda=1024; p.ldb=1024; p.ldo=1024;
      gemm_k<128,128,13><<<dim3(8,64,4),256,0,stream>>>(p); }

    attn_k<<<4096,256,0,stream>>>(qUb, qVb, khb, rhb, vhTb, ctxb);

    { // Y = gelu(ctx @ Wo^T)
      GP p{}; p.A=ctxb; p.B=wb0+4*M1; p.O1=yb;
      p.K=1024; p.lda=1024; p.ldb=1024; p.ldo=1024;
      gemm_k<128,64,6><<<dim3(16,32,1),256,0,stream>>>(p); }

    gru_fn(xbf, outf, yb, wb0 + 5*M1, o1f, o1b);

    ln_k<<<4096,256,0,stream>>>(o1f, nullptr, 1<<30,
                                ln2 + l*2048, ln2 + l*2048 + 1024, Eb);

    { GP p{}; p.A=Eb;  p.B=wb0+17*M1; p.O1=F1b; p.bias1=fb1 + l*4096;
      p.K=1024; p.lda=1024; p.ldb=1024; p.ldo=4096;
      gemm_k<128,128,6><<<dim3(32,32,1),256,0,stream>>>(p); }
    { GP p{}; p.A=F1b; p.B=wb0+21*M1; p.O1=yb; p.bias1=fb2 + l*1024;
      p.K=4096; p.lda=4096; p.ldb=4096; p.ldo=1024;
      gemm_k<128,64,6><<<dim3(16,32,1),256,0,stream>>>(p); }

    gru_fn(o1b, o1f, yb, wb0 + 11*M1, outf, xbf);
  }

  outT_k<<<4096,256,0,stream>>>(outf, (float*)d_out);
}

// Round 4
// 3028.293 us; speedup vs baseline: 1.8073x; 1.0181x over previous
//
#include <hip/hip_runtime.h>
#include <hip/hip_bf16.h>

// Gated Transformer-XL forward.
// Dims: L=4, D=1024, NH=16, HD=64, CUR=512, MEM=512, BS=8, IN=512, FF=4096, FULL=1024
// Activation layout: (seq*BS, D), row = i*BS + b.

typedef __attribute__((ext_vector_type(8))) __bf16 bfrag;
typedef __attribute__((ext_vector_type(4))) float f4;
typedef __attribute__((ext_vector_type(4))) unsigned short u16x4;
typedef __attribute__((ext_vector_type(8))) unsigned short u16x8;

__device__ __forceinline__ unsigned short f2bf(float f){
  union { float f; unsigned u; } v; v.f = f;
  unsigned r = v.u + 0x7fffu + ((v.u >> 16) & 1u);
  return (unsigned short)(r >> 16);
}
__device__ __forceinline__ float bf2f(unsigned short u){
  union { unsigned u; float f; } v; v.u = (unsigned)u << 16; return v.f;
}
__device__ __forceinline__ float geluf(float x){
  return 0.5f * x * (1.0f + erff(x * 0.7071067811865476f));
}
__device__ __forceinline__ float sigm(float x){ return 1.0f/(1.0f + __expf(-x)); }

__device__ __forceinline__ void gl_lds(const void* g, void* l){
  __builtin_amdgcn_global_load_lds(
    reinterpret_cast<const __attribute__((address_space(1))) unsigned int*>(
        reinterpret_cast<unsigned long>(g)),
    reinterpret_cast<__attribute__((address_space(3))) unsigned int*>(
        reinterpret_cast<unsigned long>(l)),
    16, 0, 0);
}

// ---------------------------------------------------------------------------
// Dense GEMM: C[M,N] = A[M,K] @ B[N,K]^T (bf16, row-major). Optional K-concat.
// 2-phase double-buffered: stage tile t+1 before computing tile t; one
// barrier per k-step so staging latency hides under ds_read+MFMA.
// EPI: 6  O1 = bf(gelu(acc + bias1))
//      7  OF = gelu(acc+bias1) f32, O1 = bf16 of same          (embed)
//      11 z==0: O1 = bf(sigm(acc) * X)   (GRU r-gate * x)
//         z==1: OF = sigm(acc - 2)       (GRU z-gate)
//      12 o = (1-Z)*X + Z*tanh(acc); OF = o; O1 = bf(o)        (GRU combine)
//      13 fused QKV+R: z=0 kh, z=1 vhT-scatter, z=2 qU/qV(+bias, *0.125), z=3 rh
// ---------------------------------------------------------------------------
struct GP {
  const unsigned short* A;
  const unsigned short* A2;
  const unsigned short* B;
  const unsigned short* B2;
  unsigned short* O1;
  unsigned short* O2;
  unsigned short* O3;
  unsigned short* O4;
  unsigned short* O5;
  float* OF;
  const float* bias1;
  const float* bias2;
  const float* X;
  const float* Z;
  int K, Ksplit, lda, ldb, ldo;
  int sBz;
};

template<int BM, int BN, int EPI>
__global__ __launch_bounds__(256) void gemm_k(GP p){
  __shared__ unsigned short As[2][BM*32];
  __shared__ unsigned short Bs[2][BN*32];
  const int tid  = threadIdx.x;
  const int lane = tid & 63;
  const int wid  = tid >> 6;
  const int lr   = lane & 15;
  const int lg   = lane >> 4;
  constexpr int FM = BM/32, FN = BN/32;
  const int m0 = blockIdx.y * BM;
  const int n0 = blockIdx.x * BN;
  const int z  = blockIdx.z;

  const unsigned short* Abase = p.A;
  const unsigned short* Bbase = p.B;
  if constexpr (EPI==13){
    if (z==2){ if (blockIdx.y >= 32) return; Abase = p.A + 4194304; }
    if (z==3){ if (blockIdx.y >= 8)  return; Abase = p.A2; }
    const int zsel = (z==0)?1:((z==1)?2:((z==2)?0:3));
    Bbase = p.B + (long)zsel*1048576;
  }

  const int ksp = p.Ksplit ? p.Ksplit : p.K;
  const unsigned short* AbL = Abase + (long)m0*p.lda;
  const unsigned short* AbH = p.A2 && EPI!=13 ? (p.A2 + (long)m0*p.lda - ksp) : AbL;
  const unsigned short* BbL = Bbase + (long)z*p.sBz + (long)n0*p.ldb;
  const unsigned short* BbH = p.B2 ? (p.B2 + (long)z*p.sBz + (long)n0*p.ldb - ksp) : BbL;

  const int srow = tid >> 2;          // 0..63
  const int skk  = (tid & 3) * 8;

  f4 acc[FM][FN];
  f4 zero4 = {0.0f, 0.0f, 0.0f, 0.0f};
  #pragma unroll
  for (int m=0;m<FM;m++)
    #pragma unroll
    for (int n=0;n<FN;n++) acc[m][n] = zero4;

  const int nk = p.K >> 5;
  // prologue: stage tile 0 (k0=0 always < ksp)
  #pragma unroll
  for (int q=0;q<BM/64;q++)
    gl_lds(AbL + (long)(q*64 + srow)*p.lda + skk, (char*)As[0] + q*4096 + wid*1024);
  #pragma unroll
  for (int q=0;q<BN/64;q++)
    gl_lds(BbL + (long)(q*64 + srow)*p.ldb + skk, (char*)Bs[0] + q*4096 + wid*1024);
  __syncthreads();

  int cur = 0;
  for (int t = 0; t < nk; ++t){
    const int k1 = (t+1) << 5;
    if (t+1 < nk){
      const unsigned short* A_ = (k1 < ksp) ? AbL : AbH;
      const unsigned short* B_ = (k1 < ksp) ? BbL : BbH;
      #pragma unroll
      for (int q=0;q<BM/64;q++)
        gl_lds(A_ + (long)(q*64 + srow)*p.lda + k1 + skk, (char*)As[cur^1] + q*4096 + wid*1024);
      #pragma unroll
      for (int q=0;q<BN/64;q++)
        gl_lds(B_ + (long)(q*64 + srow)*p.ldb + k1 + skk, (char*)Bs[cur^1] + q*4096 + wid*1024);
    }
    bfrag af[FM], bfr[FN];
    #pragma unroll
    for (int m=0;m<FM;m++)
      af[m] = *(const bfrag*)&As[cur][((wid>>1)*(BM/2) + m*16 + lr)*32 + lg*8];
    #pragma unroll
    for (int n=0;n<FN;n++)
      bfr[n] = *(const bfrag*)&Bs[cur][((wid&1)*(BN/2) + n*16 + lr)*32 + lg*8];
    #pragma unroll
    for (int m=0;m<FM;m++)
      #pragma unroll
      for (int n=0;n<FN;n++)
        acc[m][n] = __builtin_amdgcn_mfma_f32_16x16x32_bf16(af[m], bfr[n], acc[m][n], 0, 0, 0);
    __syncthreads();   // drains vmcnt(0): tile t+1 resident; buffer cur reusable
    cur ^= 1;
  }

  const int wr0 = m0 + (wid>>1)*(BM/2);
  const int wc0 = n0 + (wid&1)*(BN/2);
  #pragma unroll
  for (int m=0;m<FM;m++)
    #pragma unroll
    for (int n=0;n<FN;n++)
      #pragma unroll
      for (int r=0;r<4;r++){
        const int gr = wr0 + m*16 + lg*4 + r;
        const int gc = wc0 + n*16 + lr;
        const float a = acc[m][n][r];
        const long base = (long)gr*p.ldo + gc;
        if constexpr (EPI==6){
          const float t = a + (p.bias1 ? p.bias1[gc] : 0.0f);
          p.O1[base] = f2bf(geluf(t));
        }
        else if constexpr (EPI==7){
          const float t = geluf(a + p.bias1[gc]);
          p.OF[base] = t; p.O1[base] = f2bf(t);
        }
        else if constexpr (EPI==11){
          const long ix = (long)gr*1024 + gc;
          if (z==0) p.O1[ix] = f2bf(sigm(a) * p.X[ix]);
          else      p.OF[ix] = sigm(a - 2.0f);
        }
        else if constexpr (EPI==12){
          const long ix = (long)gr*1024 + gc;
          const float zz = p.Z[ix];
          const float oo = (1.0f - zz)*p.X[ix] + zz*tanhf(a);
          p.OF[ix] = oo; p.O1[ix] = f2bf(oo);
        }
        else if constexpr (EPI==13){
          const long ix = (long)gr*1024 + gc;
          if (z==0){ p.O1[ix] = f2bf(a); }
          else if (z==1){
            const int b_ = gr & 7, js = gr >> 3, h_ = gc >> 6, d_ = gc & 63;
            p.O2[(long)(b_*16 + h_)*65536 + (long)d_*1024 + js] = f2bf(a);
          }
          else if (z==2){ p.O3[ix] = f2bf((a + p.bias1[gc])*0.125f);
                          p.O4[ix] = f2bf((a + p.bias2[gc])*0.125f); }
          else { p.O5[ix] = f2bf(a); }
        }
      }
}

// ---------------------------------------------------------------------------
// Fused relative attention. Block = one (b,h), 16 query rows [i0,i0+16).
// 4 waves; wave w owns cols [w*128,+128) of each 512-col half.
// BDpre^T band in LDS, row stride 38B (mixed-parity banks -> ~conflict-free):
//   half0: rr = jc - di + 15            (528 rows)
//   half1: rr = jc - di - 497           (16 + i0 rows)
// Softmax over full row in regs; P staged per-32-col chunk into LDS; PV per
// wave over its 256 cols; cross-wave f32 merge.
// ---------------------------------------------------------------------------
__global__ __launch_bounds__(256,6) void attn_k(const unsigned short* __restrict__ qU,
                                                const unsigned short* __restrict__ qV,
                                                const unsigned short* __restrict__ kh,
                                                const unsigned short* __restrict__ rh,
                                                const unsigned short* __restrict__ vhT,
                                                unsigned short* __restrict__ ctx){
  __shared__ char Sm[20480];          // band (528*38=20064) / P-chunks (4KB) / po @4096 (16KB)
  __shared__ float redm[4][16];
  __shared__ float reds[4][16];
  __shared__ float invd[16];
  const int tid = threadIdx.x;
  const int w   = tid >> 6;
  const int lane= tid & 63;
  const int lr  = lane & 15;
  const int lg  = lane >> 4;
  const int id = blockIdx.x;
  const int b  = id & 7;              // id%8 -> XCD: per-b kh/vhT slice stays in one L2
  const int i0 = ((id >> 3) & 31) * 16;
  const int h  = id >> 8;
  const long hoff = (long)h * 64;
  const f4 z4 = {0.f,0.f,0.f,0.f};

  // qV as B-operand (N=di) for band fill
  bfrag bqv[2];
  #pragma unroll
  for (int kk=0;kk<2;kk++)
    bqv[kk] = *(const bfrag*)(qV + ((long)(i0 + lr)*8 + b)*1024 + hoff + kk*32 + lg*8);
  // qU as A-operand (M=i) for AC
  bfrag aq[2];
  #pragma unroll
  for (int kk=0;kk<2;kk++)
    aq[kk] = *(const bfrag*)(qU + ((long)(i0 + lr)*8 + b)*1024 + hoff + kk*32 + lg*8);

  f4 s[16];

  #pragma unroll
  for (int half=0; half<2; ++half){
    const int c0    = half*512;
    const int rbase = half ? (1008 - i0) : (496 - i0);
    const int ntil  = half ? (1 + (i0>>4)) : 33;
    const int radd  = half ? -497 : 15;      // rr = jc - di + radd
    // ---- band fill: BDpre^T rows rr, cols di ----
    for (int mt = w; mt < ntil; mt += 4){
      const int r0 = rbase + mt*16;
      f4 acc = z4;
      #pragma unroll
      for (int kk=0;kk<2;kk++){
        bfrag ar = *(const bfrag*)(rh + (long)(r0 + lr)*1024 + hoff + kk*32 + lg*8);
        acc = __builtin_amdgcn_mfma_f32_16x16x32_bf16(ar, bqv[kk], acc, 0,0,0);
      }
      #pragma unroll
      for (int q=0;q<4;q++){
        const int rr = mt*16 + lg*4 + q;
        *(unsigned short*)(Sm + rr*38 + lr*2) = f2bf(acc[q]);
      }
    }
    __syncthreads();
    // ---- AC + BD for this wave's 128 cols ----
    const int cw = c0 + w*128;
    #pragma unroll
    for (int n=0;n<8;n++){
      f4 a = z4;
      #pragma unroll
      for (int kk=0;kk<2;kk++){
        bfrag bk = *(const bfrag*)(kh + ((long)(cw + n*16 + lr)*8 + b)*1024 + hoff + kk*32 + lg*8);
        a = __builtin_amdgcn_mfma_f32_16x16x32_bf16(aq[kk], bk, a, 0,0,0);
      }
      #pragma unroll
      for (int q=0;q<4;q++){
        const int di = lg*4 + q;
        const int jc = cw + n*16 + lr;
        if (jc > i0 + di + 512) a[q] = -1e30f;
        else {
          const int rr = jc - di + radd;
          a[q] += bf2f(*(const unsigned short*)(Sm + rr*38 + di*2));
        }
      }
      s[half*8 + n] = a;
    }
    __syncthreads();   // all band reads done before next half / P staging
  }

  // ---- softmax stats over full 1024 cols ----
  float mx[4], sum[4];
  #pragma unroll
  for (int q=0;q<4;q++){
    float m = s[0][q];
    #pragma unroll
    for (int n=1;n<16;n++) m = fmaxf(m, s[n][q]);
    m = fmaxf(m, __shfl_xor(m, 1));
    m = fmaxf(m, __shfl_xor(m, 2));
    m = fmaxf(m, __shfl_xor(m, 4));
    m = fmaxf(m, __shfl_xor(m, 8));
    if (lr == 0) redm[w][lg*4+q] = m;
  }
  __syncthreads();
  #pragma unroll
  for (int q=0;q<4;q++){
    const int row = lg*4+q;
    mx[q] = fmaxf(fmaxf(redm[0][row], redm[1][row]), fmaxf(redm[2][row], redm[3][row]));
    sum[q] = 0.0f;
  }
  #pragma unroll
  for (int n=0;n<16;n++)
    #pragma unroll
    for (int q=0;q<4;q++){
      const float e = __expf(s[n][q] - mx[q]);
      s[n][q] = e;
      sum[q] += e;
    }
  #pragma unroll
  for (int q=0;q<4;q++){
    float v = sum[q];
    v += __shfl_xor(v, 1);
    v += __shfl_xor(v, 2);
    v += __shfl_xor(v, 4);
    v += __shfl_xor(v, 8);
    if (lr == 0) reds[w][lg*4+q] = v;
  }
  __syncthreads();
  if (tid < 16)
    invd[tid] = 1.0f / (reds[0][tid] + reds[1][tid] + reds[2][tid] + reds[3][tid]);

  // ---- PV: per-wave over its 256 cols, P staged per 32-col chunk ----
  f4 oac[4];
  #pragma unroll
  for (int nd=0;nd<4;nd++) oac[nd] = z4;
  const unsigned short* vb_base = vhT + (long)(b*16 + h)*65536;
  char* Pch = Sm + w*1024;            // [16 rows][32 cols] u16, swizzled
  #pragma unroll
  for (int t=0;t<8;t++){
    const int jb = (t < 4) ? (w*128 + t*32) : (512 + w*128 + (t-4)*32);
    #pragma unroll
    for (int nn=0;nn<2;nn++){
      const f4 e = s[((t<4)?0:8) + (t&3)*2 + nn];
      #pragma unroll
      for (int q=0;q<4;q++){
        const int row = lg*4 + q;
        const int col = nn*16 + lr;
        *(unsigned short*)(Pch + row*64 + ((col*2) ^ (((row>>2)&3)<<4))) = f2bf(e[q]);
      }
    }
    bfrag pa = *(const bfrag*)(Pch + lr*64 + ((lg*16) ^ (((lr>>2)&3)<<4)));
    #pragma unroll
    for (int nd=0;nd<4;nd++){
      bfrag bv = *(const bfrag*)(vb_base + (long)(nd*16 + lr)*1024 + jb + lg*8);
      oac[nd] = __builtin_amdgcn_mfma_f32_16x16x32_bf16(pa, bv, oac[nd], 0,0,0);
    }
  }
  // partial O to LDS
  float* po = (float*)(Sm + 4096 + w*4096);   // [16][64] f32
  #pragma unroll
  for (int nd=0;nd<4;nd++)
    #pragma unroll
    for (int q=0;q<4;q++)
      po[(lg*4+q)*64 + nd*16 + lr] = oac[nd][q];
  __syncthreads();
  // ---- merge + normalize + write ----
  {
    const int row = tid >> 4;
    const int d0  = (tid & 15) * 4;
    f4 v = *(const f4*)(Sm + 4096 + (row*64 + d0)*4);
    #pragma unroll
    for (int ww=1;ww<4;ww++){
      const f4 u = *(const f4*)(Sm + 4096 + ww*4096 + (row*64 + d0)*4);
      v.x += u.x; v.y += u.y; v.z += u.z; v.w += u.w;
    }
    const float iv = invd[row];
    u16x4 o;
    o.x = f2bf(v.x*iv); o.y = f2bf(v.y*iv); o.z = f2bf(v.z*iv); o.w = f2bf(v.w*iv);
    *(u16x4*)(ctx + ((long)(i0 + row)*8 + b)*1024 + hoff + d0) = o;
  }
}

// ---------------------------------------------------------------------------
__global__ __launch_bounds__(256) void ln_k(const float* __restrict__ srcA,
                                            const float* __restrict__ srcB, int splitRow,
                                            const float* __restrict__ g, const float* __restrict__ b,
                                            unsigned short* __restrict__ dst){
  const int row = blockIdx.x;
  const float* src = (srcB != nullptr && row >= splitRow)
                       ? (srcB + (long)(row - splitRow)*1024)
                       : (srcA + (long)row*1024);
  const int t = threadIdx.x;
  float4 v = ((const float4*)src)[t];
  float s1 = v.x+v.y+v.z+v.w;
  float s2 = v.x*v.x+v.y*v.y+v.z*v.z+v.w*v.w;
  #pragma unroll
  for (int o=32;o;o>>=1){ s1 += __shfl_xor(s1,o); s2 += __shfl_xor(s2,o); }
  __shared__ float r1[4], r2[4];
  const int w = t>>6;
  if ((t&63)==0){ r1[w]=s1; r2[w]=s2; }
  __syncthreads();
  s1 = r1[0]+r1[1]+r1[2]+r1[3];
  s2 = r2[0]+r2[1]+r2[2]+r2[3];
  const float mean = s1*(1.0f/1024.0f);
  const float var  = s2*(1.0f/1024.0f) - mean*mean;
  const float rs   = rsqrtf(var + 1e-5f);
  float4 gg = ((const float4*)g)[t];
  float4 bb = ((const float4*)b)[t];
  u16x4 o;
  o.x = f2bf((v.x-mean)*rs*gg.x + bb.x);
  o.y = f2bf((v.y-mean)*rs*gg.y + bb.y);
  o.z = f2bf((v.z-mean)*rs*gg.z + bb.z);
  o.w = f2bf((v.w-mean)*rs*gg.w + bb.w);
  *(u16x4*)(dst + (long)row*1024 + t*4) = o;
}

__global__ __launch_bounds__(256) void conv_k(const float* __restrict__ s,
                                              unsigned short* __restrict__ d, long n){
  long i = ((long)blockIdx.x*256 + threadIdx.x)*4;
  if (i >= n) return;
  float4 v = *(const float4*)(s + i);
  u16x4 o; o.x=f2bf(v.x); o.y=f2bf(v.y); o.z=f2bf(v.z); o.w=f2bf(v.w);
  *(u16x4*)(d + i) = o;
}

__global__ __launch_bounds__(128) void ht_k(const float* __restrict__ h,
                                            unsigned short* __restrict__ d){
  const int row = blockIdx.x;           // i*8+b
  const int i = row>>3, b = row&7;
  const float* src = h + ((long)b*512 + i)*512;
  const int t = threadIdx.x;
  float4 v = ((const float4*)src)[t];
  u16x4 o; o.x=f2bf(v.x); o.y=f2bf(v.y); o.z=f2bf(v.z); o.w=f2bf(v.w);
  *(u16x4*)(d + (long)row*512 + t*4) = o;
}

__global__ __launch_bounds__(256) void pos_k(unsigned short* __restrict__ d){
  const int r = blockIdx.x, t = threadIdx.x;
  const float seq = (float)(1023 - r);
  u16x4 o;
  #pragma unroll
  for (int q=0;q<4;q++){
    const int c = t*4 + q;
    const int f = (c < 512) ? c : (c - 512);
    const float inv = expf((float)f * -0.017988946039016f); // -2*ln(1e4)/1024
    const float ang = seq * inv;
    const float val = (c < 512) ? sinf(ang) : cosf(ang);
    o[q] = f2bf(val);
  }
  *(u16x4*)(d + (long)r*1024 + t*4) = o;
}

__global__ __launch_bounds__(256) void outT_k(const float* __restrict__ o,
                                              float* __restrict__ d){
  const int row = blockIdx.x;   // b*512 + i
  const int b = row>>9, i = row&511;
  const float4 v = ((const float4*)(o + ((long)i*8 + b)*1024))[threadIdx.x];
  ((float4*)(d + (long)row*1024))[threadIdx.x] = v;
}

// ---------------------------------------------------------------------------
extern "C" void kernel_launch(void* const* d_in, const int* in_sizes, int n_in,
                              void* d_out, int out_size, void* d_ws, size_t ws_size,
                              hipStream_t stream){
  (void)in_sizes; (void)n_in; (void)out_size; (void)ws_size;
  const float* h     = (const float*)d_in[0];
  const float* memin = (const float*)d_in[1];
  const float* Wemb  = (const float*)d_in[2];
  const float* bemb  = (const float*)d_in[3];
  const float* Ub    = (const float*)d_in[4];
  const float* Vb    = (const float*)d_in[5];
  const float* ln1   = (const float*)d_in[6];
  const float* ln2   = (const float*)d_in[7];
  const float* Wattn = (const float*)d_in[8];
  const float* g1w   = (const float*)d_in[9];
  const float* g2w   = (const float*)d_in[10];
  const float* fw1   = (const float*)d_in[11];
  const float* fb1   = (const float*)d_in[12];
  const float* fw2   = (const float*)d_in[13];
  const float* fb2   = (const float*)d_in[14];

  char* Wp = (char*)d_ws;
  size_t off = 0;
  auto take = [&](size_t bytes)->size_t{ size_t r = off; off += (bytes + 255) & ~(size_t)255; return r; };
  float*          outf = (float*)         (Wp + take(16777216)); // out (cur*bs, D) f32
  unsigned short* xbf  = (unsigned short*)(Wp + take( 8388608)); // out bf16
  float*          o1f  = (float*)         (Wp + take(16777216));
  unsigned short* o1b  = (unsigned short*)(Wp + take( 8388608));
  float*          zbf  = (float*)         (Wp + take(16777216)); // gru z-gate f32
  unsigned short* rxb  = (unsigned short*)(Wp + take( 8388608)); // r*x bf16
  unsigned short* yb   = (unsigned short*)(Wp + take( 8388608)); // Y / E2 bf16
  unsigned short* Eb   = (unsigned short*)(Wp + take( 8388608)); // LN2 out bf16
  unsigned short* wb0  = (unsigned short*)(Wp + take(52428800)); // layer weights bf16
  unsigned short* hTb  = (unsigned short*)(Wp + take( 4194304));
  unsigned short* webb = (unsigned short*)(Wp + take( 1048576));
  unsigned short* posb = (unsigned short*)(Wp + take( 2097152));
  unsigned short* nkb  = (unsigned short*)(Wp + take(16777216)); // LN'd key (full*bs, D)
  unsigned short* qUb  = (unsigned short*)(Wp + take( 8388608));
  unsigned short* qVb  = (unsigned short*)(Wp + take( 8388608));
  unsigned short* khb  = (unsigned short*)(Wp + take(16777216));
  unsigned short* vhTb = (unsigned short*)(Wp + take(16777216));
  unsigned short* F1b  = khb; // FF hidden (32MB) overlaps khb+vhTb (phase-disjoint)
  unsigned short* rhb  = (unsigned short*)(Wp + take( 2097152));
  unsigned short* ctxb = (unsigned short*)(Wp + take( 8388608));

  const int M1 = 1048576; // D*D elements

  // one-time prep
  conv_k<<<512, 256, 0, stream>>>(Wemb, webb, 524288);
  ht_k<<<4096, 128, 0, stream>>>(h, hTb);
  pos_k<<<1024, 256, 0, stream>>>(posb);

  { // embed: out = gelu(h @ Wemb^T + bemb)  (f32 + bf16)
    GP p{}; p.A=hTb; p.B=webb; p.OF=outf; p.O1=xbf; p.bias1=bemb;
    p.K=512; p.lda=512; p.ldb=512; p.ldo=1024;
    gemm_k<128,64,7><<<dim3(16,32,1),256,0,stream>>>(p);
  }

  // GRU (2 launches, K=2048 concat): x=xb/xf, y=yb_, weights w6 = [Wr,Ur,Wz,Uz,Wg,Ug]
  auto gru_fn = [&](const unsigned short* xb, const float* xf, const unsigned short* yb_,
                    const unsigned short* w6, float* of, unsigned short* ob){
    { GP p{}; p.A=yb_; p.A2=xb; p.B=w6; p.B2=w6+M1; p.sBz=2*M1;
      p.O1=rxb; p.OF=zbf; p.X=xf;
      p.K=2048; p.Ksplit=1024; p.lda=1024; p.ldb=1024; p.ldo=1024;
      gemm_k<128,64,11><<<dim3(16,32,2),256,0,stream>>>(p); }
    { GP p{}; p.A=yb_; p.A2=rxb; p.B=w6+4*M1; p.B2=w6+5*M1;
      p.X=xf; p.Z=zbf; p.OF=of; p.O1=ob;
      p.K=2048; p.Ksplit=1024; p.lda=1024; p.ldb=1024; p.ldo=1024;
      gemm_k<128,64,12><<<dim3(16,32,1),256,0,stream>>>(p); }
  };

  for (int l = 0; l < 4; ++l){
    // layer weights -> bf16
    conv_k<<<5120,256,0,stream>>>(Wattn + (long)l*5242880, wb0,          5242880);
    conv_k<<<6144,256,0,stream>>>(g1w   + (long)l*6291456, wb0 +  5*M1,  6291456);
    conv_k<<<6144,256,0,stream>>>(g2w   + (long)l*6291456, wb0 + 11*M1,  6291456);
    conv_k<<<4096,256,0,stream>>>(fw1   + (long)l*4194304, wb0 + 17*M1,  4194304);
    conv_k<<<4096,256,0,stream>>>(fw2   + (long)l*4194304, wb0 + 21*M1,  4194304);

    // nk = LN(concat(mem[l], out)); rows [4096:8192) are nq
    ln_k<<<8192,256,0,stream>>>(memin + (long)l*4194304, outf, 4096,
                                ln1 + l*2048, ln1 + l*2048 + 1024, nkb);

    { // fused QKV + R: z=0 kh, z=1 vhT, z=2 qU/qV (*0.125), z=3 rh
      GP p{}; p.A=nkb; p.A2=posb; p.B=wb0;
      p.O1=khb; p.O2=vhTb; p.O3=qUb; p.O4=qVb; p.O5=rhb;
      p.bias1=Ub; p.bias2=Vb;
      p.K=1024; p.lda=1024; p.ldb=1024; p.ldo=1024;
      gemm_k<128,128,13><<<dim3(8,64,4),256,0,stream>>>(p); }

    attn_k<<<4096,256,0,stream>>>(qUb, qVb, khb, rhb, vhTb, ctxb);

    { // Y = gelu(ctx @ Wo^T)
      GP p{}; p.A=ctxb; p.B=wb0+4*M1; p.O1=yb;
      p.K=1024; p.lda=1024; p.ldb=1024; p.ldo=1024;
      gemm_k<128,64,6><<<dim3(16,32,1),256,0,stream>>>(p); }

    gru_fn(xbf, outf, yb, wb0 + 5*M1, o1f, o1b);

    ln_k<<<4096,256,0,stream>>>(o1f, nullptr, 1<<30,
                                ln2 + l*2048, ln2 + l*2048 + 1024, Eb);

    { GP p{}; p.A=Eb;  p.B=wb0+17*M1; p.O1=F1b; p.bias1=fb1 + l*4096;
      p.K=1024; p.lda=1024; p.ldb=1024; p.ldo=4096;
      gemm_k<128,128,6><<<dim3(32,32,1),256,0,stream>>>(p); }
    { GP p{}; p.A=F1b; p.B=wb0+21*M1; p.O1=yb; p.bias1=fb2 + l*1024;
      p.K=4096; p.lda=4096; p.ldb=4096; p.ldo=1024;
      gemm_k<128,64,6><<<dim3(16,32,1),256,0,stream>>>(p); }

    gru_fn(o1b, o1f, yb, wb0 + 11*M1, outf, xbf);
  }

  outT_k<<<4096,256,0,stream>>>(outf, (float*)d_out);
}

// Round 5
// 2752.641 us; speedup vs baseline: 1.9883x; 1.1001x over previous
//
#include <hip/hip_runtime.h>
#include <hip/hip_bf16.h>

// Gated Transformer-XL forward.
// Dims: L=4, D=1024, NH=16, HD=64, CUR=512, MEM=512, BS=8, IN=512, FF=4096, FULL=1024
// Activation layout: (seq*BS, D), row = i*BS + b.

typedef __attribute__((ext_vector_type(8))) __bf16 bfrag;
typedef __attribute__((ext_vector_type(4))) float f4;
typedef __attribute__((ext_vector_type(4))) unsigned short u16x4;
typedef __attribute__((ext_vector_type(8))) unsigned short u16x8;

__device__ __forceinline__ unsigned short f2bf(float f){
  union { float f; unsigned u; } v; v.f = f;
  unsigned r = v.u + 0x7fffu + ((v.u >> 16) & 1u);
  return (unsigned short)(r >> 16);
}
__device__ __forceinline__ float bf2f(unsigned short u){
  union { unsigned u; float f; } v; v.u = (unsigned)u << 16; return v.f;
}
__device__ __forceinline__ float geluf(float x){
  return 0.5f * x * (1.0f + erff(x * 0.7071067811865476f));
}
__device__ __forceinline__ float sigm(float x){ return 1.0f/(1.0f + __expf(-x)); }

__device__ __forceinline__ void gl_lds(const void* g, void* l){
  __builtin_amdgcn_global_load_lds(
    reinterpret_cast<const __attribute__((address_space(1))) unsigned int*>(
        reinterpret_cast<unsigned long>(g)),
    reinterpret_cast<__attribute__((address_space(3))) unsigned int*>(
        reinterpret_cast<unsigned long>(l)),
    16, 0, 0);
}

// ---------------------------------------------------------------------------
// Dense GEMM: C[M,N] = A[M,K] @ B[N,K]^T (bf16, row-major). Optional K-concat.
// 2-phase double-buffered: stage tile t+1 before computing tile t; one
// barrier per k-step so staging latency hides under ds_read+MFMA.
// EPI: 6  O1 = bf(gelu(acc + bias1))
//      7  OF = gelu(acc+bias1) f32, O1 = bf16 of same          (embed)
//      11 z==0: O1 = bf(sigm(acc) * X)   (GRU r-gate * x)
//         z==1: OF = sigm(acc - 2)       (GRU z-gate)
//      12 o = (1-Z)*X + Z*tanh(acc); OF = o; O1 = bf(o)        (GRU combine)
//      13 fused QKV+R: z=0 kh, z=1 vhT-scatter, z=2 qU/qV(+bias, *0.125), z=3 rh
// ---------------------------------------------------------------------------
struct GP {
  const unsigned short* A;
  const unsigned short* A2;
  const unsigned short* B;
  const unsigned short* B2;
  unsigned short* O1;
  unsigned short* O2;
  unsigned short* O3;
  unsigned short* O4;
  unsigned short* O5;
  float* OF;
  const float* bias1;
  const float* bias2;
  const float* X;
  const float* Z;
  int K, Ksplit, lda, ldb, ldo;
  int sBz;
};

template<int BM, int BN, int EPI>
__global__ __launch_bounds__(256) void gemm_k(GP p){
  __shared__ unsigned short As[2][BM*32];
  __shared__ unsigned short Bs[2][BN*32];
  const int tid  = threadIdx.x;
  const int lane = tid & 63;
  const int wid  = tid >> 6;
  const int lr   = lane & 15;
  const int lg   = lane >> 4;
  constexpr int FM = BM/32, FN = BN/32;
  const int m0 = blockIdx.y * BM;
  const int n0 = blockIdx.x * BN;
  const int z  = blockIdx.z;

  const unsigned short* Abase = p.A;
  const unsigned short* Bbase = p.B;
  if constexpr (EPI==13){
    if (z==2){ if (blockIdx.y >= 32) return; Abase = p.A + 4194304; }
    if (z==3){ if (blockIdx.y >= 8)  return; Abase = p.A2; }
    const int zsel = (z==0)?1:((z==1)?2:((z==2)?0:3));
    Bbase = p.B + (long)zsel*1048576;
  }

  const int ksp = p.Ksplit ? p.Ksplit : p.K;
  const unsigned short* AbL = Abase + (long)m0*p.lda;
  const unsigned short* AbH = p.A2 && EPI!=13 ? (p.A2 + (long)m0*p.lda - ksp) : AbL;
  const unsigned short* BbL = Bbase + (long)z*p.sBz + (long)n0*p.ldb;
  const unsigned short* BbH = p.B2 ? (p.B2 + (long)z*p.sBz + (long)n0*p.ldb - ksp) : BbL;

  const int srow = tid >> 2;          // 0..63
  const int skk  = (tid & 3) * 8;

  f4 acc[FM][FN];
  f4 zero4 = {0.0f, 0.0f, 0.0f, 0.0f};
  #pragma unroll
  for (int m=0;m<FM;m++)
    #pragma unroll
    for (int n=0;n<FN;n++) acc[m][n] = zero4;

  const int nk = p.K >> 5;
  // prologue: stage tile 0 (k0=0 always < ksp)
  #pragma unroll
  for (int q=0;q<BM/64;q++)
    gl_lds(AbL + (long)(q*64 + srow)*p.lda + skk, (char*)As[0] + q*4096 + wid*1024);
  #pragma unroll
  for (int q=0;q<BN/64;q++)
    gl_lds(BbL + (long)(q*64 + srow)*p.ldb + skk, (char*)Bs[0] + q*4096 + wid*1024);
  __syncthreads();

  int cur = 0;
  for (int t = 0; t < nk; ++t){
    const int k1 = (t+1) << 5;
    if (t+1 < nk){
      const unsigned short* A_ = (k1 < ksp) ? AbL : AbH;
      const unsigned short* B_ = (k1 < ksp) ? BbL : BbH;
      #pragma unroll
      for (int q=0;q<BM/64;q++)
        gl_lds(A_ + (long)(q*64 + srow)*p.lda + k1 + skk, (char*)As[cur^1] + q*4096 + wid*1024);
      #pragma unroll
      for (int q=0;q<BN/64;q++)
        gl_lds(B_ + (long)(q*64 + srow)*p.ldb + k1 + skk, (char*)Bs[cur^1] + q*4096 + wid*1024);
    }
    bfrag af[FM], bfr[FN];
    #pragma unroll
    for (int m=0;m<FM;m++)
      af[m] = *(const bfrag*)&As[cur][((wid>>1)*(BM/2) + m*16 + lr)*32 + lg*8];
    #pragma unroll
    for (int n=0;n<FN;n++)
      bfr[n] = *(const bfrag*)&Bs[cur][((wid&1)*(BN/2) + n*16 + lr)*32 + lg*8];
    #pragma unroll
    for (int m=0;m<FM;m++)
      #pragma unroll
      for (int n=0;n<FN;n++)
        acc[m][n] = __builtin_amdgcn_mfma_f32_16x16x32_bf16(af[m], bfr[n], acc[m][n], 0, 0, 0);
    __syncthreads();   // drains vmcnt(0): tile t+1 resident; buffer cur reusable
    cur ^= 1;
  }

  const int wr0 = m0 + (wid>>1)*(BM/2);
  const int wc0 = n0 + (wid&1)*(BN/2);
  #pragma unroll
  for (int m=0;m<FM;m++)
    #pragma unroll
    for (int n=0;n<FN;n++)
      #pragma unroll
      for (int r=0;r<4;r++){
        const int gr = wr0 + m*16 + lg*4 + r;
        const int gc = wc0 + n*16 + lr;
        const float a = acc[m][n][r];
        const long base = (long)gr*p.ldo + gc;
        if constexpr (EPI==6){
          const float t = a + (p.bias1 ? p.bias1[gc] : 0.0f);
          p.O1[base] = f2bf(geluf(t));
        }
        else if constexpr (EPI==7){
          const float t = geluf(a + p.bias1[gc]);
          p.OF[base] = t; p.O1[base] = f2bf(t);
        }
        else if constexpr (EPI==11){
          const long ix = (long)gr*1024 + gc;
          if (z==0) p.O1[ix] = f2bf(sigm(a) * p.X[ix]);
          else      p.OF[ix] = sigm(a - 2.0f);
        }
        else if constexpr (EPI==12){
          const long ix = (long)gr*1024 + gc;
          const float zz = p.Z[ix];
          const float oo = (1.0f - zz)*p.X[ix] + zz*tanhf(a);
          p.OF[ix] = oo; p.O1[ix] = f2bf(oo);
        }
        else if constexpr (EPI==13){
          const long ix = (long)gr*1024 + gc;
          if (z==0){ p.O1[ix] = f2bf(a); }
          else if (z==1){
            const int b_ = gr & 7, js = gr >> 3, h_ = gc >> 6, d_ = gc & 63;
            p.O2[(long)(b_*16 + h_)*65536 + (long)d_*1024 + js] = f2bf(a);
          }
          else if (z==2){ p.O3[ix] = f2bf((a + p.bias1[gc])*0.125f);
                          p.O4[ix] = f2bf((a + p.bias2[gc])*0.125f); }
          else { p.O5[ix] = f2bf(a); }
        }
      }
}

// ---------------------------------------------------------------------------
// Fused relative attention. Block = one (b,h), 16 query rows [i0,i0+16).
// 4 waves; column mapping (interleaved pairs): col = half*512 + w*32 + t*128
// + sub*16, t<4, sub<2. In half1 only groups g = 2w+8t+sub <= i0/16 are ever
// unmasked -> skip the rest (s[] init -1e30 flows through softmax as 0).
// BDpre^T band in LDS, row stride 38B; shift-on-read:
//   half0: rr = jc - di + 15 (528 rows);  half1: rr = jc - di - 497
// Softmax over full row in regs; P staged per-32-col chunk into LDS; PV per
// wave over its valid chunks; cross-wave f32 merge.
// ---------------------------------------------------------------------------
__global__ __launch_bounds__(256,3) void attn_k(const unsigned short* __restrict__ qU,
                                                const unsigned short* __restrict__ qV,
                                                const unsigned short* __restrict__ kh,
                                                const unsigned short* __restrict__ rh,
                                                const unsigned short* __restrict__ vhT,
                                                unsigned short* __restrict__ ctx){
  __shared__ char Sm[20480];          // band (528*38=20064) / P-chunks (4KB) / po @4096 (16KB)
  __shared__ float redm[4][16];
  __shared__ float reds[4][16];
  __shared__ float invd[16];
  const int tid = threadIdx.x;
  const int w   = tid >> 6;
  const int lane= tid & 63;
  const int lr  = lane & 15;
  const int lg  = lane >> 4;
  const int id = blockIdx.x;
  const int b  = id & 7;              // id%8 -> XCD: per-b kh/vhT slice stays in one L2
  const int i0 = ((id >> 3) & 31) * 16;
  const int h  = id >> 8;
  const int gmax = i0 >> 4;           // last valid 16-col group in half1
  const long hoff = (long)h * 64;
  const f4 z4 = {0.f,0.f,0.f,0.f};

  // qV as B-operand (N=di) for band fill
  bfrag bqv[2];
  #pragma unroll
  for (int kk=0;kk<2;kk++)
    bqv[kk] = *(const bfrag*)(qV + ((long)(i0 + lr)*8 + b)*1024 + hoff + kk*32 + lg*8);
  // qU as A-operand (M=i) for AC
  bfrag aq[2];
  #pragma unroll
  for (int kk=0;kk<2;kk++)
    aq[kk] = *(const bfrag*)(qU + ((long)(i0 + lr)*8 + b)*1024 + hoff + kk*32 + lg*8);

  f4 s[16];
  #pragma unroll
  for (int n=0;n<16;n++) s[n] = (f4){-1e30f,-1e30f,-1e30f,-1e30f};

  #pragma unroll
  for (int half=0; half<2; ++half){
    const int c0    = half*512;
    const int rbase = half ? (1008 - i0) : (496 - i0);
    const int ntil  = half ? (gmax + 1) : 33;
    const int radd  = half ? -497 : 15;      // rr = jc - di + radd
    // ---- band fill: BDpre^T rows rr, cols di ----
    for (int mt = w; mt < ntil; mt += 4){
      const int r0 = rbase + mt*16;
      f4 acc = z4;
      #pragma unroll
      for (int kk=0;kk<2;kk++){
        bfrag ar = *(const bfrag*)(rh + (long)(r0 + lr)*1024 + hoff + kk*32 + lg*8);
        acc = __builtin_amdgcn_mfma_f32_16x16x32_bf16(ar, bqv[kk], acc, 0,0,0);
      }
      #pragma unroll
      for (int q=0;q<4;q++){
        const int rr = mt*16 + lg*4 + q;
        *(unsigned short*)(Sm + rr*38 + lr*2) = f2bf(acc[q]);
      }
    }
    __syncthreads();
    // ---- AC + BD for this wave's cols (skip fully-masked groups) ----
    #pragma unroll
    for (int n=0;n<8;n++){
      const int g = 2*w + ((n>>1)<<3) + (n&1);
      if (half==1 && g > gmax) continue;
      const int cb = c0 + w*32 + (n>>1)*128 + (n&1)*16;
      f4 a = z4;
      #pragma unroll
      for (int kk=0;kk<2;kk++){
        bfrag bk = *(const bfrag*)(kh + ((long)(cb + lr)*8 + b)*1024 + hoff + kk*32 + lg*8);
        a = __builtin_amdgcn_mfma_f32_16x16x32_bf16(aq[kk], bk, a, 0,0,0);
      }
      #pragma unroll
      for (int q=0;q<4;q++){
        const int di = lg*4 + q;
        const int jc = cb + lr;
        if (jc > i0 + di + 512) a[q] = -1e30f;
        else {
          const int rr = jc - di + radd;
          a[q] += bf2f(*(const unsigned short*)(Sm + rr*38 + di*2));
        }
      }
      s[half*8 + n] = a;
    }
    __syncthreads();   // all band reads done before next half / P staging
  }

  // ---- softmax stats over full 1024 cols ----
  float mx[4], sum[4];
  #pragma unroll
  for (int q=0;q<4;q++){
    float m = s[0][q];
    #pragma unroll
    for (int n=1;n<16;n++) m = fmaxf(m, s[n][q]);
    m = fmaxf(m, __shfl_xor(m, 1));
    m = fmaxf(m, __shfl_xor(m, 2));
    m = fmaxf(m, __shfl_xor(m, 4));
    m = fmaxf(m, __shfl_xor(m, 8));
    if (lr == 0) redm[w][lg*4+q] = m;
  }
  __syncthreads();
  #pragma unroll
  for (int q=0;q<4;q++){
    const int row = lg*4+q;
    mx[q] = fmaxf(fmaxf(redm[0][row], redm[1][row]), fmaxf(redm[2][row], redm[3][row]));
    sum[q] = 0.0f;
  }
  #pragma unroll
  for (int n=0;n<16;n++)
    #pragma unroll
    for (int q=0;q<4;q++){
      const float e = __expf(s[n][q] - mx[q]);
      s[n][q] = e;
      sum[q] += e;
    }
  #pragma unroll
  for (int q=0;q<4;q++){
    float v = sum[q];
    v += __shfl_xor(v, 1);
    v += __shfl_xor(v, 2);
    v += __shfl_xor(v, 4);
    v += __shfl_xor(v, 8);
    if (lr == 0) reds[w][lg*4+q] = v;
  }
  __syncthreads();
  if (tid < 16)
    invd[tid] = 1.0f / (reds[0][tid] + reds[1][tid] + reds[2][tid] + reds[3][tid]);

  // ---- PV: per-wave over its valid 32-col chunks, P staged in LDS ----
  f4 oac[4];
  #pragma unroll
  for (int nd=0;nd<4;nd++) oac[nd] = z4;
  const unsigned short* vb_base = vhT + (long)(b*16 + h)*65536;
  char* Pch = Sm + w*1024;            // [16 rows][32 cols] u16, swizzled
  #pragma unroll
  for (int t=0;t<8;t++){
    const int hh_ = t>>2, tt = t&3;
    if (hh_==1 && (2*w + 8*tt) > gmax) continue;   // both groups dead
    const int jb = hh_*512 + w*32 + tt*128;
    #pragma unroll
    for (int nn=0;nn<2;nn++){
      const f4 e = s[hh_*8 + tt*2 + nn];
      #pragma unroll
      for (int q=0;q<4;q++){
        const int row = lg*4 + q;
        const int col = nn*16 + lr;
        *(unsigned short*)(Pch + row*64 + ((col*2) ^ (((row>>2)&3)<<4))) = f2bf(e[q]);
      }
    }
    bfrag pa = *(const bfrag*)(Pch + lr*64 + ((lg*16) ^ (((lr>>2)&3)<<4)));
    #pragma unroll
    for (int nd=0;nd<4;nd++){
      bfrag bv = *(const bfrag*)(vb_base + (long)(nd*16 + lr)*1024 + jb + lg*8);
      oac[nd] = __builtin_amdgcn_mfma_f32_16x16x32_bf16(pa, bv, oac[nd], 0,0,0);
    }
  }
  // partial O to LDS
  float* po = (float*)(Sm + 4096 + w*4096);   // [16][64] f32
  #pragma unroll
  for (int nd=0;nd<4;nd++)
    #pragma unroll
    for (int q=0;q<4;q++)
      po[(lg*4+q)*64 + nd*16 + lr] = oac[nd][q];
  __syncthreads();
  // ---- merge + normalize + write ----
  {
    const int row = tid >> 4;
    const int d0  = (tid & 15) * 4;
    f4 v = *(const f4*)(Sm + 4096 + (row*64 + d0)*4);
    #pragma unroll
    for (int ww=1;ww<4;ww++){
      const f4 u = *(const f4*)(Sm + 4096 + ww*4096 + (row*64 + d0)*4);
      v.x += u.x; v.y += u.y; v.z += u.z; v.w += u.w;
    }
    const float iv = invd[row];
    u16x4 o;
    o.x = f2bf(v.x*iv); o.y = f2bf(v.y*iv); o.z = f2bf(v.z*iv); o.w = f2bf(v.w*iv);
    *(u16x4*)(ctx + ((long)(i0 + row)*8 + b)*1024 + hoff + d0) = o;
  }
}

// ---------------------------------------------------------------------------
__global__ __launch_bounds__(256) void ln_k(const float* __restrict__ srcA,
                                            const float* __restrict__ srcB, int splitRow,
                                            const float* __restrict__ g, const float* __restrict__ b,
                                            unsigned short* __restrict__ dst){
  const int row = blockIdx.x;
  const float* src = (srcB != nullptr && row >= splitRow)
                       ? (srcB + (long)(row - splitRow)*1024)
                       : (srcA + (long)row*1024);
  const int t = threadIdx.x;
  float4 v = ((const float4*)src)[t];
  float s1 = v.x+v.y+v.z+v.w;
  float s2 = v.x*v.x+v.y*v.y+v.z*v.z+v.w*v.w;
  #pragma unroll
  for (int o=32;o;o>>=1){ s1 += __shfl_xor(s1,o); s2 += __shfl_xor(s2,o); }
  __shared__ float r1[4], r2[4];
  const int w = t>>6;
  if ((t&63)==0){ r1[w]=s1; r2[w]=s2; }
  __syncthreads();
  s1 = r1[0]+r1[1]+r1[2]+r1[3];
  s2 = r2[0]+r2[1]+r2[2]+r2[3];
  const float mean = s1*(1.0f/1024.0f);
  const float var  = s2*(1.0f/1024.0f) - mean*mean;
  const float rs   = rsqrtf(var + 1e-5f);
  float4 gg = ((const float4*)g)[t];
  float4 bb = ((const float4*)b)[t];
  u16x4 o;
  o.x = f2bf((v.x-mean)*rs*gg.x + bb.x);
  o.y = f2bf((v.y-mean)*rs*gg.y + bb.y);
  o.z = f2bf((v.z-mean)*rs*gg.z + bb.z);
  o.w = f2bf((v.w-mean)*rs*gg.w + bb.w);
  *(u16x4*)(dst + (long)row*1024 + t*4) = o;
}

__global__ __launch_bounds__(256) void conv_k(const float* __restrict__ s,
                                              unsigned short* __restrict__ d, long n){
  long i = ((long)blockIdx.x*256 + threadIdx.x)*4;
  if (i >= n) return;
  float4 v = *(const float4*)(s + i);
  u16x4 o; o.x=f2bf(v.x); o.y=f2bf(v.y); o.z=f2bf(v.z); o.w=f2bf(v.w);
  *(u16x4*)(d + i) = o;
}

__global__ __launch_bounds__(128) void ht_k(const float* __restrict__ h,
                                            unsigned short* __restrict__ d){
  const int row = blockIdx.x;           // i*8+b
  const int i = row>>3, b = row&7;
  const float* src = h + ((long)b*512 + i)*512;
  const int t = threadIdx.x;
  float4 v = ((const float4*)src)[t];
  u16x4 o; o.x=f2bf(v.x); o.y=f2bf(v.y); o.z=f2bf(v.z); o.w=f2bf(v.w);
  *(u16x4*)(d + (long)row*512 + t*4) = o;
}

__global__ __launch_bounds__(256) void pos_k(unsigned short* __restrict__ d){
  const int r = blockIdx.x, t = threadIdx.x;
  const float seq = (float)(1023 - r);
  u16x4 o;
  #pragma unroll
  for (int q=0;q<4;q++){
    const int c = t*4 + q;
    const int f = (c < 512) ? c : (c - 512);
    const float inv = expf((float)f * -0.017988946039016f); // -2*ln(1e4)/1024
    const float ang = seq * inv;
    const float val = (c < 512) ? sinf(ang) : cosf(ang);
    o[q] = f2bf(val);
  }
  *(u16x4*)(d + (long)r*1024 + t*4) = o;
}

__global__ __launch_bounds__(256) void outT_k(const float* __restrict__ o,
                                              float* __restrict__ d){
  const int row = blockIdx.x;   // b*512 + i
  const int b = row>>9, i = row&511;
  const float4 v = ((const float4*)(o + ((long)i*8 + b)*1024))[threadIdx.x];
  ((float4*)(d + (long)row*1024))[threadIdx.x] = v;
}

// ---------------------------------------------------------------------------
extern "C" void kernel_launch(void* const* d_in, const int* in_sizes, int n_in,
                              void* d_out, int out_size, void* d_ws, size_t ws_size,
                              hipStream_t stream){
  (void)in_sizes; (void)n_in; (void)out_size; (void)ws_size;
  const float* h     = (const float*)d_in[0];
  const float* memin = (const float*)d_in[1];
  const float* Wemb  = (const float*)d_in[2];
  const float* bemb  = (const float*)d_in[3];
  const float* Ub    = (const float*)d_in[4];
  const float* Vb    = (const float*)d_in[5];
  const float* ln1   = (const float*)d_in[6];
  const float* ln2   = (const float*)d_in[7];
  const float* Wattn = (const float*)d_in[8];
  const float* g1w   = (const float*)d_in[9];
  const float* g2w   = (const float*)d_in[10];
  const float* fw1   = (const float*)d_in[11];
  const float* fb1   = (const float*)d_in[12];
  const float* fw2   = (const float*)d_in[13];
  const float* fb2   = (const float*)d_in[14];

  char* Wp = (char*)d_ws;
  size_t off = 0;
  auto take = [&](size_t bytes)->size_t{ size_t r = off; off += (bytes + 255) & ~(size_t)255; return r; };
  float*          outf = (float*)         (Wp + take(16777216)); // out (cur*bs, D) f32
  unsigned short* xbf  = (unsigned short*)(Wp + take( 8388608)); // out bf16
  float*          o1f  = (float*)         (Wp + take(16777216));
  unsigned short* o1b  = (unsigned short*)(Wp + take( 8388608));
  float*          zbf  = (float*)         (Wp + take(16777216)); // gru z-gate f32
  unsigned short* rxb  = (unsigned short*)(Wp + take( 8388608)); // r*x bf16
  unsigned short* yb   = (unsigned short*)(Wp + take( 8388608)); // Y / E2 bf16
  unsigned short* Eb   = (unsigned short*)(Wp + take( 8388608)); // LN2 out bf16
  unsigned short* wb0  = (unsigned short*)(Wp + take(52428800)); // layer weights bf16
  unsigned short* hTb  = (unsigned short*)(Wp + take( 4194304));
  unsigned short* webb = (unsigned short*)(Wp + take( 1048576));
  unsigned short* posb = (unsigned short*)(Wp + take( 2097152));
  unsigned short* nkb  = (unsigned short*)(Wp + take(16777216)); // LN'd key (full*bs, D)
  unsigned short* qUb  = (unsigned short*)(Wp + take( 8388608));
  unsigned short* qVb  = (unsigned short*)(Wp + take( 8388608));
  unsigned short* khb  = (unsigned short*)(Wp + take(16777216));
  unsigned short* vhTb = (unsigned short*)(Wp + take(16777216));
  unsigned short* F1b  = khb; // FF hidden (32MB) overlaps khb+vhTb (phase-disjoint)
  unsigned short* rhb  = (unsigned short*)(Wp + take( 2097152));
  unsigned short* ctxb = (unsigned short*)(Wp + take( 8388608));

  const int M1 = 1048576; // D*D elements

  // one-time prep
  conv_k<<<512, 256, 0, stream>>>(Wemb, webb, 524288);
  ht_k<<<4096, 128, 0, stream>>>(h, hTb);
  pos_k<<<1024, 256, 0, stream>>>(posb);

  { // embed: out = gelu(h @ Wemb^T + bemb)  (f32 + bf16)
    GP p{}; p.A=hTb; p.B=webb; p.OF=outf; p.O1=xbf; p.bias1=bemb;
    p.K=512; p.lda=512; p.ldb=512; p.ldo=1024;
    gemm_k<128,64,7><<<dim3(16,32,1),256,0,stream>>>(p);
  }

  // GRU (2 launches, K=2048 concat): x=xb/xf, y=yb_, weights w6 = [Wr,Ur,Wz,Uz,Wg,Ug]
  auto gru_fn = [&](const unsigned short* xb, const float* xf, const unsigned short* yb_,
                    const unsigned short* w6, float* of, unsigned short* ob){
    { GP p{}; p.A=yb_; p.A2=xb; p.B=w6; p.B2=w6+M1; p.sBz=2*M1;
      p.O1=rxb; p.OF=zbf; p.X=xf;
      p.K=2048; p.Ksplit=1024; p.lda=1024; p.ldb=1024; p.ldo=1024;
      gemm_k<128,128,11><<<dim3(8,32,2),256,0,stream>>>(p); }
    { GP p{}; p.A=yb_; p.A2=rxb; p.B=w6+4*M1; p.B2=w6+5*M1;
      p.X=xf; p.Z=zbf; p.OF=of; p.O1=ob;
      p.K=2048; p.Ksplit=1024; p.lda=1024; p.ldb=1024; p.ldo=1024;
      gemm_k<128,64,12><<<dim3(16,32,1),256,0,stream>>>(p); }
  };

  for (int l = 0; l < 4; ++l){
    // layer weights -> bf16
    conv_k<<<5120,256,0,stream>>>(Wattn + (long)l*5242880, wb0,          5242880);
    conv_k<<<6144,256,0,stream>>>(g1w   + (long)l*6291456, wb0 +  5*M1,  6291456);
    conv_k<<<6144,256,0,stream>>>(g2w   + (long)l*6291456, wb0 + 11*M1,  6291456);
    conv_k<<<4096,256,0,stream>>>(fw1   + (long)l*4194304, wb0 + 17*M1,  4194304);
    conv_k<<<4096,256,0,stream>>>(fw2   + (long)l*4194304, wb0 + 21*M1,  4194304);

    // nk = LN(concat(mem[l], out)); rows [4096:8192) are nq
    ln_k<<<8192,256,0,stream>>>(memin + (long)l*4194304, outf, 4096,
                                ln1 + l*2048, ln1 + l*2048 + 1024, nkb);

    { // fused QKV + R: z=0 kh, z=1 vhT, z=2 qU/qV (*0.125), z=3 rh
      GP p{}; p.A=nkb; p.A2=posb; p.B=wb0;
      p.O1=khb; p.O2=vhTb; p.O3=qUb; p.O4=qVb; p.O5=rhb;
      p.bias1=Ub; p.bias2=Vb;
      p.K=1024; p.lda=1024; p.ldb=1024; p.ldo=1024;
      gemm_k<128,128,13><<<dim3(8,64,4),256,0,stream>>>(p); }

    attn_k<<<4096,256,0,stream>>>(qUb, qVb, khb, rhb, vhTb, ctxb);

    { // Y = gelu(ctx @ Wo^T)
      GP p{}; p.A=ctxb; p.B=wb0+4*M1; p.O1=yb;
      p.K=1024; p.lda=1024; p.ldb=1024; p.ldo=1024;
      gemm_k<128,64,6><<<dim3(16,32,1),256,0,stream>>>(p); }

    gru_fn(xbf, outf, yb, wb0 + 5*M1, o1f, o1b);

    ln_k<<<4096,256,0,stream>>>(o1f, nullptr, 1<<30,
                                ln2 + l*2048, ln2 + l*2048 + 1024, Eb);

    { GP p{}; p.A=Eb;  p.B=wb0+17*M1; p.O1=F1b; p.bias1=fb1 + l*4096;
      p.K=1024; p.lda=1024; p.ldb=1024; p.ldo=4096;
      gemm_k<128,128,6><<<dim3(32,32,1),256,0,stream>>>(p); }
    { GP p{}; p.A=F1b; p.B=wb0+21*M1; p.O1=yb; p.bias1=fb2 + l*1024;
      p.K=4096; p.lda=4096; p.ldb=4096; p.ldo=1024;
      gemm_k<128,64,6><<<dim3(16,32,1),256,0,stream>>>(p); }

    gru_fn(o1b, o1f, yb, wb0 + 11*M1, outf, xbf);
  }

  outT_k<<<4096,256,0,stream>>>(outf, (float*)d_out);
}

// Round 6
// 2733.193 us; speedup vs baseline: 2.0024x; 1.0071x over previous
//
#include <hip/hip_runtime.h>
#include <hip/hip_bf16.h>

// Gated Transformer-XL forward.
// Dims: L=4, D=1024, NH=16, HD=64, CUR=512, MEM=512, BS=8, IN=512, FF=4096, FULL=1024
// Activation layout: (seq*BS, D), row = i*BS + b.

typedef __attribute__((ext_vector_type(8))) __bf16 bfrag;
typedef __attribute__((ext_vector_type(4))) float f4;
typedef __attribute__((ext_vector_type(4))) unsigned short u16x4;
typedef __attribute__((ext_vector_type(8))) unsigned short u16x8;

__device__ __forceinline__ unsigned short f2bf(float f){
  union { float f; unsigned u; } v; v.f = f;
  unsigned r = v.u + 0x7fffu + ((v.u >> 16) & 1u);
  return (unsigned short)(r >> 16);
}
__device__ __forceinline__ float bf2f(unsigned short u){
  union { unsigned u; float f; } v; v.u = (unsigned)u << 16; return v.f;
}
__device__ __forceinline__ float geluf(float x){
  return 0.5f * x * (1.0f + erff(x * 0.7071067811865476f));
}
__device__ __forceinline__ float sigm(float x){ return 1.0f/(1.0f + __expf(-x)); }

__device__ __forceinline__ void gl_lds(const void* g, void* l){
  __builtin_amdgcn_global_load_lds(
    reinterpret_cast<const __attribute__((address_space(1))) unsigned int*>(
        reinterpret_cast<unsigned long>(g)),
    reinterpret_cast<__attribute__((address_space(3))) unsigned int*>(
        reinterpret_cast<unsigned long>(l)),
    16, 0, 0);
}

// ---------------------------------------------------------------------------
// Dense GEMM: C[M,N] = A[M,K] @ B[N,K]^T (bf16, row-major). Optional K-concat.
// BK=64 mega-steps: two BK=32 sub-tiles staged per barrier (4 LDS buffers);
// stage mega-tile t+1 before computing tile t; ONE barrier per 64-K.
// EPI: 6  O1 = bf(gelu(acc + bias1))
//      7  OF = gelu(acc+bias1) f32, O1 = bf16 of same          (embed)
//      11 z==0: O1 = bf(sigm(acc) * X)   (GRU r-gate * x)
//         z==1: OF = sigm(acc - 2)       (GRU z-gate)
//      12 o = (1-Z)*X + Z*tanh(acc); OF = o; O1 = bf(o)        (GRU combine)
//      13 fused QKV+R: z=0 kh, z=1 vhT-scatter, z=2 qU/qV(+bias, *0.125), z=3 rh
// ---------------------------------------------------------------------------
struct GP {
  const unsigned short* A;
  const unsigned short* A2;
  const unsigned short* B;
  const unsigned short* B2;
  unsigned short* O1;
  unsigned short* O2;
  unsigned short* O3;
  unsigned short* O4;
  unsigned short* O5;
  float* OF;
  const float* bias1;
  const float* bias2;
  const float* X;
  const float* Z;
  int K, Ksplit, lda, ldb, ldo;
  int sBz;
};

template<int BM, int BN, int EPI>
__global__ __launch_bounds__(256) void gemm_k(GP p){
  __shared__ unsigned short As[2][2][BM*32];
  __shared__ unsigned short Bs[2][2][BN*32];
  const int tid  = threadIdx.x;
  const int lane = tid & 63;
  const int wid  = tid >> 6;
  const int lr   = lane & 15;
  const int lg   = lane >> 4;
  constexpr int FM = BM/32, FN = BN/32;
  const int m0 = blockIdx.y * BM;
  const int n0 = blockIdx.x * BN;
  const int z  = blockIdx.z;

  const unsigned short* Abase = p.A;
  const unsigned short* Bbase = p.B;
  if constexpr (EPI==13){
    if (z==2){ if (blockIdx.y >= 32) return; Abase = p.A + 4194304; }
    if (z==3){ if (blockIdx.y >= 8)  return; Abase = p.A2; }
    const int zsel = (z==0)?1:((z==1)?2:((z==2)?0:3));
    Bbase = p.B + (long)zsel*1048576;
  }

  const int ksp = p.Ksplit ? p.Ksplit : p.K;
  const unsigned short* AbL = Abase + (long)m0*p.lda;
  const unsigned short* AbH = p.A2 && EPI!=13 ? (p.A2 + (long)m0*p.lda - ksp) : AbL;
  const unsigned short* BbL = Bbase + (long)z*p.sBz + (long)n0*p.ldb;
  const unsigned short* BbH = p.B2 ? (p.B2 + (long)z*p.sBz + (long)n0*p.ldb - ksp) : BbL;

  const int srow = tid >> 2;          // 0..63
  const int skk  = (tid & 3) * 8;

  f4 acc[FM][FN];
  f4 zero4 = {0.0f, 0.0f, 0.0f, 0.0f};
  #pragma unroll
  for (int m=0;m<FM;m++)
    #pragma unroll
    for (int n=0;n<FN;n++) acc[m][n] = zero4;

  auto stage = [&](int buf, int sub, int k0){
    const unsigned short* A_ = (k0 < ksp) ? AbL : AbH;
    #pragma unroll
    for (int q=0;q<BM/64;q++)
      gl_lds(A_ + (long)(q*64 + srow)*p.lda + k0 + skk, (char*)As[buf][sub] + q*4096 + wid*1024);
    const unsigned short* B_ = (k0 < ksp) ? BbL : BbH;
    #pragma unroll
    for (int q=0;q<BN/64;q++)
      gl_lds(B_ + (long)(q*64 + srow)*p.ldb + k0 + skk, (char*)Bs[buf][sub] + q*4096 + wid*1024);
  };

  const int nk2 = p.K >> 6;
  stage(0,0,0); stage(0,1,32);
  __syncthreads();

  int cur = 0;
  for (int t = 0; t < nk2; ++t){
    if (t+1 < nk2){
      stage(cur^1, 0, (t+1)*64);
      stage(cur^1, 1, (t+1)*64 + 32);
    }
    #pragma unroll
    for (int sub=0; sub<2; ++sub){
      bfrag af[FM], bfr[FN];
      #pragma unroll
      for (int m=0;m<FM;m++)
        af[m] = *(const bfrag*)&As[cur][sub][((wid>>1)*(BM/2) + m*16 + lr)*32 + lg*8];
      #pragma unroll
      for (int n=0;n<FN;n++)
        bfr[n] = *(const bfrag*)&Bs[cur][sub][((wid&1)*(BN/2) + n*16 + lr)*32 + lg*8];
      #pragma unroll
      for (int m=0;m<FM;m++)
        #pragma unroll
        for (int n=0;n<FN;n++)
          acc[m][n] = __builtin_amdgcn_mfma_f32_16x16x32_bf16(af[m], bfr[n], acc[m][n], 0, 0, 0);
    }
    __syncthreads();   // drains vmcnt(0): mega-tile t+1 resident; buffers reusable
    cur ^= 1;
  }

  const int wr0 = m0 + (wid>>1)*(BM/2);
  const int wc0 = n0 + (wid&1)*(BN/2);
  #pragma unroll
  for (int m=0;m<FM;m++)
    #pragma unroll
    for (int n=0;n<FN;n++)
      #pragma unroll
      for (int r=0;r<4;r++){
        const int gr = wr0 + m*16 + lg*4 + r;
        const int gc = wc0 + n*16 + lr;
        const float a = acc[m][n][r];
        const long base = (long)gr*p.ldo + gc;
        if constexpr (EPI==6){
          const float t = a + (p.bias1 ? p.bias1[gc] : 0.0f);
          p.O1[base] = f2bf(geluf(t));
        }
        else if constexpr (EPI==7){
          const float t = geluf(a + p.bias1[gc]);
          p.OF[base] = t; p.O1[base] = f2bf(t);
        }
        else if constexpr (EPI==11){
          const long ix = (long)gr*1024 + gc;
          if (z==0) p.O1[ix] = f2bf(sigm(a) * p.X[ix]);
          else      p.OF[ix] = sigm(a - 2.0f);
        }
        else if constexpr (EPI==12){
          const long ix = (long)gr*1024 + gc;
          const float zz = p.Z[ix];
          const float oo = (1.0f - zz)*p.X[ix] + zz*tanhf(a);
          p.OF[ix] = oo; p.O1[ix] = f2bf(oo);
        }
        else if constexpr (EPI==13){
          const long ix = (long)gr*1024 + gc;
          if (z==0){ p.O1[ix] = f2bf(a); }
          else if (z==1){
            const int b_ = gr & 7, js = gr >> 3, h_ = gc >> 6, d_ = gc & 63;
            p.O2[(long)(b_*16 + h_)*65536 + (long)d_*1024 + js] = f2bf(a);
          }
          else if (z==2){ p.O3[ix] = f2bf((a + p.bias1[gc])*0.125f);
                          p.O4[ix] = f2bf((a + p.bias2[gc])*0.125f); }
          else { p.O5[ix] = f2bf(a); }
        }
      }
}

// ---------------------------------------------------------------------------
// Fused relative attention. Block = one (b,h), 16 query rows [i0,i0+16).
// 4 waves; column mapping (interleaved pairs): col = half*512 + w*32 + t*128
// + sub*16. In half1 only groups g = 2w+8t+sub <= gmax are unmasked -> valid
// n form a prefix; skipped entries set to -1e30 (exp -> 0).
// BDpre^T band in LDS, row stride 38B; shift-on-read:
//   half0: rr = jc - di + 15 (528 rows);  half1: rr = jc - di - 497
// Software prefetch: rh 1 band-iter ahead; kh 1 group ahead; vhT t=0
// pre-issued before softmax, next-t issued after each MFMA cluster.
// ---------------------------------------------------------------------------
__global__ __launch_bounds__(256,4) void attn_k(const unsigned short* __restrict__ qU,
                                                const unsigned short* __restrict__ qV,
                                                const unsigned short* __restrict__ kh,
                                                const unsigned short* __restrict__ rh,
                                                const unsigned short* __restrict__ vhT,
                                                unsigned short* __restrict__ ctx){
  __shared__ char Sm[20480];          // band (528*38=20064) / P-chunks (4KB) / po @4096 (16KB)
  __shared__ float redm[4][16];
  __shared__ float reds[4][16];
  __shared__ float invd[16];
  const int tid = threadIdx.x;
  const int w   = tid >> 6;
  const int lane= tid & 63;
  const int lr  = lane & 15;
  const int lg  = lane >> 4;
  const int id = blockIdx.x;
  const int b  = id & 7;              // id%8 -> XCD: per-b kh/vhT slice stays in one L2
  const int i0 = ((id >> 3) & 31) * 16;
  const int h  = id >> 8;
  const int gmax = i0 >> 4;           // last valid 16-col group in half1
  const long hoff = (long)h * 64;
  const f4 z4 = {0.f,0.f,0.f,0.f};

  // qV as B-operand (N=di) for band fill
  bfrag bqv[2];
  #pragma unroll
  for (int kk=0;kk<2;kk++)
    bqv[kk] = *(const bfrag*)(qV + ((long)(i0 + lr)*8 + b)*1024 + hoff + kk*32 + lg*8);
  // qU as A-operand (M=i) for AC
  bfrag aq[2];
  #pragma unroll
  for (int kk=0;kk<2;kk++)
    aq[kk] = *(const bfrag*)(qU + ((long)(i0 + lr)*8 + b)*1024 + hoff + kk*32 + lg*8);

  f4 s[16];   // filled: half0 -> s[0..7], half1 -> s[8..15] (lazy, keeps VGPR low)

  #pragma unroll
  for (int half=0; half<2; ++half){
    const int c0    = half*512;
    const int rbase = half ? (1008 - i0) : (496 - i0);
    const int ntil  = half ? (gmax + 1) : 33;
    const int radd  = half ? -497 : 15;      // rr = jc - di + radd
    // ---- band fill: BDpre^T rows rr, cols di (rh prefetched 1 iter ahead) ----
    bfrag ar[2][2];
    if (w < ntil){
      #pragma unroll
      for (int kk=0;kk<2;kk++)
        ar[0][kk] = *(const bfrag*)(rh + (long)(rbase + w*16 + lr)*1024 + hoff + kk*32 + lg*8);
    }
    #pragma unroll
    for (int it=0; it<9; ++it){
      const int mt = w + it*4;
      if (mt < ntil){
        const int mtn = mt + 4;
        if (mtn < ntil){
          #pragma unroll
          for (int kk=0;kk<2;kk++)
            ar[(it+1)&1][kk] = *(const bfrag*)(rh + (long)(rbase + mtn*16 + lr)*1024 + hoff + kk*32 + lg*8);
        }
        f4 acc = z4;
        #pragma unroll
        for (int kk=0;kk<2;kk++)
          acc = __builtin_amdgcn_mfma_f32_16x16x32_bf16(ar[it&1][kk], bqv[kk], acc, 0,0,0);
        #pragma unroll
        for (int q=0;q<4;q++){
          const int rr = mt*16 + lg*4 + q;
          *(unsigned short*)(Sm + rr*38 + lr*2) = f2bf(acc[q]);
        }
      }
    }
    __syncthreads();
    // ---- AC + BD (kh prefetched 1 group ahead; valid groups form a prefix) ----
    int nv = 8;
    if (half==1){
      nv = 0;
      #pragma unroll
      for (int n=0;n<8;n++)
        if ((2*w + 8*(n>>1) + (n&1)) <= gmax) nv++;
    }
    bfrag bk[2][2];
    if (nv > 0){
      const int cb0 = c0 + w*32;
      #pragma unroll
      for (int kk=0;kk<2;kk++)
        bk[0][kk] = *(const bfrag*)(kh + ((long)(cb0 + lr)*8 + b)*1024 + hoff + kk*32 + lg*8);
    }
    #pragma unroll
    for (int n=0;n<8;n++){
      if (n+1 < nv){
        const int cbn = c0 + w*32 + ((n+1)>>1)*128 + ((n+1)&1)*16;
        #pragma unroll
        for (int kk=0;kk<2;kk++)
          bk[(n+1)&1][kk] = *(const bfrag*)(kh + ((long)(cbn + lr)*8 + b)*1024 + hoff + kk*32 + lg*8);
      }
      if (n < nv){
        const int cb = c0 + w*32 + (n>>1)*128 + (n&1)*16;
        f4 a = z4;
        #pragma unroll
        for (int kk=0;kk<2;kk++)
          a = __builtin_amdgcn_mfma_f32_16x16x32_bf16(aq[kk], bk[n&1][kk], a, 0,0,0);
        #pragma unroll
        for (int q=0;q<4;q++){
          const int di = lg*4 + q;
          const int jc = cb + lr;
          if (jc > i0 + di + 512) a[q] = -1e30f;
          else {
            const int rr = jc - di + radd;
            a[q] += bf2f(*(const unsigned short*)(Sm + rr*38 + di*2));
          }
        }
        s[half*8 + n] = a;
      } else {
        s[half*8 + n] = (f4){-1e30f,-1e30f,-1e30f,-1e30f};
      }
    }
    __syncthreads();   // all band reads done before next half / P staging
  }

  // ---- pre-issue vhT for t=0 (hides under softmax) ----
  const unsigned short* vb_base = vhT + (long)(b*16 + h)*65536;
  bfrag vb[4];
  #pragma unroll
  for (int nd=0;nd<4;nd++)
    vb[nd] = *(const bfrag*)(vb_base + (long)(nd*16 + lr)*1024 + (w*32) + lg*8);

  // ---- softmax stats over full 1024 cols ----
  float mx[4], sum[4];
  #pragma unroll
  for (int q=0;q<4;q++){
    float m = s[0][q];
    #pragma unroll
    for (int n=1;n<16;n++) m = fmaxf(m, s[n][q]);
    m = fmaxf(m, __shfl_xor(m, 1));
    m = fmaxf(m, __shfl_xor(m, 2));
    m = fmaxf(m, __shfl_xor(m, 4));
    m = fmaxf(m, __shfl_xor(m, 8));
    if (lr == 0) redm[w][lg*4+q] = m;
  }
  __syncthreads();
  #pragma unroll
  for (int q=0;q<4;q++){
    const int row = lg*4+q;
    mx[q] = fmaxf(fmaxf(redm[0][row], redm[1][row]), fmaxf(redm[2][row], redm[3][row]));
    sum[q] = 0.0f;
  }
  #pragma unroll
  for (int n=0;n<16;n++)
    #pragma unroll
    for (int q=0;q<4;q++){
      const float e = __expf(s[n][q] - mx[q]);
      s[n][q] = e;
      sum[q] += e;
    }
  #pragma unroll
  for (int q=0;q<4;q++){
    float v = sum[q];
    v += __shfl_xor(v, 1);
    v += __shfl_xor(v, 2);
    v += __shfl_xor(v, 4);
    v += __shfl_xor(v, 8);
    if (lr == 0) reds[w][lg*4+q] = v;
  }
  __syncthreads();
  if (tid < 16)
    invd[tid] = 1.0f / (reds[0][tid] + reds[1][tid] + reds[2][tid] + reds[3][tid]);

  // ---- PV: per-wave over its valid 32-col chunks, P staged in LDS ----
  f4 oac[4];
  #pragma unroll
  for (int nd=0;nd<4;nd++) oac[nd] = z4;
  char* Pch = Sm + w*1024;            // [16 rows][32 cols] u16, swizzled
  #pragma unroll
  for (int t=0;t<8;t++){
    const int hh_ = t>>2, tt = t&3;
    const bool val = (hh_==0) || ((2*w + 8*tt) <= gmax);
    if (val){
      #pragma unroll
      for (int nn=0;nn<2;nn++){
        const f4 e = s[hh_*8 + tt*2 + nn];
        #pragma unroll
        for (int q=0;q<4;q++){
          const int row = lg*4 + q;
          const int col = nn*16 + lr;
          *(unsigned short*)(Pch + row*64 + ((col*2) ^ (((row>>2)&3)<<4))) = f2bf(e[q]);
        }
      }
      bfrag pa = *(const bfrag*)(Pch + lr*64 + ((lg*16) ^ (((lr>>2)&3)<<4)));
      #pragma unroll
      for (int nd=0;nd<4;nd++)
        oac[nd] = __builtin_amdgcn_mfma_f32_16x16x32_bf16(pa, vb[nd], oac[nd], 0,0,0);
    }
    if (t+1 < 8){
      const int h2 = (t+1)>>2, t2 = (t+1)&3;
      const bool v2 = (h2==0) || ((2*w + 8*t2) <= gmax);
      if (v2){
        const int jb2 = h2*512 + w*32 + t2*128;
        #pragma unroll
        for (int nd=0;nd<4;nd++)
          vb[nd] = *(const bfrag*)(vb_base + (long)(nd*16 + lr)*1024 + jb2 + lg*8);
      }
    }
  }
  // partial O to LDS
  float* po = (float*)(Sm + 4096 + w*4096);   // [16][64] f32
  #pragma unroll
  for (int nd=0;nd<4;nd++)
    #pragma unroll
    for (int q=0;q<4;q++)
      po[(lg*4+q)*64 + nd*16 + lr] = oac[nd][q];
  __syncthreads();
  // ---- merge + normalize + write ----
  {
    const int row = tid >> 4;
    const int d0  = (tid & 15) * 4;
    f4 v = *(const f4*)(Sm + 4096 + (row*64 + d0)*4);
    #pragma unroll
    for (int ww=1;ww<4;ww++){
      const f4 u = *(const f4*)(Sm + 4096 + ww*4096 + (row*64 + d0)*4);
      v.x += u.x; v.y += u.y; v.z += u.z; v.w += u.w;
    }
    const float iv = invd[row];
    u16x4 o;
    o.x = f2bf(v.x*iv); o.y = f2bf(v.y*iv); o.z = f2bf(v.z*iv); o.w = f2bf(v.w*iv);
    *(u16x4*)(ctx + ((long)(i0 + row)*8 + b)*1024 + hoff + d0) = o;
  }
}

// ---------------------------------------------------------------------------
__global__ __launch_bounds__(256) void ln_k(const float* __restrict__ srcA,
                                            const float* __restrict__ srcB, int splitRow,
                                            const float* __restrict__ g, const float* __restrict__ b,
                                            unsigned short* __restrict__ dst){
  const int row = blockIdx.x;
  const float* src = (srcB != nullptr && row >= splitRow)
                       ? (srcB + (long)(row - splitRow)*1024)
                       : (srcA + (long)row*1024);
  const int t = threadIdx.x;
  float4 v = ((const float4*)src)[t];
  float s1 = v.x+v.y+v.z+v.w;
  float s2 = v.x*v.x+v.y*v.y+v.z*v.z+v.w*v.w;
  #pragma unroll
  for (int o=32;o;o>>=1){ s1 += __shfl_xor(s1,o); s2 += __shfl_xor(s2,o); }
  __shared__ float r1[4], r2[4];
  const int w = t>>6;
  if ((t&63)==0){ r1[w]=s1; r2[w]=s2; }
  __syncthreads();
  s1 = r1[0]+r1[1]+r1[2]+r1[3];
  s2 = r2[0]+r2[1]+r2[2]+r2[3];
  const float mean = s1*(1.0f/1024.0f);
  const float var  = s2*(1.0f/1024.0f) - mean*mean;
  const float rs   = rsqrtf(var + 1e-5f);
  float4 gg = ((const float4*)g)[t];
  float4 bb = ((const float4*)b)[t];
  u16x4 o;
  o.x = f2bf((v.x-mean)*rs*gg.x + bb.x);
  o.y = f2bf((v.y-mean)*rs*gg.y + bb.y);
  o.z = f2bf((v.z-mean)*rs*gg.z + bb.z);
  o.w = f2bf((v.w-mean)*rs*gg.w + bb.w);
  *(u16x4*)(dst + (long)row*1024 + t*4) = o;
}

__global__ __launch_bounds__(256) void conv_k(const float* __restrict__ s,
                                              unsigned short* __restrict__ d, long n){
  long i = ((long)blockIdx.x*256 + threadIdx.x)*4;
  if (i >= n) return;
  float4 v = *(const float4*)(s + i);
  u16x4 o; o.x=f2bf(v.x); o.y=f2bf(v.y); o.z=f2bf(v.z); o.w=f2bf(v.w);
  *(u16x4*)(d + i) = o;
}

__global__ __launch_bounds__(128) void ht_k(const float* __restrict__ h,
                                            unsigned short* __restrict__ d){
  const int row = blockIdx.x;           // i*8+b
  const int i = row>>3, b = row&7;
  const float* src = h + ((long)b*512 + i)*512;
  const int t = threadIdx.x;
  float4 v = ((const float4*)src)[t];
  u16x4 o; o.x=f2bf(v.x); o.y=f2bf(v.y); o.z=f2bf(v.z); o.w=f2bf(v.w);
  *(u16x4*)(d + (long)row*512 + t*4) = o;
}

__global__ __launch_bounds__(256) void pos_k(unsigned short* __restrict__ d){
  const int r = blockIdx.x, t = threadIdx.x;
  const float seq = (float)(1023 - r);
  u16x4 o;
  #pragma unroll
  for (int q=0;q<4;q++){
    const int c = t*4 + q;
    const int f = (c < 512) ? c : (c - 512);
    const float inv = expf((float)f * -0.017988946039016f); // -2*ln(1e4)/1024
    const float ang = seq * inv;
    const float val = (c < 512) ? sinf(ang) : cosf(ang);
    o[q] = f2bf(val);
  }
  *(u16x4*)(d + (long)r*1024 + t*4) = o;
}

__global__ __launch_bounds__(256) void outT_k(const float* __restrict__ o,
                                              float* __restrict__ d){
  const int row = blockIdx.x;   // b*512 + i
  const int b = row>>9, i = row&511;
  const float4 v = ((const float4*)(o + ((long)i*8 + b)*1024))[threadIdx.x];
  ((float4*)(d + (long)row*1024))[threadIdx.x] = v;
}

// ---------------------------------------------------------------------------
extern "C" void kernel_launch(void* const* d_in, const int* in_sizes, int n_in,
                              void* d_out, int out_size, void* d_ws, size_t ws_size,
                              hipStream_t stream){
  (void)in_sizes; (void)n_in; (void)out_size; (void)ws_size;
  const float* h     = (const float*)d_in[0];
  const float* memin = (const float*)d_in[1];
  const float* Wemb  = (const float*)d_in[2];
  const float* bemb  = (const float*)d_in[3];
  const float* Ub    = (const float*)d_in[4];
  const float* Vb    = (const float*)d_in[5];
  const float* ln1   = (const float*)d_in[6];
  const float* ln2   = (const float*)d_in[7];
  const float* Wattn = (const float*)d_in[8];
  const float* g1w   = (const float*)d_in[9];
  const float* g2w   = (const float*)d_in[10];
  const float* fw1   = (const float*)d_in[11];
  const float* fb1   = (const float*)d_in[12];
  const float* fw2   = (const float*)d_in[13];
  const float* fb2   = (const float*)d_in[14];

  char* Wp = (char*)d_ws;
  size_t off = 0;
  auto take = [&](size_t bytes)->size_t{ size_t r = off; off += (bytes + 255) & ~(size_t)255; return r; };
  float*          outf = (float*)         (Wp + take(16777216)); // out (cur*bs, D) f32
  unsigned short* xbf  = (unsigned short*)(Wp + take( 8388608)); // out bf16
  float*          o1f  = (float*)         (Wp + take(16777216));
  unsigned short* o1b  = (unsigned short*)(Wp + take( 8388608));
  float*          zbf  = (float*)         (Wp + take(16777216)); // gru z-gate f32
  unsigned short* rxb  = (unsigned short*)(Wp + take( 8388608)); // r*x bf16
  unsigned short* yb   = (unsigned short*)(Wp + take( 8388608)); // Y / E2 bf16
  unsigned short* Eb   = (unsigned short*)(Wp + take( 8388608)); // LN2 out bf16
  unsigned short* wb0  = (unsigned short*)(Wp + take(52428800)); // layer weights bf16
  unsigned short* hTb  = (unsigned short*)(Wp + take( 4194304));
  unsigned short* webb = (unsigned short*)(Wp + take( 1048576));
  unsigned short* posb = (unsigned short*)(Wp + take( 2097152));
  unsigned short* nkb  = (unsigned short*)(Wp + take(16777216)); // LN'd key (full*bs, D)
  unsigned short* qUb  = (unsigned short*)(Wp + take( 8388608));
  unsigned short* qVb  = (unsigned short*)(Wp + take( 8388608));
  unsigned short* khb  = (unsigned short*)(Wp + take(16777216));
  unsigned short* vhTb = (unsigned short*)(Wp + take(16777216));
  unsigned short* F1b  = khb; // FF hidden (32MB) overlaps khb+vhTb (phase-disjoint)
  unsigned short* rhb  = (unsigned short*)(Wp + take( 2097152));
  unsigned short* ctxb = (unsigned short*)(Wp + take( 8388608));

  const int M1 = 1048576; // D*D elements

  // one-time prep
  conv_k<<<512, 256, 0, stream>>>(Wemb, webb, 524288);
  ht_k<<<4096, 128, 0, stream>>>(h, hTb);
  pos_k<<<1024, 256, 0, stream>>>(posb);

  { // embed: out = gelu(h @ Wemb^T + bemb)  (f32 + bf16)
    GP p{}; p.A=hTb; p.B=webb; p.OF=outf; p.O1=xbf; p.bias1=bemb;
    p.K=512; p.lda=512; p.ldb=512; p.ldo=1024;
    gemm_k<128,64,7><<<dim3(16,32,1),256,0,stream>>>(p);
  }

  // GRU (2 launches, K=2048 concat): x=xb/xf, y=yb_, weights w6 = [Wr,Ur,Wz,Uz,Wg,Ug]
  auto gru_fn = [&](const unsigned short* xb, const float* xf, const unsigned short* yb_,
                    const unsigned short* w6, float* of, unsigned short* ob){
    { GP p{}; p.A=yb_; p.A2=xb; p.B=w6; p.B2=w6+M1; p.sBz=2*M1;
      p.O1=rxb; p.OF=zbf; p.X=xf;
      p.K=2048; p.Ksplit=1024; p.lda=1024; p.ldb=1024; p.ldo=1024;
      gemm_k<128,64,11><<<dim3(16,32,2),256,0,stream>>>(p); }
    { GP p{}; p.A=yb_; p.A2=rxb; p.B=w6+4*M1; p.B2=w6+5*M1;
      p.X=xf; p.Z=zbf; p.OF=of; p.O1=ob;
      p.K=2048; p.Ksplit=1024; p.lda=1024; p.ldb=1024; p.ldo=1024;
      gemm_k<128,64,12><<<dim3(16,32,1),256,0,stream>>>(p); }
  };

  for (int l = 0; l < 4; ++l){
    // layer weights -> bf16
    conv_k<<<5120,256,0,stream>>>(Wattn + (long)l*5242880, wb0,          5242880);
    conv_k<<<6144,256,0,stream>>>(g1w   + (long)l*6291456, wb0 +  5*M1,  6291456);
    conv_k<<<6144,256,0,stream>>>(g2w   + (long)l*6291456, wb0 + 11*M1,  6291456);
    conv_k<<<4096,256,0,stream>>>(fw1   + (long)l*4194304, wb0 + 17*M1,  4194304);
    conv_k<<<4096,256,0,stream>>>(fw2   + (long)l*4194304, wb0 + 21*M1,  4194304);

    // nk = LN(concat(mem[l], out)); rows [4096:8192) are nq
    ln_k<<<8192,256,0,stream>>>(memin + (long)l*4194304, outf, 4096,
                                ln1 + l*2048, ln1 + l*2048 + 1024, nkb);

    { // fused QKV + R: z=0 kh, z=1 vhT, z=2 qU/qV (*0.125), z=3 rh
      GP p{}; p.A=nkb; p.A2=posb; p.B=wb0;
      p.O1=khb; p.O2=vhTb; p.O3=qUb; p.O4=qVb; p.O5=rhb;
      p.bias1=Ub; p.bias2=Vb;
      p.K=1024; p.lda=1024; p.ldb=1024; p.ldo=1024;
      gemm_k<128,64,13><<<dim3(16,64,4),256,0,stream>>>(p); }

    attn_k<<<4096,256,0,stream>>>(qUb, qVb, khb, rhb, vhTb, ctxb);

    { // Y = gelu(ctx @ Wo^T)
      GP p{}; p.A=ctxb; p.B=wb0+4*M1; p.O1=yb;
      p.K=1024; p.lda=1024; p.ldb=1024; p.ldo=1024;
      gemm_k<128,64,6><<<dim3(16,32,1),256,0,stream>>>(p); }

    gru_fn(xbf, outf, yb, wb0 + 5*M1, o1f, o1b);

    ln_k<<<4096,256,0,stream>>>(o1f, nullptr, 1<<30,
                                ln2 + l*2048, ln2 + l*2048 + 1024, Eb);

    { GP p{}; p.A=Eb;  p.B=wb0+17*M1; p.O1=F1b; p.bias1=fb1 + l*4096;
      p.K=1024; p.lda=1024; p.ldb=1024; p.ldo=4096;
      gemm_k<128,64,6><<<dim3(64,32,1),256,0,stream>>>(p); }
    { GP p{}; p.A=F1b; p.B=wb0+21*M1; p.O1=yb; p.bias1=fb2 + l*1024;
      p.K=4096; p.lda=4096; p.ldb=4096; p.ldo=1024;
      gemm_k<128,64,6><<<dim3(16,32,1),256,0,stream>>>(p); }

    gru_fn(o1b, o1f, yb, wb0 + 11*M1, outf, xbf);
  }

  outT_k<<<4096,256,0,stream>>>(outf, (float*)d_out);
}

// Round 7
// 2686.854 us; speedup vs baseline: 2.0369x; 1.0172x over previous
//
#include <hip/hip_runtime.h>
#include <hip/hip_bf16.h>

// Gated Transformer-XL forward.
// Dims: L=4, D=1024, NH=16, HD=64, CUR=512, MEM=512, BS=8, IN=512, FF=4096, FULL=1024
// Activation layout: (seq*BS, D), row = i*BS + b.

typedef __attribute__((ext_vector_type(8))) __bf16 bfrag;
typedef __attribute__((ext_vector_type(4))) float f4;
typedef __attribute__((ext_vector_type(4))) unsigned short u16x4;
typedef __attribute__((ext_vector_type(8))) unsigned short u16x8;

__device__ __forceinline__ unsigned short f2bf(float f){
  union { float f; unsigned u; } v; v.f = f;
  unsigned r = v.u + 0x7fffu + ((v.u >> 16) & 1u);
  return (unsigned short)(r >> 16);
}
__device__ __forceinline__ float bf2f(unsigned short u){
  union { unsigned u; float f; } v; v.u = (unsigned)u << 16; return v.f;
}
__device__ __forceinline__ float geluf(float x){
  return 0.5f * x * (1.0f + erff(x * 0.7071067811865476f));
}
__device__ __forceinline__ float sigm(float x){ return 1.0f/(1.0f + __expf(-x)); }

__device__ __forceinline__ void gl_lds(const void* g, void* l){
  __builtin_amdgcn_global_load_lds(
    reinterpret_cast<const __attribute__((address_space(1))) unsigned int*>(
        reinterpret_cast<unsigned long>(g)),
    reinterpret_cast<__attribute__((address_space(3))) unsigned int*>(
        reinterpret_cast<unsigned long>(l)),
    16, 0, 0);
}

// ---------------------------------------------------------------------------
// Dense GEMM: C[M,N] = A[M,K] @ B[N,K]^T (bf16, row-major). Optional K-concat.
// BK=64 mega-steps (4 LDS buffers, one barrier per 64-K).
// XCD-aware block swizzle: each XCD gets a contiguous y-chunk so A row-panels
// are fetched into ONE per-XCD L2 instead of all 8.
// EPI: 6  O1 = bf(gelu(acc + bias1))
//      7  OF = gelu(acc+bias1) f32, O1 = bf16 of same          (embed)
//      11 z==0: O1 = bf(sigm(acc) * X)   (GRU r-gate * x)
//         z==1: OF = sigm(acc - 2)       (GRU z-gate)
//      12 o = (1-Z)*X + Z*tanh(acc); OF = o; O1 = bf(o)        (GRU combine)
//      13 fused QKV+R: z=0 kh, z=1 vhT-scatter, z=2 qU/qV(+bias, *0.125), z=3 rh
// ---------------------------------------------------------------------------
struct GP {
  const unsigned short* A;
  const unsigned short* A2;
  const unsigned short* B;
  const unsigned short* B2;
  unsigned short* O1;
  unsigned short* O2;
  unsigned short* O3;
  unsigned short* O4;
  unsigned short* O5;
  float* OF;
  const float* bias1;
  const float* bias2;
  const float* X;
  const float* Z;
  int K, Ksplit, lda, ldb, ldo;
  int sBz;
};

template<int BM, int BN, int EPI>
__global__ __launch_bounds__(256) void gemm_k(GP p){
  __shared__ unsigned short As[2][2][BM*32];
  __shared__ unsigned short Bs[2][2][BN*32];
  const int tid  = threadIdx.x;
  const int lane = tid & 63;
  const int wid  = tid >> 6;
  const int lr   = lane & 15;
  const int lg   = lane >> 4;
  constexpr int FM = BM/32, FN = BN/32;

  // XCD swizzle (bijective; all grids have nwg%8==0)
  int bx = blockIdx.x, by = blockIdx.y;
  {
    const int gx = gridDim.x;
    const int nwg = gx * gridDim.y;
    if ((nwg & 7) == 0){
      const int bid = by*gx + bx;
      const int vid = (bid & 7)*(nwg >> 3) + (bid >> 3);
      bx = vid % gx;
      by = vid / gx;
    }
  }
  const int m0 = by * BM;
  const int n0 = bx * BN;
  const int z  = blockIdx.z;

  const unsigned short* Abase = p.A;
  const unsigned short* Bbase = p.B;
  if constexpr (EPI==13){
    if (z==2){ if (by >= 32) return; Abase = p.A + 4194304; }
    if (z==3){ if (by >= 8)  return; Abase = p.A2; }
    const int zsel = (z==0)?1:((z==1)?2:((z==2)?0:3));
    Bbase = p.B + (long)zsel*1048576;
  }

  const int ksp = p.Ksplit ? p.Ksplit : p.K;
  const unsigned short* AbL = Abase + (long)m0*p.lda;
  const unsigned short* AbH = p.A2 && EPI!=13 ? (p.A2 + (long)m0*p.lda - ksp) : AbL;
  const unsigned short* BbL = Bbase + (long)z*p.sBz + (long)n0*p.ldb;
  const unsigned short* BbH = p.B2 ? (p.B2 + (long)z*p.sBz + (long)n0*p.ldb - ksp) : BbL;

  const int srow = tid >> 2;          // 0..63
  const int skk  = (tid & 3) * 8;

  f4 acc[FM][FN];
  f4 zero4 = {0.0f, 0.0f, 0.0f, 0.0f};
  #pragma unroll
  for (int m=0;m<FM;m++)
    #pragma unroll
    for (int n=0;n<FN;n++) acc[m][n] = zero4;

  auto stage = [&](int buf, int sub, int k0){
    const unsigned short* A_ = (k0 < ksp) ? AbL : AbH;
    #pragma unroll
    for (int q=0;q<BM/64;q++)
      gl_lds(A_ + (long)(q*64 + srow)*p.lda + k0 + skk, (char*)As[buf][sub] + q*4096 + wid*1024);
    const unsigned short* B_ = (k0 < ksp) ? BbL : BbH;
    #pragma unroll
    for (int q=0;q<BN/64;q++)
      gl_lds(B_ + (long)(q*64 + srow)*p.ldb + k0 + skk, (char*)Bs[buf][sub] + q*4096 + wid*1024);
  };

  const int nk2 = p.K >> 6;
  stage(0,0,0); stage(0,1,32);
  __syncthreads();

  int cur = 0;
  for (int t = 0; t < nk2; ++t){
    if (t+1 < nk2){
      stage(cur^1, 0, (t+1)*64);
      stage(cur^1, 1, (t+1)*64 + 32);
    }
    #pragma unroll
    for (int sub=0; sub<2; ++sub){
      bfrag af[FM], bfr[FN];
      #pragma unroll
      for (int m=0;m<FM;m++)
        af[m] = *(const bfrag*)&As[cur][sub][((wid>>1)*(BM/2) + m*16 + lr)*32 + lg*8];
      #pragma unroll
      for (int n=0;n<FN;n++)
        bfr[n] = *(const bfrag*)&Bs[cur][sub][((wid&1)*(BN/2) + n*16 + lr)*32 + lg*8];
      #pragma unroll
      for (int m=0;m<FM;m++)
        #pragma unroll
        for (int n=0;n<FN;n++)
          acc[m][n] = __builtin_amdgcn_mfma_f32_16x16x32_bf16(af[m], bfr[n], acc[m][n], 0, 0, 0);
    }
    __syncthreads();   // drains vmcnt(0): mega-tile t+1 resident; buffers reusable
    cur ^= 1;
  }

  const int wr0 = m0 + (wid>>1)*(BM/2);
  const int wc0 = n0 + (wid&1)*(BN/2);
  #pragma unroll
  for (int m=0;m<FM;m++)
    #pragma unroll
    for (int n=0;n<FN;n++)
      #pragma unroll
      for (int r=0;r<4;r++){
        const int gr = wr0 + m*16 + lg*4 + r;
        const int gc = wc0 + n*16 + lr;
        const float a = acc[m][n][r];
        const long base = (long)gr*p.ldo + gc;
        if constexpr (EPI==6){
          const float t = a + (p.bias1 ? p.bias1[gc] : 0.0f);
          p.O1[base] = f2bf(geluf(t));
        }
        else if constexpr (EPI==7){
          const float t = geluf(a + p.bias1[gc]);
          p.OF[base] = t; p.O1[base] = f2bf(t);
        }
        else if constexpr (EPI==11){
          const long ix = (long)gr*1024 + gc;
          if (z==0) p.O1[ix] = f2bf(sigm(a) * p.X[ix]);
          else      p.OF[ix] = sigm(a - 2.0f);
        }
        else if constexpr (EPI==12){
          const long ix = (long)gr*1024 + gc;
          const float zz = p.Z[ix];
          const float oo = (1.0f - zz)*p.X[ix] + zz*tanhf(a);
          p.OF[ix] = oo; p.O1[ix] = f2bf(oo);
        }
        else if constexpr (EPI==13){
          const long ix = (long)gr*1024 + gc;
          if (z==0){ p.O1[ix] = f2bf(a); }
          else if (z==1){
            const int b_ = gr & 7, js = gr >> 3, h_ = gc >> 6, d_ = gc & 63;
            p.O2[(long)(b_*16 + h_)*65536 + (long)d_*1024 + js] = f2bf(a);
          }
          else if (z==2){ p.O3[ix] = f2bf((a + p.bias1[gc])*0.125f);
                          p.O4[ix] = f2bf((a + p.bias2[gc])*0.125f); }
          else { p.O5[ix] = f2bf(a); }
        }
      }
}

// ---------------------------------------------------------------------------
// Fused relative attention (round-5 proven body). Block = one (b,h), 16 query
// rows [i0,i0+16). 4 waves; interleaved-pair column mapping; triangular skip
// in half1 (valid groups g = 2w+8t+sub <= gmax). BDpre^T band in LDS stride
// 38B, shift-on-read. Softmax in regs; P staged per-32-col chunk; PV per wave.
// ---------------------------------------------------------------------------
__global__ __launch_bounds__(256,4) void attn_k(const unsigned short* __restrict__ qU,
                                                const unsigned short* __restrict__ qV,
                                                const unsigned short* __restrict__ kh,
                                                const unsigned short* __restrict__ rh,
                                                const unsigned short* __restrict__ vhT,
                                                unsigned short* __restrict__ ctx){
  __shared__ char Sm[20480];          // band (528*38=20064) / P-chunks (4KB) / po @4096 (16KB)
  __shared__ float redm[4][16];
  __shared__ float reds[4][16];
  __shared__ float invd[16];
  const int tid = threadIdx.x;
  const int w   = tid >> 6;
  const int lane= tid & 63;
  const int lr  = lane & 15;
  const int lg  = lane >> 4;
  const int id = blockIdx.x;
  const int b  = id & 7;              // id%8 -> XCD: per-b kh/vhT slice stays in one L2
  const int i0 = ((id >> 3) & 31) * 16;
  const int h  = id >> 8;
  const int gmax = i0 >> 4;           // last valid 16-col group in half1
  const long hoff = (long)h * 64;
  const f4 z4 = {0.f,0.f,0.f,0.f};

  // qV as B-operand (N=di) for band fill
  bfrag bqv[2];
  #pragma unroll
  for (int kk=0;kk<2;kk++)
    bqv[kk] = *(const bfrag*)(qV + ((long)(i0 + lr)*8 + b)*1024 + hoff + kk*32 + lg*8);
  // qU as A-operand (M=i) for AC
  bfrag aq[2];
  #pragma unroll
  for (int kk=0;kk<2;kk++)
    aq[kk] = *(const bfrag*)(qU + ((long)(i0 + lr)*8 + b)*1024 + hoff + kk*32 + lg*8);

  f4 s[16];
  #pragma unroll
  for (int n=0;n<16;n++) s[n] = (f4){-1e30f,-1e30f,-1e30f,-1e30f};

  #pragma unroll
  for (int half=0; half<2; ++half){
    const int c0    = half*512;
    const int rbase = half ? (1008 - i0) : (496 - i0);
    const int ntil  = half ? (gmax + 1) : 33;
    const int radd  = half ? -497 : 15;      // rr = jc - di + radd
    // ---- band fill: BDpre^T rows rr, cols di ----
    for (int mt = w; mt < ntil; mt += 4){
      const int r0 = rbase + mt*16;
      f4 acc = z4;
      #pragma unroll
      for (int kk=0;kk<2;kk++){
        bfrag ar = *(const bfrag*)(rh + (long)(r0 + lr)*1024 + hoff + kk*32 + lg*8);
        acc = __builtin_amdgcn_mfma_f32_16x16x32_bf16(ar, bqv[kk], acc, 0,0,0);
      }
      #pragma unroll
      for (int q=0;q<4;q++){
        const int rr = mt*16 + lg*4 + q;
        *(unsigned short*)(Sm + rr*38 + lr*2) = f2bf(acc[q]);
      }
    }
    __syncthreads();
    // ---- AC + BD for this wave's cols (skip fully-masked groups) ----
    #pragma unroll
    for (int n=0;n<8;n++){
      const int g = 2*w + ((n>>1)<<3) + (n&1);
      if (half==1 && g > gmax) continue;
      const int cb = c0 + w*32 + (n>>1)*128 + (n&1)*16;
      f4 a = z4;
      #pragma unroll
      for (int kk=0;kk<2;kk++){
        bfrag bk = *(const bfrag*)(kh + ((long)(cb + lr)*8 + b)*1024 + hoff + kk*32 + lg*8);
        a = __builtin_amdgcn_mfma_f32_16x16x32_bf16(aq[kk], bk, a, 0,0,0);
      }
      #pragma unroll
      for (int q=0;q<4;q++){
        const int di = lg*4 + q;
        const int jc = cb + lr;
        if (jc > i0 + di + 512) a[q] = -1e30f;
        else {
          const int rr = jc - di + radd;
          a[q] += bf2f(*(const unsigned short*)(Sm + rr*38 + di*2));
        }
      }
      s[half*8 + n] = a;
    }
    __syncthreads();   // all band reads done before next half / P staging
  }

  // ---- softmax stats over full 1024 cols ----
  float mx[4], sum[4];
  #pragma unroll
  for (int q=0;q<4;q++){
    float m = s[0][q];
    #pragma unroll
    for (int n=1;n<16;n++) m = fmaxf(m, s[n][q]);
    m = fmaxf(m, __shfl_xor(m, 1));
    m = fmaxf(m, __shfl_xor(m, 2));
    m = fmaxf(m, __shfl_xor(m, 4));
    m = fmaxf(m, __shfl_xor(m, 8));
    if (lr == 0) redm[w][lg*4+q] = m;
  }
  __syncthreads();
  #pragma unroll
  for (int q=0;q<4;q++){
    const int row = lg*4+q;
    mx[q] = fmaxf(fmaxf(redm[0][row], redm[1][row]), fmaxf(redm[2][row], redm[3][row]));
    sum[q] = 0.0f;
  }
  #pragma unroll
  for (int n=0;n<16;n++)
    #pragma unroll
    for (int q=0;q<4;q++){
      const float e = __expf(s[n][q] - mx[q]);
      s[n][q] = e;
      sum[q] += e;
    }
  #pragma unroll
  for (int q=0;q<4;q++){
    float v = sum[q];
    v += __shfl_xor(v, 1);
    v += __shfl_xor(v, 2);
    v += __shfl_xor(v, 4);
    v += __shfl_xor(v, 8);
    if (lr == 0) reds[w][lg*4+q] = v;
  }
  __syncthreads();
  if (tid < 16)
    invd[tid] = 1.0f / (reds[0][tid] + reds[1][tid] + reds[2][tid] + reds[3][tid]);

  // ---- PV: per-wave over its valid 32-col chunks, P staged in LDS ----
  f4 oac[4];
  #pragma unroll
  for (int nd=0;nd<4;nd++) oac[nd] = z4;
  const unsigned short* vb_base = vhT + (long)(b*16 + h)*65536;
  char* Pch = Sm + w*1024;            // [16 rows][32 cols] u16, swizzled
  #pragma unroll
  for (int t=0;t<8;t++){
    const int hh_ = t>>2, tt = t&3;
    if (hh_==1 && (2*w + 8*tt) > gmax) continue;   // both groups dead
    const int jb = hh_*512 + w*32 + tt*128;
    #pragma unroll
    for (int nn=0;nn<2;nn++){
      const f4 e = s[hh_*8 + tt*2 + nn];
      #pragma unroll
      for (int q=0;q<4;q++){
        const int row = lg*4 + q;
        const int col = nn*16 + lr;
        *(unsigned short*)(Pch + row*64 + ((col*2) ^ (((row>>2)&3)<<4))) = f2bf(e[q]);
      }
    }
    bfrag pa = *(const bfrag*)(Pch + lr*64 + ((lg*16) ^ (((lr>>2)&3)<<4)));
    #pragma unroll
    for (int nd=0;nd<4;nd++){
      bfrag bv = *(const bfrag*)(vb_base + (long)(nd*16 + lr)*1024 + jb + lg*8);
      oac[nd] = __builtin_amdgcn_mfma_f32_16x16x32_bf16(pa, bv, oac[nd], 0,0,0);
    }
  }
  // partial O to LDS
  float* po = (float*)(Sm + 4096 + w*4096);   // [16][64] f32
  #pragma unroll
  for (int nd=0;nd<4;nd++)
    #pragma unroll
    for (int q=0;q<4;q++)
      po[(lg*4+q)*64 + nd*16 + lr] = oac[nd][q];
  __syncthreads();
  // ---- merge + normalize + write ----
  {
    const int row = tid >> 4;
    const int d0  = (tid & 15) * 4;
    f4 v = *(const f4*)(Sm + 4096 + (row*64 + d0)*4);
    #pragma unroll
    for (int ww=1;ww<4;ww++){
      const f4 u = *(const f4*)(Sm + 4096 + ww*4096 + (row*64 + d0)*4);
      v.x += u.x; v.y += u.y; v.z += u.z; v.w += u.w;
    }
    const float iv = invd[row];
    u16x4 o;
    o.x = f2bf(v.x*iv); o.y = f2bf(v.y*iv); o.z = f2bf(v.z*iv); o.w = f2bf(v.w*iv);
    *(u16x4*)(ctx + ((long)(i0 + row)*8 + b)*1024 + hoff + d0) = o;
  }
}

// ---------------------------------------------------------------------------
__global__ __launch_bounds__(256) void ln_k(const float* __restrict__ srcA,
                                            const float* __restrict__ srcB, int splitRow,
                                            const float* __restrict__ g, const float* __restrict__ b,
                                            unsigned short* __restrict__ dst){
  const int row = blockIdx.x;
  const float* src = (srcB != nullptr && row >= splitRow)
                       ? (srcB + (long)(row - splitRow)*1024)
                       : (srcA + (long)row*1024);
  const int t = threadIdx.x;
  float4 v = ((const float4*)src)[t];
  float s1 = v.x+v.y+v.z+v.w;
  float s2 = v.x*v.x+v.y*v.y+v.z*v.z+v.w*v.w;
  #pragma unroll
  for (int o=32;o;o>>=1){ s1 += __shfl_xor(s1,o); s2 += __shfl_xor(s2,o); }
  __shared__ float r1[4], r2[4];
  const int w = t>>6;
  if ((t&63)==0){ r1[w]=s1; r2[w]=s2; }
  __syncthreads();
  s1 = r1[0]+r1[1]+r1[2]+r1[3];
  s2 = r2[0]+r2[1]+r2[2]+r2[3];
  const float mean = s1*(1.0f/1024.0f);
  const float var  = s2*(1.0f/1024.0f) - mean*mean;
  const float rs   = rsqrtf(var + 1e-5f);
  float4 gg = ((const float4*)g)[t];
  float4 bb = ((const float4*)b)[t];
  u16x4 o;
  o.x = f2bf((v.x-mean)*rs*gg.x + bb.x);
  o.y = f2bf((v.y-mean)*rs*gg.y + bb.y);
  o.z = f2bf((v.z-mean)*rs*gg.z + bb.z);
  o.w = f2bf((v.w-mean)*rs*gg.w + bb.w);
  *(u16x4*)(dst + (long)row*1024 + t*4) = o;
}

__global__ __launch_bounds__(256) void conv_k(const float* __restrict__ s,
                                              unsigned short* __restrict__ d, long n){
  long i = ((long)blockIdx.x*256 + threadIdx.x)*4;
  if (i >= n) return;
  float4 v = *(const float4*)(s + i);
  u16x4 o; o.x=f2bf(v.x); o.y=f2bf(v.y); o.z=f2bf(v.z); o.w=f2bf(v.w);
  *(u16x4*)(d + i) = o;
}

// one launch converts all 5 weight blocks of a layer into contiguous wb0
__global__ __launch_bounds__(256) void conv5_k(const float* __restrict__ wat,
                                               const float* __restrict__ g1,
                                               const float* __restrict__ g2,
                                               const float* __restrict__ f1,
                                               const float* __restrict__ f2,
                                               unsigned short* __restrict__ dst){
  const long i = ((long)blockIdx.x*256 + threadIdx.x)*4;   // < 26214400
  const float* s; long off;
  if      (i <  5242880){ s = wat; off = 0; }
  else if (i < 11534336){ s = g1;  off = 5242880; }
  else if (i < 17825792){ s = g2;  off = 11534336; }
  else if (i < 22020096){ s = f1;  off = 17825792; }
  else                  { s = f2;  off = 22020096; }
  float4 v = *(const float4*)(s + (i - off));
  u16x4 o; o.x=f2bf(v.x); o.y=f2bf(v.y); o.z=f2bf(v.z); o.w=f2bf(v.w);
  *(u16x4*)(dst + i) = o;
}

__global__ __launch_bounds__(128) void ht_k(const float* __restrict__ h,
                                            unsigned short* __restrict__ d){
  const int row = blockIdx.x;           // i*8+b
  const int i = row>>3, b = row&7;
  const float* src = h + ((long)b*512 + i)*512;
  const int t = threadIdx.x;
  float4 v = ((const float4*)src)[t];
  u16x4 o; o.x=f2bf(v.x); o.y=f2bf(v.y); o.z=f2bf(v.z); o.w=f2bf(v.w);
  *(u16x4*)(d + (long)row*512 + t*4) = o;
}

__global__ __launch_bounds__(256) void pos_k(unsigned short* __restrict__ d){
  const int r = blockIdx.x, t = threadIdx.x;
  const float seq = (float)(1023 - r);
  u16x4 o;
  #pragma unroll
  for (int q=0;q<4;q++){
    const int c = t*4 + q;
    const int f = (c < 512) ? c : (c - 512);
    const float inv = expf((float)f * -0.017988946039016f); // -2*ln(1e4)/1024
    const float ang = seq * inv;
    const float val = (c < 512) ? sinf(ang) : cosf(ang);
    o[q] = f2bf(val);
  }
  *(u16x4*)(d + (long)r*1024 + t*4) = o;
}

__global__ __launch_bounds__(256) void outT_k(const float* __restrict__ o,
                                              float* __restrict__ d){
  const int row = blockIdx.x;   // b*512 + i
  const int b = row>>9, i = row&511;
  const float4 v = ((const float4*)(o + ((long)i*8 + b)*1024))[threadIdx.x];
  ((float4*)(d + (long)row*1024))[threadIdx.x] = v;
}

// ---------------------------------------------------------------------------
extern "C" void kernel_launch(void* const* d_in, const int* in_sizes, int n_in,
                              void* d_out, int out_size, void* d_ws, size_t ws_size,
                              hipStream_t stream){
  (void)in_sizes; (void)n_in; (void)out_size; (void)ws_size;
  const float* h     = (const float*)d_in[0];
  const float* memin = (const float*)d_in[1];
  const float* Wemb  = (const float*)d_in[2];
  const float* bemb  = (const float*)d_in[3];
  const float* Ub    = (const float*)d_in[4];
  const float* Vb    = (const float*)d_in[5];
  const float* ln1   = (const float*)d_in[6];
  const float* ln2   = (const float*)d_in[7];
  const float* Wattn = (const float*)d_in[8];
  const float* g1w   = (const float*)d_in[9];
  const float* g2w   = (const float*)d_in[10];
  const float* fw1   = (const float*)d_in[11];
  const float* fb1   = (const float*)d_in[12];
  const float* fw2   = (const float*)d_in[13];
  const float* fb2   = (const float*)d_in[14];

  char* Wp = (char*)d_ws;
  size_t off = 0;
  auto take = [&](size_t bytes)->size_t{ size_t r = off; off += (bytes + 255) & ~(size_t)255; return r; };
  float*          outf = (float*)         (Wp + take(16777216)); // out (cur*bs, D) f32
  unsigned short* xbf  = (unsigned short*)(Wp + take( 8388608)); // out bf16
  float*          o1f  = (float*)         (Wp + take(16777216));
  unsigned short* o1b  = (unsigned short*)(Wp + take( 8388608));
  float*          zbf  = (float*)         (Wp + take(16777216)); // gru z-gate f32
  unsigned short* rxb  = (unsigned short*)(Wp + take( 8388608)); // r*x bf16
  unsigned short* yb   = (unsigned short*)(Wp + take( 8388608)); // Y / E2 bf16
  unsigned short* Eb   = (unsigned short*)(Wp + take( 8388608)); // LN2 out bf16
  unsigned short* wb0  = (unsigned short*)(Wp + take(52428800)); // layer weights bf16
  unsigned short* hTb  = (unsigned short*)(Wp + take( 4194304));
  unsigned short* webb = (unsigned short*)(Wp + take( 1048576));
  unsigned short* posb = (unsigned short*)(Wp + take( 2097152));
  unsigned short* nkb  = (unsigned short*)(Wp + take(16777216)); // LN'd key (full*bs, D)
  unsigned short* qUb  = (unsigned short*)(Wp + take( 8388608));
  unsigned short* qVb  = (unsigned short*)(Wp + take( 8388608));
  unsigned short* khb  = (unsigned short*)(Wp + take(16777216));
  unsigned short* vhTb = (unsigned short*)(Wp + take(16777216));
  unsigned short* F1b  = khb; // FF hidden (32MB) overlaps khb+vhTb (phase-disjoint)
  unsigned short* rhb  = (unsigned short*)(Wp + take( 2097152));
  unsigned short* ctxb = (unsigned short*)(Wp + take( 8388608));

  const int M1 = 1048576; // D*D elements

  // one-time prep
  conv_k<<<512, 256, 0, stream>>>(Wemb, webb, 524288);
  ht_k<<<4096, 128, 0, stream>>>(h, hTb);
  pos_k<<<1024, 256, 0, stream>>>(posb);

  { // embed: out = gelu(h @ Wemb^T + bemb)  (f32 + bf16)
    GP p{}; p.A=hTb; p.B=webb; p.OF=outf; p.O1=xbf; p.bias1=bemb;
    p.K=512; p.lda=512; p.ldb=512; p.ldo=1024;
    gemm_k<128,64,7><<<dim3(16,32,1),256,0,stream>>>(p);
  }

  // GRU (2 launches, K=2048 concat): x=xb/xf, y=yb_, weights w6 = [Wr,Ur,Wz,Uz,Wg,Ug]
  auto gru_fn = [&](const unsigned short* xb, const float* xf, const unsigned short* yb_,
                    const unsigned short* w6, float* of, unsigned short* ob){
    { GP p{}; p.A=yb_; p.A2=xb; p.B=w6; p.B2=w6+M1; p.sBz=2*M1;
      p.O1=rxb; p.OF=zbf; p.X=xf;
      p.K=2048; p.Ksplit=1024; p.lda=1024; p.ldb=1024; p.ldo=1024;
      gemm_k<128,64,11><<<dim3(16,32,2),256,0,stream>>>(p); }
    { GP p{}; p.A=yb_; p.A2=rxb; p.B=w6+4*M1; p.B2=w6+5*M1;
      p.X=xf; p.Z=zbf; p.OF=of; p.O1=ob;
      p.K=2048; p.Ksplit=1024; p.lda=1024; p.ldb=1024; p.ldo=1024;
      gemm_k<128,64,12><<<dim3(16,32,1),256,0,stream>>>(p); }
  };

  for (int l = 0; l < 4; ++l){
    // layer weights -> bf16 (single merged launch: 25600 blocks)
    conv5_k<<<25600,256,0,stream>>>(Wattn + (long)l*5242880,
                                    g1w   + (long)l*6291456,
                                    g2w   + (long)l*6291456,
                                    fw1   + (long)l*4194304,
                                    fw2   + (long)l*4194304, wb0);

    // nk = LN(concat(mem[l], out)); rows [4096:8192) are nq
    ln_k<<<8192,256,0,stream>>>(memin + (long)l*4194304, outf, 4096,
                                ln1 + l*2048, ln1 + l*2048 + 1024, nkb);

    { // fused QKV + R: z=0 kh, z=1 vhT, z=2 qU/qV (*0.125), z=3 rh
      GP p{}; p.A=nkb; p.A2=posb; p.B=wb0;
      p.O1=khb; p.O2=vhTb; p.O3=qUb; p.O4=qVb; p.O5=rhb;
      p.bias1=Ub; p.bias2=Vb;
      p.K=1024; p.lda=1024; p.ldb=1024; p.ldo=1024;
      gemm_k<128,64,13><<<dim3(16,64,4),256,0,stream>>>(p); }

    attn_k<<<4096,256,0,stream>>>(qUb, qVb, khb, rhb, vhTb, ctxb);

    { // Y = gelu(ctx @ Wo^T)
      GP p{}; p.A=ctxb; p.B=wb0+4*M1; p.O1=yb;
      p.K=1024; p.lda=1024; p.ldb=1024; p.ldo=1024;
      gemm_k<128,64,6><<<dim3(16,32,1),256,0,stream>>>(p); }

    gru_fn(xbf, outf, yb, wb0 + 5*M1, o1f, o1b);

    ln_k<<<4096,256,0,stream>>>(o1f, nullptr, 1<<30,
                                ln2 + l*2048, ln2 + l*2048 + 1024, Eb);

    { GP p{}; p.A=Eb;  p.B=wb0+17*M1; p.O1=F1b; p.bias1=fb1 + l*4096;
      p.K=1024; p.lda=1024; p.ldb=1024; p.ldo=4096;
      gemm_k<128,64,6><<<dim3(64,32,1),256,0,stream>>>(p); }
    { GP p{}; p.A=F1b; p.B=wb0+21*M1; p.O1=yb; p.bias1=fb2 + l*1024;
      p.K=4096; p.lda=4096; p.ldb=4096; p.ldo=1024;
      gemm_k<128,64,6><<<dim3(16,32,1),256,0,stream>>>(p); }

    gru_fn(o1b, o1f, yb, wb0 + 11*M1, outf, xbf);
  }

  outT_k<<<4096,256,0,stream>>>(outf, (float*)d_out);
}